// Round 8
// baseline (3964.186 us; speedup 1.0000x reference)
//
#include <hip/hip_runtime.h>
#include <cstdint>
#include <cstddef>

typedef unsigned short u16;
typedef unsigned long long u64;
typedef __attribute__((ext_vector_type(8))) short s16x8;
typedef __attribute__((ext_vector_type(4))) float f32x4;
typedef __attribute__((ext_vector_type(4))) unsigned short u16x4;

#define AGENT __HIP_MEMORY_SCOPE_AGENT

namespace {
constexpr int NWG  = 256;
constexpr int NTHR = 256;
constexpr int Bb   = 256;   // batch
constexpr int Tt   = 256;   // timesteps
constexpr int EMB_ = 256;
constexpr int HID_ = 512;
constexpr int NCLS = 32000;

// ---- LDS layout (bytes). B-operands stored in MFMA lane order.
constexpr int OFF_W1  = 0;        // cell1 [24 kb][2 n][64 lane][8] = 49152 B
constexpr int OFF_W3  = 49152;    // cell2, same shape
constexpr int OFF_W2  = 98304;    // mix   [32 kb][1 n][64][8]     = 32768 B
constexpr int OFF_DS  = 131072;   // cell2 gate scratch [64][33] f32 = 8448 B
constexpr int OFF_DS1 = 139520;   // cell1 gate scratch [64][33] f32 = 8448 B
constexpr int OFF_DSM = 147968;   // mix per-wave transpose 2 x [16][17] f32 = 2176 B
constexpr int OFF_C   = 150144;   // cell1 C state [64][8] f32 (bq reuse in final)
constexpr int OFF_C1  = 152192;   // cell2 C state
constexpr int OFF_B1  = 154240;
constexpr int OFF_B3  = 154368;
constexpr int OFF_B2  = 154496;
constexpr int SMEM_BYTES = 154560;            // 1 WG/CU

// ---- workspace layout (bytes) ----
// fl lines: 256 x 128B. dword +0: heavy-barrier flag (init; store-then-compare,
// poison-immune). dword +16 (byte +64, separate sector) of the group's lines:
// monotonic event counters, EXPLICITLY ZEROED in init (ws is poisoned):
//   lines LA+0..7  : A-counters (cell2 done)  +1/WG/event  -> +8 /line/event
//   lines LM+0..7  : M-counters (mix done)    +1/wave(w01) -> +16/line/event
//   lines LC+0..7  : C-counters (cell1 done)  +1/wave      -> +16/line/event
constexpr int LA = 0, LM = 8, LC = 16;
constexpr size_t WS_FL   = 0;                          // 256 WGs x 128 B = 32 KB
constexpr size_t WS_DONE = 32768;                      // 256 int done flags (one-time)
constexpr size_t WS_HB0  = 33792;                      // H parity buffers [B][512] bf16
constexpr size_t WS_HB1  = WS_HB0 + (size_t)Bb * HID_ * 2;
constexpr size_t WS_H1   = WS_HB1 + (size_t)Bb * HID_ * 2;   // H1 state
constexpr size_t WS_HM   = WS_H1 + (size_t)Bb * HID_ * 2;    // H1mix
constexpr size_t WS_XE   = WS_HM + (size_t)Bb * HID_ * 2;    // Xe [T][B][EMB] bf16
}  // namespace

struct Params {
  const int* X; const float* Hin; const float* Cin; const float* E;
  const float* Wx[4];  const float* Wh[4];  const float* bg[4];   // cell 1 (i,f,o,c)
  const float* Wx1[4]; const float* Wh1[4]; const float* bg1[4];  // cell 2
  const float* Wxh; const float* Whh; const float* bh;
  const float* Whq; const float* bq;
  float* out; char* ws;
};

__device__ __forceinline__ u16 f2bf(float f) {
  union { float f; unsigned u; } v; v.f = f;
  unsigned r = v.u + 0x7FFFu + ((v.u >> 16) & 1u);
  return (u16)(r >> 16);
}
__device__ __forceinline__ float sigm(float x) { return 1.f / (1.f + __expf(-x)); }
__device__ __forceinline__ float tanh_(float x) {
  x = fminf(fmaxf(x, -10.f), 10.f);
  float e = __expf(-2.f * x);
  return (1.f - e) / (1.f + e);
}
__device__ __forceinline__ f32x4 mfma16(s16x8 a, s16x8 b, f32x4 c) {
  return __builtin_amdgcn_mfma_f32_16x16x32_bf16(a, b, c, 0, 0, 0);
}

// ---- producer side: LLC-coherent bypass stores (relaxed agent atomics).
__device__ __forceinline__ void st8_llc(u16* p2, u64 v) {
  __hip_atomic_store((u64*)p2, v, __ATOMIC_RELAXED, AGENT);
}

// ---- consumer side: 16B LLC-coherent bypass loads (sc0 sc1 bypass L1/L2).
// Full-line coalescing: 4 lanes x 16B = one 64B fabric txn (round-5 proven).
#define LD16A(d, b, off)                                                      \
  asm volatile("global_load_dwordx4 %0, %1, off offset:" #off " sc0 sc1"      \
               : "=&v"(d) : "v"(b) : "memory")

__device__ __forceinline__ void ld_h16(s16x8* d, const u16* b) {
  LD16A(d[0],  b, 0);   LD16A(d[1],  b, 64);  LD16A(d[2],  b, 128);
  LD16A(d[3],  b, 192); LD16A(d[4],  b, 256); LD16A(d[5],  b, 320);
  LD16A(d[6],  b, 384); LD16A(d[7],  b, 448); LD16A(d[8],  b, 512);
  LD16A(d[9],  b, 576); LD16A(d[10], b, 640); LD16A(d[11], b, 704);
  LD16A(d[12], b, 768); LD16A(d[13], b, 832); LD16A(d[14], b, 896);
  LD16A(d[15], b, 960);
}
// Drain asm loads; sched_barrier stops MFMAs hoisting above (rule #18).
__device__ __forceinline__ void waitld() {
  asm volatile("s_waitcnt vmcnt(0)" ::: "memory");
  __builtin_amdgcn_sched_barrier(0);
}

// ---- event-typed split barriers -------------------------------------------
// wait: wave-converged poll (64 lanes each read line lane&7 of the set) until
// all 8 sub-counters reach tgt. NO syncthreads -> waves block independently.
__device__ __forceinline__ void wait_wave(int* fl, int lineBase, int tgt) {
  const int lane = threadIdx.x & 63;
  for (;;) {
    int v = __hip_atomic_load(&fl[(lineBase + (lane & 7)) * 32 + 16],
                              __ATOMIC_RELAXED, AGENT);
    if (!__any(v < tgt)) break;
    __builtin_amdgcn_s_sleep(1);
  }
  __builtin_amdgcn_fence(__ATOMIC_ACQUIRE, "workgroup");  // compiler/order only
}
// per-wave arrive: drain this wave's sc1 stores (vmcnt), then one add.
__device__ __forceinline__ void arrive_wave(int* fl, int lineBase, int c) {
  asm volatile("s_waitcnt vmcnt(0)" ::: "memory");
  if ((threadIdx.x & 63) == 0)
    (void)__hip_atomic_fetch_add(&fl[(lineBase + (c & 7)) * 32 + 16], 1,
                                 __ATOMIC_RELAXED, AGENT);
}
// whole-WG arrive (cell2): syncthreads drains all waves' stores, one add.
__device__ __forceinline__ void arrive_all(int* fl, int lineBase, int c) {
  __syncthreads();
  if (threadIdx.x == 0)
    (void)__hip_atomic_fetch_add(&fl[(lineBase + (c & 7)) * 32 + 16], 1,
                                 __ATOMIC_RELAXED, AGENT);
}

// Heavy barrier (release store + agent acquire fence). Used ONCE after init
// (publishes normal-stored Xe/H-init AND the counter zero-stores).
__device__ __forceinline__ void groupbar_heavy(int* fl, int slot, int ph) {
  __syncthreads();
  if (threadIdx.x == 0)
    __hip_atomic_store(&fl[slot * 32], ph, __ATOMIC_RELEASE, AGENT);
  if (threadIdx.x < 64) {
    for (;;) {
      int v = __hip_atomic_load(&fl[threadIdx.x * 32], __ATOMIC_RELAXED, AGENT);
      if (!__any(v < ph)) break;
      __builtin_amdgcn_s_sleep(1);
    }
  }
  __syncthreads();
  __builtin_amdgcn_fence(__ATOMIC_ACQUIRE, "agent");
}

// One-time all-grid done wait; heavy so the final GEMM can use cached loads.
__device__ __forceinline__ void donebar(int* dn, int bi) {
  __syncthreads();
  if (threadIdx.x == 0)
    __hip_atomic_store(&dn[bi], 1, __ATOMIC_RELEASE, AGENT);
  for (;;) {
    int v = __hip_atomic_load(&dn[threadIdx.x], __ATOMIC_RELAXED, AGENT);
    if (!__any(v < 1)) break;
    __builtin_amdgcn_s_sleep(1);
  }
  __syncthreads();
  __builtin_amdgcn_fence(__ATOMIC_ACQUIRE, "agent");
}

// Prologue cell1(0): 4 waves, internal syncthreads, stores by tid<128.
__device__ __forceinline__ void cell_phase(char* smem, int offW, int offB, int offC,
                                           const u16* Xt, const u16* Hrec, u16* Hdst,
                                           int g, int c, int w, int lane, int tid) {
  const int r = lane & 15, q = lane >> 4;
  const int row0 = w * 16;
  const u16* xrow = Xt + (size_t)(g * 64 + row0 + r) * EMB_;
  const u16* hrow = Hrec + (size_t)(g * 64 + row0 + r) * HID_;
  const u16* wb = (const u16*)(smem + offW) + lane * 8;
  f32x4 acc0 = {0.f, 0.f, 0.f, 0.f}, acc1 = {0.f, 0.f, 0.f, 0.f};
#pragma unroll
  for (int kb = 0; kb < 8; kb++) {
    s16x8 a  = *(const s16x8*)(xrow + kb * 32 + q * 8);
    s16x8 b0 = *(const s16x8*)(wb + (size_t)(kb * 2 + 0) * 512);
    s16x8 b1 = *(const s16x8*)(wb + (size_t)(kb * 2 + 1) * 512);
    acc0 = mfma16(a, b0, acc0);
    acc1 = mfma16(a, b1, acc1);
  }
  s16x8 ha[16];
  ld_h16(ha, hrow + q * 8);
  waitld();
#pragma unroll
  for (int kb = 0; kb < 16; kb++) {
    s16x8 b0 = *(const s16x8*)(wb + (size_t)((kb + 8) * 2 + 0) * 512);
    s16x8 b1 = *(const s16x8*)(wb + (size_t)((kb + 8) * 2 + 1) * 512);
    acc0 = mfma16(ha[kb], b0, acc0);
    acc1 = mfma16(ha[kb], b1, acc1);
  }
  float* Ds = (float*)(smem + OFF_DS);
#pragma unroll
  for (int i = 0; i < 4; i++) {
    Ds[(row0 + q * 4 + i) * 33 + r]      = acc0[i];
    Ds[(row0 + q * 4 + i) * 33 + 16 + r] = acc1[i];
  }
  __syncthreads();
  const float* bs = (const float*)(smem + offB);
  float* Cs = (float*)(smem + offC);
  if (tid < 128) {
    int row = tid >> 1, j0 = (tid & 1) * 4;
    union { u16 h[4]; u64 qv; } pk;
#pragma unroll
    for (int i = 0; i < 4; i++) {
      int j = j0 + i;
      float vi = Ds[row * 33 + 0 + j]  + bs[0 + j];
      float vf = Ds[row * 33 + 8 + j]  + bs[8 + j];
      float vo = Ds[row * 33 + 16 + j] + bs[16 + j];
      float vc = Ds[row * 33 + 24 + j] + bs[24 + j];
      float I = sigm(vi), F = sigm(vf), O = sigm(vo), Ct = tanh_(vc);
      float Cn = F * Cs[row * 8 + j] + I * Ct;
      Cs[row * 8 + j] = Cn;
      pk.h[i] = f2bf(O * tanh_(Cn));
    }
    st8_llc(Hdst + (size_t)(g * 64 + row) * HID_ + c * 8 + j0, pk.qv);
  }
}

// cell1 on waves 2-3 only: full gate GEMM + elementwise + H-store, wave-local.
__device__ __forceinline__ void cell1_w23(char* smem, const u16* Xt, const u16* Hrec,
                                          u16* Hdst, int g, int c, int lane, int tid) {
  const int wv = (tid >> 6) - 2;
  const int r = lane & 15, q = lane >> 4;
  const u16* wb1 = (const u16*)(smem + OFF_W1) + lane * 8;
  float* D1 = (float*)(smem + OFF_DS1);
#pragma unroll
  for (int blk = 0; blk < 2; blk++) {
    const int rb = wv * 32 + blk * 16;
    const u16* xrow = Xt + (size_t)(g * 64 + rb + r) * EMB_;
    const u16* hrow = Hrec + (size_t)(g * 64 + rb + r) * HID_;
    s16x8 xa[8];
#pragma unroll
    for (int kb = 0; kb < 8; kb++) xa[kb] = *(const s16x8*)(xrow + kb * 32 + q * 8);
    s16x8 hh[16];
    ld_h16(hh, hrow + q * 8);
    f32x4 a0 = {0.f, 0.f, 0.f, 0.f}, a1 = {0.f, 0.f, 0.f, 0.f};
#pragma unroll
    for (int kb = 0; kb < 8; kb++) {
      a0 = mfma16(xa[kb], *(const s16x8*)(wb1 + (size_t)(kb * 2 + 0) * 512), a0);
      a1 = mfma16(xa[kb], *(const s16x8*)(wb1 + (size_t)(kb * 2 + 1) * 512), a1);
    }
    waitld();
#pragma unroll
    for (int kb = 0; kb < 16; kb++) {
      a0 = mfma16(hh[kb], *(const s16x8*)(wb1 + (size_t)((kb + 8) * 2 + 0) * 512), a0);
      a1 = mfma16(hh[kb], *(const s16x8*)(wb1 + (size_t)((kb + 8) * 2 + 1) * 512), a1);
    }
#pragma unroll
    for (int i = 0; i < 4; i++) {
      D1[(rb + q * 4 + i) * 33 + r]      = a0[i];
      D1[(rb + q * 4 + i) * 33 + 16 + r] = a1[i];
    }
  }
  const float* bs = (const float*)(smem + OFF_B1);
  float* Cs = (float*)(smem + OFF_C);
  int t2 = tid - 128;
  int row = t2 >> 1, j0 = (t2 & 1) * 4;
  union { u16 h[4]; u64 qv; } pk;
#pragma unroll
  for (int i = 0; i < 4; i++) {
    int j = j0 + i;
    float vi = D1[row * 33 + 0 + j]  + bs[0 + j];
    float vf = D1[row * 33 + 8 + j]  + bs[8 + j];
    float vo = D1[row * 33 + 16 + j] + bs[16 + j];
    float vc = D1[row * 33 + 24 + j] + bs[24 + j];
    float I = sigm(vi), F = sigm(vf), O = sigm(vo), Ct = tanh_(vc);
    float Cn = F * Cs[row * 8 + j] + I * Ct;
    Cs[row * 8 + j] = Cn;
    pk.h[i] = f2bf(O * tanh_(Cn));
  }
  st8_llc(Hdst + (size_t)(g * 64 + row) * HID_ + c * 8 + j0, pk.qv);
}

// mix part 1: acc = H(t+1) @ W_xh  (waves 0-1 only)
__device__ __forceinline__ f32x4 mix_part1(char* smem, const u16* Hnew, int g, int c,
                                           int w, int lane) {
  const int r = lane & 15, q = lane >> 4;
  int rbase = g * 64 + (c & 1) * 32 + w * 16 + r;
  const u16* h0 = Hnew + (size_t)rbase * HID_;
  const u16* wb = (const u16*)(smem + OFF_W2) + lane * 8;
  s16x8 ha[16];
  ld_h16(ha, h0 + q * 8);
  waitld();
  f32x4 acc = {0.f, 0.f, 0.f, 0.f};
#pragma unroll
  for (int kb = 0; kb < 16; kb++)
    acc = mfma16(ha[kb], *(const s16x8*)(wb + (size_t)kb * 512), acc);
  return acc;
}

// mix part 2: acc += H1(t) @ W_hh; sigmoid; store H1m (per-wave LDS transpose).
__device__ __forceinline__ void mix_part2(char* smem, f32x4 acc, const u16* H1old,
                                          u16* H1m, int g, int c, int w, int lane) {
  const int r = lane & 15, q = lane >> 4;
  int rbase = g * 64 + (c & 1) * 32 + w * 16 + r;
  const u16* h1 = H1old + (size_t)rbase * HID_;
  const u16* wb = (const u16*)(smem + OFF_W2) + lane * 8;
  s16x8 hb[16];
  ld_h16(hb, h1 + q * 8);
  waitld();
#pragma unroll
  for (int kb = 0; kb < 16; kb++)
    acc = mfma16(hb[kb], *(const s16x8*)(wb + (size_t)(16 + kb) * 512), acc);
  float* Dm = (float*)(smem + OFF_DSM) + (size_t)w * 16 * 17;
#pragma unroll
  for (int i = 0; i < 4; i++) Dm[(q * 4 + i) * 17 + r] = acc[i];
  const float* b2 = (const float*)(smem + OFF_B2);
  int row2 = lane >> 2, j0 = (lane & 3) * 4;
  union { u16 h[4]; u64 qv; } pk;
#pragma unroll
  for (int i = 0; i < 4; i++)
    pk.h[i] = f2bf(sigm(Dm[row2 * 17 + j0 + i] + b2[j0 + i]));
  st8_llc(H1m + (size_t)(g * 64 + (c & 1) * 32 + w * 16 + row2) * HID_ + (c >> 1) * 16 + j0,
          pk.qv);
}

__global__ __launch_bounds__(NTHR, 1) void lstm_pers(Params p) {
  extern __shared__ char smem[];
  const int tid = threadIdx.x;
  const int bi = blockIdx.x;
  const int w = tid >> 6, lane = tid & 63;
  const int g = bi >> 6, c = bi & 63;
  const int r = lane & 15, q = lane >> 4;

  int* fl = (int*)(p.ws + WS_FL) + g * 64 * 32;   // padded: one line per WG
  int* dn = (int*)(p.ws + WS_DONE);
  u16* Hb0 = (u16*)(p.ws + WS_HB0);
  u16* Hb1 = (u16*)(p.ws + WS_HB1);
  u16* H1b = (u16*)(p.ws + WS_H1);
  u16* H1m = (u16*)(p.ws + WS_HM);
  u16* Xe  = (u16*)(p.ws + WS_XE);

  // ---- CRITICAL: zero the group's 24 event counters (ws is POISONED).
  // Published by groupbar_heavy (zero-store is program-order before the
  // release flag; every WG acquire-fences after seeing all 64 flags).
  if (tid == 0 && c < 24)
    __hip_atomic_store(&fl[c * 32 + 16], 0, __ATOMIC_RELAXED, AGENT);

  // ---- one-time init: weights -> LDS (bf16, MFMA lane-order swizzle) ----
  {
    u16* w1 = (u16*)(smem + OFF_W1);
    u16* w3 = (u16*)(smem + OFF_W3);
    int gate = tid >> 6, kk8 = (tid >> 3) & 7, j = tid & 7;
    int cc = gate * 8 + j;
    int n = cc >> 4, rr = cc & 15;
    int hid = c * 8 + j;
    for (int kk = kk8; kk < 768; kk += 8) {
      int kb = kk >> 5, q2 = (kk >> 3) & 3, e = kk & 7;
      size_t dst = ((size_t)(kb * 2 + n) * 64 + q2 * 16 + rr) * 8 + e;
      float s1 = (kk < 256) ? p.Wx[gate][(size_t)kk * HID_ + hid]
                            : p.Wh[gate][(size_t)(kk - 256) * HID_ + hid];
      float s3 = (kk < 256) ? p.Wx1[gate][(size_t)kk * HID_ + hid]
                            : p.Wh1[gate][(size_t)(kk - 256) * HID_ + hid];
      w1[dst] = f2bf(s1);
      w3[dst] = f2bf(s3);
    }
    {  // mix weights: every WG holds cols (c>>1)*16..+15 (pairs share)
      u16* w2 = (u16*)(smem + OFF_W2);
      int kk16 = tid >> 4, j2 = tid & 15;
      int hid2 = (c >> 1) * 16 + j2;
      for (int kk = kk16; kk < 1024; kk += 16) {
        int kb = kk >> 5, q2 = (kk >> 3) & 3, e = kk & 7;
        size_t dst = ((size_t)kb * 64 + q2 * 16 + j2) * 8 + e;
        float s = (kk < 512) ? p.Wxh[(size_t)kk * HID_ + hid2]
                             : p.Whh[(size_t)(kk - 512) * HID_ + hid2];
        w2[dst] = f2bf(s);
      }
      if (tid < 16) ((float*)(smem + OFF_B2))[tid] = p.bh[(c >> 1) * 16 + tid];
    }
    if (tid < 32) {
      int gt = tid >> 3, jj = tid & 7;
      ((float*)(smem + OFF_B1))[tid] = p.bg[gt][c * 8 + jj];
      ((float*)(smem + OFF_B3))[tid] = p.bg1[gt][c * 8 + jj];
    }
    float* Cs = (float*)(smem + OFF_C);
    float* C1s = (float*)(smem + OFF_C1);
    for (int it = 0; it < 2; it++) {
      int idx = tid + it * 256;
      int row = idx >> 3, j8 = idx & 7;
      float v = p.Cin[(size_t)(g * 64 + row) * HID_ + c * 8 + j8];
      Cs[row * 8 + j8] = v;
      C1s[row * 8 + j8] = v;
    }
  }
  // H / H1 init (bf16, normal stores -> published by heavy barrier).
  // Convention: H(t) lives in Hb[t&1]; H(-1)=Hin in Hb1.
  for (int it = 0; it < 2; it++) {
    int idx = bi * 512 + tid + it * 256;
    u16 hv = f2bf(p.Hin[idx]);
    Hb1[idx] = hv;
    H1b[idx] = hv;
  }
  // Embedding gather: WG (g,c) fills Xe[t=4c..4c+3][g*64..+63][:]
  for (int tt = 0; tt < 4; tt++) {
    int t0 = c * 4 + tt;
    for (int pp = 0; pp < 16; pp++) {
      int b = g * 64 + w * 16 + pp;
      int tok = p.X[(size_t)b * Tt + t0];
      const float4* er = (const float4*)(p.E + (size_t)tok * EMB_);
      float4 v = er[lane];
      u16x4 u; u.x = f2bf(v.x); u.y = f2bf(v.y); u.z = f2bf(v.z); u.w = f2bf(v.w);
      *(u16x4*)(Xe + ((size_t)t0 * Bb + b) * EMB_ + lane * 4) = u;
    }
  }
  groupbar_heavy(fl, c, 1);   // publish init data + counter zeros

  // Event bookkeeping (per line):
  //  C events: cell1(0)=ev1 [P0], cell1(1)=ev2 [P1], cell1(t+2)=ev t+3 [B_t]
  //  M events: mix(0)=ev1 [P1], mix(t+1)=ev t+2 [B_t]
  //  A events: cell2(t)=ev t+1 [A_t], t=0..Tt-2 (epilogue doesn't arrive)

  // ---- P0: cell1(0): Hb1 -> Hb0 ----
  cell_phase(smem, OFF_W1, OFF_B1, OFF_C, Xe, Hb1, Hb0, g, c, w, lane, tid);
  if (w < 2) arrive_wave(fl, LC, c);          // C ev1 (stores were by waves 0-1)

  // ---- P1: mix(0) [w 0-1] + cell1(1) [w 2-3]; no syncthreads ----
  wait_wave(fl, LC, 1 * 16);                  // cell1(0) done everywhere
  if (w < 2) {
    f32x4 macc = mix_part1(smem, Hb0, g, c, w, lane);
    mix_part2(smem, macc, H1b, H1m, g, c, w, lane);
    arrive_wave(fl, LM, c);                   // M ev1
  } else {
    cell1_w23(smem, Xe + (size_t)1 * Bb * EMB_, Hb0, Hb1, g, c, lane, tid);
    arrive_wave(fl, LC, c);                   // C ev2
  }

  // ---- steady state ----
  for (int t = 0; t < Tt - 1; t++) {
    const u16* Xt = Xe + (size_t)t * Bb * EMB_;
    // ---------- A_t: cell2(t) -- waits ONLY on mix(t) ----------
    {
      const u16* wb3 = (const u16*)(smem + OFF_W3) + lane * 8;
      const u16* xrow = Xt + (size_t)(g * 64 + w * 16 + r) * EMB_;
      f32x4 acc0 = {0.f, 0.f, 0.f, 0.f}, acc1 = {0.f, 0.f, 0.f, 0.f};
      s16x8 xa[8];
#pragma unroll
      for (int kb = 0; kb < 8; kb++) xa[kb] = *(const s16x8*)(xrow + kb * 32 + q * 8);
#pragma unroll
      for (int kb = 0; kb < 8; kb++) {        // x-part pre-wait
        acc0 = mfma16(xa[kb], *(const s16x8*)(wb3 + (size_t)(kb * 2 + 0) * 512), acc0);
        acc1 = mfma16(xa[kb], *(const s16x8*)(wb3 + (size_t)(kb * 2 + 1) * 512), acc1);
      }
      wait_wave(fl, LM, (t + 1) * 16);        // mix(t) done (RAW H1m, WAR H1b)
      __syncthreads();                        // converge WG for Ds usage
      const u16* hrow = H1m + (size_t)(g * 64 + w * 16 + r) * HID_;
      s16x8 ha[16];
      ld_h16(ha, hrow + q * 8);
      waitld();
#pragma unroll
      for (int kb = 0; kb < 16; kb++) {
        acc0 = mfma16(ha[kb], *(const s16x8*)(wb3 + (size_t)((kb + 8) * 2 + 0) * 512), acc0);
        acc1 = mfma16(ha[kb], *(const s16x8*)(wb3 + (size_t)((kb + 8) * 2 + 1) * 512), acc1);
      }
      float* Ds = (float*)(smem + OFF_DS);
#pragma unroll
      for (int i = 0; i < 4; i++) {
        Ds[(w * 16 + q * 4 + i) * 33 + r]      = acc0[i];
        Ds[(w * 16 + q * 4 + i) * 33 + 16 + r] = acc1[i];
      }
      __syncthreads();
      if (tid < 128) {
        const float* bs = (const float*)(smem + OFF_B3);
        float* Cs = (float*)(smem + OFF_C1);
        int row = tid >> 1, j0 = (tid & 1) * 4;
        union { u16 h[4]; u64 qv; } pk;
#pragma unroll
        for (int i = 0; i < 4; i++) {
          int j = j0 + i;
          float vi = Ds[row * 33 + 0 + j]  + bs[0 + j];
          float vf = Ds[row * 33 + 8 + j]  + bs[8 + j];
          float vo = Ds[row * 33 + 16 + j] + bs[16 + j];
          float vc = Ds[row * 33 + 24 + j] + bs[24 + j];
          float I = sigm(vi), F = sigm(vf), O = sigm(vo), Ct = tanh_(vc);
          float Cn = F * Cs[row * 8 + j] + I * Ct;
          Cs[row * 8 + j] = Cn;
          pk.h[i] = f2bf(O * tanh_(Cn));
        }
        st8_llc(H1b + (size_t)(g * 64 + row) * HID_ + c * 8 + j0, pk.qv);
      }
      arrive_all(fl, LA, c);                  // A ev t+1
    }
    // ---------- B_t: mix(t+1) [w 0-1] + cell1(t+2) [w 2-3]; NO syncthreads ----------
    {
      const u16* Hnew = (t & 1) ? Hb0 : Hb1;  // H(t+1)
      u16* Hdst1      = (t & 1) ? Hb1 : Hb0;  // H(t+2)
      wait_wave(fl, LC, (t + 2) * 16);        // cell1(t+1) done (RAW H, WAR H)
      if (w < 2) {
        f32x4 macc = mix_part1(smem, Hnew, g, c, w, lane);
        wait_wave(fl, LA, (t + 1) * 8);       // cell2(t) done (RAW H1, WAR H1m)
        mix_part2(smem, macc, H1b, H1m, g, c, w, lane);
        arrive_wave(fl, LM, c);               // M ev t+2
      } else if (t + 2 < Tt) {
        cell1_w23(smem, Xe + (size_t)(t + 2) * Bb * EMB_, Hnew, Hdst1, g, c, lane, tid);
        arrive_wave(fl, LC, c);               // C ev t+3
      }
    }
  }

  // ---- epilogue: cell2(255) ----
  {
    const u16* Xt = Xe + (size_t)(Tt - 1) * Bb * EMB_;
    const u16* wb3 = (const u16*)(smem + OFF_W3) + lane * 8;
    const u16* xrow = Xt + (size_t)(g * 64 + w * 16 + r) * EMB_;
    f32x4 acc0 = {0.f, 0.f, 0.f, 0.f}, acc1 = {0.f, 0.f, 0.f, 0.f};
    s16x8 xa[8];
#pragma unroll
    for (int kb = 0; kb < 8; kb++) xa[kb] = *(const s16x8*)(xrow + kb * 32 + q * 8);
#pragma unroll
    for (int kb = 0; kb < 8; kb++) {
      acc0 = mfma16(xa[kb], *(const s16x8*)(wb3 + (size_t)(kb * 2 + 0) * 512), acc0);
      acc1 = mfma16(xa[kb], *(const s16x8*)(wb3 + (size_t)(kb * 2 + 1) * 512), acc1);
    }
    wait_wave(fl, LM, Tt * 16);               // mix(255) done
    __syncthreads();
    const u16* hrow = H1m + (size_t)(g * 64 + w * 16 + r) * HID_;
    s16x8 ha[16];
    ld_h16(ha, hrow + q * 8);
    waitld();
#pragma unroll
    for (int kb = 0; kb < 16; kb++) {
      acc0 = mfma16(ha[kb], *(const s16x8*)(wb3 + (size_t)((kb + 8) * 2 + 0) * 512), acc0);
      acc1 = mfma16(ha[kb], *(const s16x8*)(wb3 + (size_t)((kb + 8) * 2 + 1) * 512), acc1);
    }
    float* Ds = (float*)(smem + OFF_DS);
#pragma unroll
    for (int i = 0; i < 4; i++) {
      Ds[(w * 16 + q * 4 + i) * 33 + r]      = acc0[i];
      Ds[(w * 16 + q * 4 + i) * 33 + 16 + r] = acc1[i];
    }
    __syncthreads();
    if (tid < 128) {
      const float* bs = (const float*)(smem + OFF_B3);
      float* Cs = (float*)(smem + OFF_C1);
      int row = tid >> 1, j0 = (tid & 1) * 4;
      union { u16 h[4]; u64 qv; } pk;
#pragma unroll
      for (int i = 0; i < 4; i++) {
        int j = j0 + i;
        float vi = Ds[row * 33 + 0 + j]  + bs[0 + j];
        float vf = Ds[row * 33 + 8 + j]  + bs[8 + j];
        float vo = Ds[row * 33 + 16 + j] + bs[16 + j];
        float vc = Ds[row * 33 + 24 + j] + bs[24 + j];
        float I = sigm(vi), F = sigm(vf), O = sigm(vo), Ct = tanh_(vc);
        float Cn = F * Cs[row * 8 + j] + I * Ct;
        Cs[row * 8 + j] = Cn;
        pk.h[i] = f2bf(O * tanh_(Cn));
      }
      st8_llc(H1b + (size_t)(g * 64 + row) * HID_ + c * 8 + j0, pk.qv);
    }
  }

  // ---- all-groups done, then final GEMM with cached loads ----
  donebar(dn, bi);
  if (bi < 250) {
    const int n0 = bi * 128;
    u16* Wf = (u16*)smem;   // reuse weight LDS: [16 kb][8 nt][64 lane][8]
    for (int idx = tid; idx < 512 * 128; idx += NTHR) {
      int k = idx >> 7, nn2 = idx & 127;
      int nt = nn2 >> 4, rr = nn2 & 15;
      int kb = k >> 5, q2 = (k >> 3) & 3, e = k & 7;
      Wf[((size_t)(kb * 8 + nt) * 64 + q2 * 16 + rr) * 8 + e] =
          f2bf(p.Whq[(size_t)k * NCLS + n0 + nn2]);
    }
    float* bqs = (float*)(smem + OFF_C);
    if (tid < 128) bqs[tid] = p.bq[n0 + tid];
    __syncthreads();
    const int r2 = lane & 15, q2 = lane >> 4;
    for (int mt = 0; mt < 4; mt++) {
      int rowb = mt * 64 + w * 16;
      const u16* arow = H1b + (size_t)(rowb + r2) * HID_;
      f32x4 acc[8];
#pragma unroll
      for (int nt = 0; nt < 8; nt++) acc[nt] = (f32x4){0.f, 0.f, 0.f, 0.f};
      for (int kb = 0; kb < 16; kb++) {
        s16x8 a = *(const s16x8*)(arow + kb * 32 + q2 * 8);
#pragma unroll
        for (int nt = 0; nt < 8; nt++) {
          s16x8 b = *(const s16x8*)((const u16*)Wf + ((size_t)(kb * 8 + nt) * 64 + lane) * 8);
          acc[nt] = mfma16(a, b, acc[nt]);
        }
      }
#pragma unroll
      for (int nt = 0; nt < 8; nt++)
#pragma unroll
        for (int i = 0; i < 4; i++)
          p.out[(size_t)(rowb + q2 * 4 + i) * NCLS + n0 + nt * 16 + r2] =
              acc[nt][i] + bqs[nt * 16 + r2];
    }
  }
}

extern "C" void kernel_launch(void* const* d_in, const int* in_sizes, int n_in,
                              void* d_out, int out_size, void* d_ws, size_t ws_size,
                              hipStream_t stream) {
  (void)in_sizes; (void)n_in; (void)out_size; (void)ws_size;
  Params p;
  p.X   = (const int*)d_in[0];
  p.Hin = (const float*)d_in[1];
  p.Cin = (const float*)d_in[2];
  p.E   = (const float*)d_in[3];
  for (int gidx = 0; gidx < 4; gidx++) {   // gate order i,f,o,c
    int base = 4 + gidx * 6;
    p.Wx[gidx]  = (const float*)d_in[base + 0];
    p.Wh[gidx]  = (const float*)d_in[base + 1];
    p.bg[gidx]  = (const float*)d_in[base + 2];
    p.Wx1[gidx] = (const float*)d_in[base + 3];
    p.Wh1[gidx] = (const float*)d_in[base + 4];
    p.bg1[gidx] = (const float*)d_in[base + 5];
  }
  p.Wxh = (const float*)d_in[28];
  p.Whh = (const float*)d_in[29];
  p.bh  = (const float*)d_in[30];
  p.Whq = (const float*)d_in[31];
  p.bq  = (const float*)d_in[32];
  p.out = (float*)d_out;
  p.ws  = (char*)d_ws;

  hipFuncSetAttribute(reinterpret_cast<const void*>(lstm_pers),
                      hipFuncAttributeMaxDynamicSharedMemorySize, SMEM_BYTES);
  lstm_pers<<<dim3(NWG), dim3(NTHR), SMEM_BYTES, stream>>>(p);
}

// Round 9
// 3399.290 us; speedup vs baseline: 1.1662x; 1.1662x over previous
//
#include <hip/hip_runtime.h>
#include <cstdint>
#include <cstddef>

typedef unsigned short u16;
typedef unsigned long long u64;
typedef __attribute__((ext_vector_type(8))) short s16x8;
typedef __attribute__((ext_vector_type(4))) float f32x4;
typedef __attribute__((ext_vector_type(4))) unsigned short u16x4;

#define AGENT __HIP_MEMORY_SCOPE_AGENT

namespace {
constexpr int NWG  = 256;
constexpr int NTHR = 256;
constexpr int Bb   = 256;   // batch
constexpr int Tt   = 256;   // timesteps
constexpr int EMB_ = 256;
constexpr int HID_ = 512;
constexpr int NCLS = 32000;

// ---- LDS layout (bytes). B-operands stored in MFMA lane order.
constexpr int OFF_W1  = 0;        // cell1 [24 kb][2 n][64 lane][8] = 49152 B
constexpr int OFF_W3  = 49152;    // cell2, same shape
constexpr int OFF_W2  = 98304;    // mix   [32 kb][1 n][64][8]     = 32768 B
constexpr int OFF_DS  = 131072;   // cell2 gate scratch [64][33] f32 = 8448 B
constexpr int OFF_DS1 = 139520;   // cell1 gate scratch [64][33] f32 = 8448 B
constexpr int OFF_DSM = 147968;   // mix per-wave transpose 2 x [16][17] f32 = 2176 B
constexpr int OFF_C   = 150144;   // cell1 C state [64][8] f32 (bq reuse in final)
constexpr int OFF_C1  = 152192;   // cell2 C state
constexpr int OFF_B1  = 154240;
constexpr int OFF_B3  = 154368;
constexpr int OFF_B2  = 154496;
constexpr int SMEM_BYTES = 154560;            // 1 WG/CU

// ---- workspace layout (bytes) ----
// fl lines: 256 x 128B. dword +0: heavy-barrier flag (init only; store-then-
// compare -> poison-immune). dword +16 (byte +64, separate sector) of lines
// (g*64 + 0..7): monotonic phase counters -- 8 sub-counters per group, 8 WGs
// each, +8 per phase. RMW on workspace -> MUST be explicitly zeroed in init
// (harness POISONS the workspace; un-zeroed counters deadlock, rounds 3/6).
constexpr size_t WS_FL   = 0;                          // 256 WGs x 128 B = 32 KB
constexpr size_t WS_DONE = 32768;                      // 256 int done flags (one-time)
constexpr size_t WS_HB0  = 33792;                      // H parity buffers [B][512] bf16
constexpr size_t WS_HB1  = WS_HB0 + (size_t)Bb * HID_ * 2;
constexpr size_t WS_H1   = WS_HB1 + (size_t)Bb * HID_ * 2;   // H1 state
constexpr size_t WS_HM   = WS_H1 + (size_t)Bb * HID_ * 2;    // H1mix
constexpr size_t WS_XE   = WS_HM + (size_t)Bb * HID_ * 2;    // Xe [T][B][EMB] bf16
}  // namespace

struct Params {
  const int* X; const float* Hin; const float* Cin; const float* E;
  const float* Wx[4];  const float* Wh[4];  const float* bg[4];   // cell 1 (i,f,o,c)
  const float* Wx1[4]; const float* Wh1[4]; const float* bg1[4];  // cell 2
  const float* Wxh; const float* Whh; const float* bh;
  const float* Whq; const float* bq;
  float* out; char* ws;
};

__device__ __forceinline__ u16 f2bf(float f) {
  union { float f; unsigned u; } v; v.f = f;
  unsigned r = v.u + 0x7FFFu + ((v.u >> 16) & 1u);
  return (u16)(r >> 16);
}
__device__ __forceinline__ float sigm(float x) { return 1.f / (1.f + __expf(-x)); }
__device__ __forceinline__ float tanh_(float x) {
  x = fminf(fmaxf(x, -10.f), 10.f);
  float e = __expf(-2.f * x);
  return (1.f - e) / (1.f + e);
}
__device__ __forceinline__ f32x4 mfma16(s16x8 a, s16x8 b, f32x4 c) {
  return __builtin_amdgcn_mfma_f32_16x16x32_bf16(a, b, c, 0, 0, 0);
}

// ---- producer side: LLC-coherent bypass stores (relaxed agent atomics).
__device__ __forceinline__ void st8_llc(u16* p2, u64 v) {
  __hip_atomic_store((u64*)p2, v, __ATOMIC_RELAXED, AGENT);
}

// ---- consumer side: 16B LLC-coherent bypass loads (sc0 sc1 bypass L1/L2).
// Full-line coalescing: 4 lanes x 16B = one 64B fabric txn (round-5 proven).
#define LD16A(d, b, off)                                                      \
  asm volatile("global_load_dwordx4 %0, %1, off offset:" #off " sc0 sc1"      \
               : "=&v"(d) : "v"(b) : "memory")

__device__ __forceinline__ void ld_h16(s16x8* d, const u16* b) {
  LD16A(d[0],  b, 0);   LD16A(d[1],  b, 64);  LD16A(d[2],  b, 128);
  LD16A(d[3],  b, 192); LD16A(d[4],  b, 256); LD16A(d[5],  b, 320);
  LD16A(d[6],  b, 384); LD16A(d[7],  b, 448); LD16A(d[8],  b, 512);
  LD16A(d[9],  b, 576); LD16A(d[10], b, 640); LD16A(d[11], b, 704);
  LD16A(d[12], b, 768); LD16A(d[13], b, 832); LD16A(d[14], b, 896);
  LD16A(d[15], b, 960);
}
// half-burst variants: spread the slack-path LLC demand over the phase so the
// group's lockstep post-barrier burst doesn't queue against critical loads.
__device__ __forceinline__ void ld_h8a(s16x8* d, const u16* b) {
  LD16A(d[0], b, 0);   LD16A(d[1], b, 64);  LD16A(d[2], b, 128);
  LD16A(d[3], b, 192); LD16A(d[4], b, 256); LD16A(d[5], b, 320);
  LD16A(d[6], b, 384); LD16A(d[7], b, 448);
}
__device__ __forceinline__ void ld_h8b(s16x8* d, const u16* b) {
  LD16A(d[8],  b, 512); LD16A(d[9],  b, 576); LD16A(d[10], b, 640);
  LD16A(d[11], b, 704); LD16A(d[12], b, 768); LD16A(d[13], b, 832);
  LD16A(d[14], b, 896); LD16A(d[15], b, 960);
}
// Full drain; sched_barrier stops MFMAs hoisting above (rule #18).
__device__ __forceinline__ void waitld() {
  asm volatile("s_waitcnt vmcnt(0)" ::: "memory");
  __builtin_amdgcn_sched_barrier(0);
}
// Partial drain for chunked consumption on the CRITICAL paths: consume 4
// loads while 12/8/4 remain in flight. sched_barrier pins both the MFMAs
// (no hoist above the waitcnt) and any compiler vmem (out of the counted
// region) -- between chunks only MFMAs + DS reads occur (lgkmcnt domain).
#define WAITLDN(n) do {                                                       \
  asm volatile("s_waitcnt vmcnt(" #n ")" ::: "memory");                       \
  __builtin_amdgcn_sched_barrier(0); } while (0)

// ---- counter barrier (steady state): arrive = one atomicAdd to sub-counter
// (c&7); wait = 8 lanes poll 8 lines until all == 8*ph. Monotonic, zeroed in
// init. __syncthreads drains vmcnt so all sc1 data stores are LLC-acked
// before the add -> data visible before the count.
__device__ __forceinline__ void arrive_cnt(int* fl, int c) {
  __syncthreads();
  if (threadIdx.x == 0)
    (void)__hip_atomic_fetch_add(&fl[(c & 7) * 32 + 16], 1, __ATOMIC_RELAXED, AGENT);
}
__device__ __forceinline__ void wait_cnt(int* fl, int ph) {
  const int tgt = ph * 8;
  if (threadIdx.x < 8) {
    for (;;) {
      int v = __hip_atomic_load(&fl[threadIdx.x * 32 + 16], __ATOMIC_RELAXED, AGENT);
      if (!__any(v < tgt)) break;
      __builtin_amdgcn_s_sleep(1);
    }
  }
  __syncthreads();
  __builtin_amdgcn_fence(__ATOMIC_ACQUIRE, "workgroup");  // compiler/order barrier, cheap
}

// Heavy barrier (release store + agent acquire fence). Used ONCE after init
// (publishes normal-stored Xe/H-init AND the counter zero-stores).
__device__ __forceinline__ void groupbar_heavy(int* fl, int slot, int ph) {
  __syncthreads();
  if (threadIdx.x == 0)
    __hip_atomic_store(&fl[slot * 32], ph, __ATOMIC_RELEASE, AGENT);
  if (threadIdx.x < 64) {
    for (;;) {
      int v = __hip_atomic_load(&fl[threadIdx.x * 32], __ATOMIC_RELAXED, AGENT);
      if (!__any(v < ph)) break;
      __builtin_amdgcn_s_sleep(1);
    }
  }
  __syncthreads();
  __builtin_amdgcn_fence(__ATOMIC_ACQUIRE, "agent");
}

// One-time all-grid done wait; heavy so the final GEMM can use cached loads.
__device__ __forceinline__ void donebar(int* dn, int bi) {
  __syncthreads();
  if (threadIdx.x == 0)
    __hip_atomic_store(&dn[bi], 1, __ATOMIC_RELEASE, AGENT);
  for (;;) {
    int v = __hip_atomic_load(&dn[threadIdx.x], __ATOMIC_RELAXED, AGENT);
    if (!__any(v < 1)) break;
    __builtin_amdgcn_s_sleep(1);
  }
  __syncthreads();
  __builtin_amdgcn_fence(__ATOMIC_ACQUIRE, "agent");
}

// Prologue cell1(0): 4 waves, full syncthreads handoff (runs once).
__device__ __forceinline__ void cell_phase(char* smem, int offW, int offB, int offC,
                                           const u16* Xt, const u16* Hrec, u16* Hdst,
                                           int g, int c, int w, int lane, int tid) {
  const int r = lane & 15, q = lane >> 4;
  const int row0 = w * 16;
  const u16* xrow = Xt + (size_t)(g * 64 + row0 + r) * EMB_;
  const u16* hrow = Hrec + (size_t)(g * 64 + row0 + r) * HID_;
  const u16* wb = (const u16*)(smem + offW) + lane * 8;
  f32x4 acc0 = {0.f, 0.f, 0.f, 0.f}, acc1 = {0.f, 0.f, 0.f, 0.f};
#pragma unroll
  for (int kb = 0; kb < 8; kb++) {
    s16x8 a  = *(const s16x8*)(xrow + kb * 32 + q * 8);
    s16x8 b0 = *(const s16x8*)(wb + (size_t)(kb * 2 + 0) * 512);
    s16x8 b1 = *(const s16x8*)(wb + (size_t)(kb * 2 + 1) * 512);
    acc0 = mfma16(a, b0, acc0);
    acc1 = mfma16(a, b1, acc1);
  }
  s16x8 ha[16];
  ld_h16(ha, hrow + q * 8);
  waitld();
#pragma unroll
  for (int kb = 0; kb < 16; kb++) {
    s16x8 b0 = *(const s16x8*)(wb + (size_t)((kb + 8) * 2 + 0) * 512);
    s16x8 b1 = *(const s16x8*)(wb + (size_t)((kb + 8) * 2 + 1) * 512);
    acc0 = mfma16(ha[kb], b0, acc0);
    acc1 = mfma16(ha[kb], b1, acc1);
  }
  float* Ds = (float*)(smem + OFF_DS);
#pragma unroll
  for (int i = 0; i < 4; i++) {
    Ds[(row0 + q * 4 + i) * 33 + r]      = acc0[i];
    Ds[(row0 + q * 4 + i) * 33 + 16 + r] = acc1[i];
  }
  __syncthreads();
  const float* bs = (const float*)(smem + offB);
  float* Cs = (float*)(smem + offC);
  if (tid < 128) {
    int row = tid >> 1, j0 = (tid & 1) * 4;
    union { u16 h[4]; u64 qv; } pk;
#pragma unroll
    for (int i = 0; i < 4; i++) {
      int j = j0 + i;
      float vi = Ds[row * 33 + 0 + j]  + bs[0 + j];
      float vf = Ds[row * 33 + 8 + j]  + bs[8 + j];
      float vo = Ds[row * 33 + 16 + j] + bs[16 + j];
      float vc = Ds[row * 33 + 24 + j] + bs[24 + j];
      float I = sigm(vi), F = sigm(vf), O = sigm(vo), Ct = tanh_(vc);
      float Cn = F * Cs[row * 8 + j] + I * Ct;
      Cs[row * 8 + j] = Cn;
      pk.h[i] = f2bf(O * tanh_(Cn));
    }
    st8_llc(Hdst + (size_t)(g * 64 + row) * HID_ + c * 8 + j0, pk.qv);
  }
}

// cell1 on waves 2-3 (slack path): half-bursts spread its LLC demand.
__device__ __forceinline__ void cell1_w23(char* smem, const u16* Xt, const u16* Hrec,
                                          u16* Hdst, int g, int c, int lane, int tid) {
  const int wv = (tid >> 6) - 2;
  const int r = lane & 15, q = lane >> 4;
  const u16* wb1 = (const u16*)(smem + OFF_W1) + lane * 8;
  float* D1 = (float*)(smem + OFF_DS1);
#pragma unroll
  for (int blk = 0; blk < 2; blk++) {
    const int rb = wv * 32 + blk * 16;
    const u16* xrow = Xt + (size_t)(g * 64 + rb + r) * EMB_;
    const u16* hrow = Hrec + (size_t)(g * 64 + rb + r) * HID_;
    s16x8 xa[8];
#pragma unroll
    for (int kb = 0; kb < 8; kb++) xa[kb] = *(const s16x8*)(xrow + kb * 32 + q * 8);
    s16x8 hh[16];
    ld_h8a(hh, hrow + q * 8);
    f32x4 a0 = {0.f, 0.f, 0.f, 0.f}, a1 = {0.f, 0.f, 0.f, 0.f};
#pragma unroll
    for (int kb = 0; kb < 8; kb++) {
      a0 = mfma16(xa[kb], *(const s16x8*)(wb1 + (size_t)(kb * 2 + 0) * 512), a0);
      a1 = mfma16(xa[kb], *(const s16x8*)(wb1 + (size_t)(kb * 2 + 1) * 512), a1);
    }
    waitld();
#pragma unroll
    for (int kb = 0; kb < 8; kb++) {
      a0 = mfma16(hh[kb], *(const s16x8*)(wb1 + (size_t)((kb + 8) * 2 + 0) * 512), a0);
      a1 = mfma16(hh[kb], *(const s16x8*)(wb1 + (size_t)((kb + 8) * 2 + 1) * 512), a1);
    }
    ld_h8b(hh, hrow + q * 8);
    waitld();
#pragma unroll
    for (int kb = 8; kb < 16; kb++) {
      a0 = mfma16(hh[kb], *(const s16x8*)(wb1 + (size_t)((kb + 8) * 2 + 0) * 512), a0);
      a1 = mfma16(hh[kb], *(const s16x8*)(wb1 + (size_t)((kb + 8) * 2 + 1) * 512), a1);
    }
#pragma unroll
    for (int i = 0; i < 4; i++) {
      D1[(rb + q * 4 + i) * 33 + r]      = a0[i];
      D1[(rb + q * 4 + i) * 33 + 16 + r] = a1[i];
    }
  }
  const float* bs = (const float*)(smem + OFF_B1);
  float* Cs = (float*)(smem + OFF_C);
  int t2 = tid - 128;
  int row = t2 >> 1, j0 = (t2 & 1) * 4;
  union { u16 h[4]; u64 qv; } pk;
#pragma unroll
  for (int i = 0; i < 4; i++) {
    int j = j0 + i;
    float vi = D1[row * 33 + 0 + j]  + bs[0 + j];
    float vf = D1[row * 33 + 8 + j]  + bs[8 + j];
    float vo = D1[row * 33 + 16 + j] + bs[16 + j];
    float vc = D1[row * 33 + 24 + j] + bs[24 + j];
    float I = sigm(vi), F = sigm(vf), O = sigm(vo), Ct = tanh_(vc);
    float Cn = F * Cs[row * 8 + j] + I * Ct;
    Cs[row * 8 + j] = Cn;
    pk.h[i] = f2bf(O * tanh_(Cn));
  }
  st8_llc(Hdst + (size_t)(g * 64 + row) * HID_ + c * 8 + j0, pk.qv);
}

// mix part 1 (slack path, waves 0-1): half-bursts spread its demand.
__device__ __forceinline__ f32x4 mix_part1(char* smem, const u16* Hnew, int g, int c,
                                           int w, int lane) {
  const int r = lane & 15, q = lane >> 4;
  int rbase = g * 64 + (c & 1) * 32 + w * 16 + r;
  const u16* h0 = Hnew + (size_t)rbase * HID_;
  const u16* wb = (const u16*)(smem + OFF_W2) + lane * 8;
  s16x8 ha[16];
  f32x4 acc = {0.f, 0.f, 0.f, 0.f};
  ld_h8a(ha, h0 + q * 8);
  waitld();
#pragma unroll
  for (int kb = 0; kb < 8; kb++)
    acc = mfma16(ha[kb], *(const s16x8*)(wb + (size_t)kb * 512), acc);
  ld_h8b(ha, h0 + q * 8);
  waitld();
#pragma unroll
  for (int kb = 8; kb < 16; kb++)
    acc = mfma16(ha[kb], *(const s16x8*)(wb + (size_t)kb * 512), acc);
  return acc;
}

// mix part 2 (CRITICAL path): chunked partial-vmcnt consumption -- first MFMA
// starts one RTT earlier; queue drains under compute.
__device__ __forceinline__ void mix_part2(char* smem, f32x4 acc, const u16* H1old,
                                          u16* H1m, int g, int c, int w, int lane) {
  const int r = lane & 15, q = lane >> 4;
  int rbase = g * 64 + (c & 1) * 32 + w * 16 + r;
  const u16* h1 = H1old + (size_t)rbase * HID_;
  const u16* wb = (const u16*)(smem + OFF_W2) + lane * 8;
  s16x8 hb[16];
  ld_h16(hb, h1 + q * 8);
  __builtin_amdgcn_sched_barrier(0);
  WAITLDN(12);
#pragma unroll
  for (int kb = 0; kb < 4; kb++)
    acc = mfma16(hb[kb], *(const s16x8*)(wb + (size_t)(16 + kb) * 512), acc);
  WAITLDN(8);
#pragma unroll
  for (int kb = 4; kb < 8; kb++)
    acc = mfma16(hb[kb], *(const s16x8*)(wb + (size_t)(16 + kb) * 512), acc);
  WAITLDN(4);
#pragma unroll
  for (int kb = 8; kb < 12; kb++)
    acc = mfma16(hb[kb], *(const s16x8*)(wb + (size_t)(16 + kb) * 512), acc);
  WAITLDN(0);
#pragma unroll
  for (int kb = 12; kb < 16; kb++)
    acc = mfma16(hb[kb], *(const s16x8*)(wb + (size_t)(16 + kb) * 512), acc);
  float* Dm = (float*)(smem + OFF_DSM) + (size_t)w * 16 * 17;
#pragma unroll
  for (int i = 0; i < 4; i++) Dm[(q * 4 + i) * 17 + r] = acc[i];
  const float* b2 = (const float*)(smem + OFF_B2);
  int row2 = lane >> 2, j0 = (lane & 3) * 4;
  union { u16 h[4]; u64 qv; } pk;
#pragma unroll
  for (int i = 0; i < 4; i++)
    pk.h[i] = f2bf(sigm(Dm[row2 * 17 + j0 + i] + b2[j0 + i]));
  st8_llc(H1m + (size_t)(g * 64 + (c & 1) * 32 + w * 16 + row2) * HID_ + (c >> 1) * 16 + j0,
          pk.qv);
}

__global__ __launch_bounds__(NTHR, 1) void lstm_pers(Params p) {
  extern __shared__ char smem[];
  const int tid = threadIdx.x;
  const int bi = blockIdx.x;
  const int w = tid >> 6, lane = tid & 63;
  const int g = bi >> 6, c = bi & 63;
  const int r = lane & 15, q = lane >> 4;

  int* fl = (int*)(p.ws + WS_FL) + g * 64 * 32;   // padded: one line per WG
  int* dn = (int*)(p.ws + WS_DONE);
  u16* Hb0 = (u16*)(p.ws + WS_HB0);
  u16* Hb1 = (u16*)(p.ws + WS_HB1);
  u16* H1b = (u16*)(p.ws + WS_H1);
  u16* H1m = (u16*)(p.ws + WS_HM);
  u16* Xe  = (u16*)(p.ws + WS_XE);

  // ---- CRITICAL: zero this group's 8 phase counters (ws is POISONED).
  if (tid == 0 && c < 8)
    __hip_atomic_store(&fl[c * 32 + 16], 0, __ATOMIC_RELAXED, AGENT);

  // ---- one-time init: weights -> LDS (bf16, MFMA lane-order swizzle) ----
  {
    u16* w1 = (u16*)(smem + OFF_W1);
    u16* w3 = (u16*)(smem + OFF_W3);
    int gate = tid >> 6, kk8 = (tid >> 3) & 7, j = tid & 7;
    int cc = gate * 8 + j;
    int n = cc >> 4, rr = cc & 15;
    int hid = c * 8 + j;
    for (int kk = kk8; kk < 768; kk += 8) {
      int kb = kk >> 5, q2 = (kk >> 3) & 3, e = kk & 7;
      size_t dst = ((size_t)(kb * 2 + n) * 64 + q2 * 16 + rr) * 8 + e;
      float s1 = (kk < 256) ? p.Wx[gate][(size_t)kk * HID_ + hid]
                            : p.Wh[gate][(size_t)(kk - 256) * HID_ + hid];
      float s3 = (kk < 256) ? p.Wx1[gate][(size_t)kk * HID_ + hid]
                            : p.Wh1[gate][(size_t)(kk - 256) * HID_ + hid];
      w1[dst] = f2bf(s1);
      w3[dst] = f2bf(s3);
    }
    {  // mix weights: every WG holds cols (c>>1)*16..+15 (pairs share)
      u16* w2 = (u16*)(smem + OFF_W2);
      int kk16 = tid >> 4, j2 = tid & 15;
      int hid2 = (c >> 1) * 16 + j2;
      for (int kk = kk16; kk < 1024; kk += 16) {
        int kb = kk >> 5, q2 = (kk >> 3) & 3, e = kk & 7;
        size_t dst = ((size_t)kb * 64 + q2 * 16 + j2) * 8 + e;
        float s = (kk < 512) ? p.Wxh[(size_t)kk * HID_ + hid2]
                             : p.Whh[(size_t)(kk - 512) * HID_ + hid2];
        w2[dst] = f2bf(s);
      }
      if (tid < 16) ((float*)(smem + OFF_B2))[tid] = p.bh[(c >> 1) * 16 + tid];
    }
    if (tid < 32) {
      int gt = tid >> 3, jj = tid & 7;
      ((float*)(smem + OFF_B1))[tid] = p.bg[gt][c * 8 + jj];
      ((float*)(smem + OFF_B3))[tid] = p.bg1[gt][c * 8 + jj];
    }
    float* Cs = (float*)(smem + OFF_C);
    float* C1s = (float*)(smem + OFF_C1);
    for (int it = 0; it < 2; it++) {
      int idx = tid + it * 256;
      int row = idx >> 3, j8 = idx & 7;
      float v = p.Cin[(size_t)(g * 64 + row) * HID_ + c * 8 + j8];
      Cs[row * 8 + j8] = v;
      C1s[row * 8 + j8] = v;
    }
  }
  // H / H1 init (bf16, normal stores -> published by heavy barrier).
  // Convention: H(t) lives in Hb[t&1]; H(-1)=Hin in Hb1.
  for (int it = 0; it < 2; it++) {
    int idx = bi * 512 + tid + it * 256;
    u16 hv = f2bf(p.Hin[idx]);
    Hb1[idx] = hv;
    H1b[idx] = hv;
  }
  // Embedding gather: WG (g,c) fills Xe[t=4c..4c+3][g*64..+63][:]
  for (int tt = 0; tt < 4; tt++) {
    int t0 = c * 4 + tt;
    for (int pp = 0; pp < 16; pp++) {
      int b = g * 64 + w * 16 + pp;
      int tok = p.X[(size_t)b * Tt + t0];
      const float4* er = (const float4*)(p.E + (size_t)tok * EMB_);
      float4 v = er[lane];
      u16x4 u; u.x = f2bf(v.x); u.y = f2bf(v.y); u.z = f2bf(v.z); u.w = f2bf(v.w);
      *(u16x4*)(Xe + ((size_t)t0 * Bb + b) * EMB_ + lane * 4) = u;
    }
  }
  groupbar_heavy(fl, c, 1);   // publish init data + counter zeros

  int cph = 0;   // counted phases (counter barrier)

  // ---- P0: cell1(0): Hb1 -> Hb0 ----
  cell_phase(smem, OFF_W1, OFF_B1, OFF_C, Xe, Hb1, Hb0, g, c, w, lane, tid);
  arrive_cnt(fl, c); ++cph;      // cph=1

  // ---- P1: mix(0) [w 0-1] + cell1(1) [w 2-3] ----
  wait_cnt(fl, cph);
  if (w < 2) {
    f32x4 macc = mix_part1(smem, Hb0, g, c, w, lane);
    mix_part2(smem, macc, H1b, H1m, g, c, w, lane);
  } else {
    cell1_w23(smem, Xe + (size_t)1 * Bb * EMB_, Hb0, Hb1, g, c, lane, tid);
  }
  arrive_cnt(fl, c); ++cph;      // cph=2

  // ---- steady state: 2 phases per timestep ----
  for (int t = 0; t < Tt - 1; t++) {
    const u16* Xt = Xe + (size_t)t * Bb * EMB_;
    // ---------- Phase A_t: cell2(t) ----------
    {
      const u16* wb3 = (const u16*)(smem + OFF_W3) + lane * 8;
      const u16* xrow = Xt + (size_t)(g * 64 + w * 16 + r) * EMB_;
      f32x4 acc0 = {0.f, 0.f, 0.f, 0.f}, acc1 = {0.f, 0.f, 0.f, 0.f};
      s16x8 xa[8];
#pragma unroll
      for (int kb = 0; kb < 8; kb++) xa[kb] = *(const s16x8*)(xrow + kb * 32 + q * 8);
#pragma unroll
      for (int kb = 0; kb < 8; kb++) {     // x-part pre-wait
        acc0 = mfma16(xa[kb], *(const s16x8*)(wb3 + (size_t)(kb * 2 + 0) * 512), acc0);
        acc1 = mfma16(xa[kb], *(const s16x8*)(wb3 + (size_t)(kb * 2 + 1) * 512), acc1);
      }
      wait_cnt(fl, cph);                   // need H1m(t) from B_{t-1}
      const u16* hrow = H1m + (size_t)(g * 64 + w * 16 + r) * HID_;
      s16x8 ha[16];
      ld_h16(ha, hrow + q * 8);
      __builtin_amdgcn_sched_barrier(0);
      WAITLDN(12);
#pragma unroll
      for (int kb = 0; kb < 4; kb++) {
        acc0 = mfma16(ha[kb], *(const s16x8*)(wb3 + (size_t)((kb + 8) * 2 + 0) * 512), acc0);
        acc1 = mfma16(ha[kb], *(const s16x8*)(wb3 + (size_t)((kb + 8) * 2 + 1) * 512), acc1);
      }
      WAITLDN(8);
#pragma unroll
      for (int kb = 4; kb < 8; kb++) {
        acc0 = mfma16(ha[kb], *(const s16x8*)(wb3 + (size_t)((kb + 8) * 2 + 0) * 512), acc0);
        acc1 = mfma16(ha[kb], *(const s16x8*)(wb3 + (size_t)((kb + 8) * 2 + 1) * 512), acc1);
      }
      WAITLDN(4);
#pragma unroll
      for (int kb = 8; kb < 12; kb++) {
        acc0 = mfma16(ha[kb], *(const s16x8*)(wb3 + (size_t)((kb + 8) * 2 + 0) * 512), acc0);
        acc1 = mfma16(ha[kb], *(const s16x8*)(wb3 + (size_t)((kb + 8) * 2 + 1) * 512), acc1);
      }
      WAITLDN(0);
#pragma unroll
      for (int kb = 12; kb < 16; kb++) {
        acc0 = mfma16(ha[kb], *(const s16x8*)(wb3 + (size_t)((kb + 8) * 2 + 0) * 512), acc0);
        acc1 = mfma16(ha[kb], *(const s16x8*)(wb3 + (size_t)((kb + 8) * 2 + 1) * 512), acc1);
      }
      float* Ds = (float*)(smem + OFF_DS);
#pragma unroll
      for (int i = 0; i < 4; i++) {
        Ds[(w * 16 + q * 4 + i) * 33 + r]      = acc0[i];
        Ds[(w * 16 + q * 4 + i) * 33 + 16 + r] = acc1[i];
      }
      __syncthreads();
      if (tid < 128) {
        const float* bs = (const float*)(smem + OFF_B3);
        float* Cs = (float*)(smem + OFF_C1);
        int row = tid >> 1, j0 = (tid & 1) * 4;
        union { u16 h[4]; u64 qv; } pk;
#pragma unroll
        for (int i = 0; i < 4; i++) {
          int j = j0 + i;
          float vi = Ds[row * 33 + 0 + j]  + bs[0 + j];
          float vf = Ds[row * 33 + 8 + j]  + bs[8 + j];
          float vo = Ds[row * 33 + 16 + j] + bs[16 + j];
          float vc = Ds[row * 33 + 24 + j] + bs[24 + j];
          float I = sigm(vi), F = sigm(vf), O = sigm(vo), Ct = tanh_(vc);
          float Cn = F * Cs[row * 8 + j] + I * Ct;
          Cs[row * 8 + j] = Cn;
          pk.h[i] = f2bf(O * tanh_(Cn));
        }
        st8_llc(H1b + (size_t)(g * 64 + row) * HID_ + c * 8 + j0, pk.qv);
      }
      arrive_cnt(fl, c); ++cph;
    }
    // ---------- Phase B_t: mix(t+1) [w 0-1] + cell1(t+2) [w 2-3, pre-wait] ----------
    {
      const u16* Hnew = (t & 1) ? Hb0 : Hb1;   // H(t+1)
      u16* Hdst1      = (t & 1) ? Hb1 : Hb0;   // H(t+2)
      f32x4 macc = {0.f, 0.f, 0.f, 0.f};
      if (w < 2) {
        macc = mix_part1(smem, Hnew, g, c, w, lane);        // pre-wait half
      } else if (t + 2 < Tt) {
        cell1_w23(smem, Xe + (size_t)(t + 2) * Bb * EMB_, Hnew, Hdst1, g, c, lane, tid);
      }
      wait_cnt(fl, cph);                     // need H1(t) from A_t
      if (w < 2) mix_part2(smem, macc, H1b, H1m, g, c, w, lane);
      arrive_cnt(fl, c); ++cph;
    }
  }

  // ---- epilogue: cell2(255) ----
  {
    const u16* Xt = Xe + (size_t)(Tt - 1) * Bb * EMB_;
    const u16* wb3 = (const u16*)(smem + OFF_W3) + lane * 8;
    const u16* xrow = Xt + (size_t)(g * 64 + w * 16 + r) * EMB_;
    f32x4 acc0 = {0.f, 0.f, 0.f, 0.f}, acc1 = {0.f, 0.f, 0.f, 0.f};
    s16x8 xa[8];
#pragma unroll
    for (int kb = 0; kb < 8; kb++) xa[kb] = *(const s16x8*)(xrow + kb * 32 + q * 8);
#pragma unroll
    for (int kb = 0; kb < 8; kb++) {
      acc0 = mfma16(xa[kb], *(const s16x8*)(wb3 + (size_t)(kb * 2 + 0) * 512), acc0);
      acc1 = mfma16(xa[kb], *(const s16x8*)(wb3 + (size_t)(kb * 2 + 1) * 512), acc1);
    }
    wait_cnt(fl, cph);                       // mix(255) from B_254
    const u16* hrow = H1m + (size_t)(g * 64 + w * 16 + r) * HID_;
    s16x8 ha[16];
    ld_h16(ha, hrow + q * 8);
    waitld();
#pragma unroll
    for (int kb = 0; kb < 16; kb++) {
      acc0 = mfma16(ha[kb], *(const s16x8*)(wb3 + (size_t)((kb + 8) * 2 + 0) * 512), acc0);
      acc1 = mfma16(ha[kb], *(const s16x8*)(wb3 + (size_t)((kb + 8) * 2 + 1) * 512), acc1);
    }
    float* Ds = (float*)(smem + OFF_DS);
#pragma unroll
    for (int i = 0; i < 4; i++) {
      Ds[(w * 16 + q * 4 + i) * 33 + r]      = acc0[i];
      Ds[(w * 16 + q * 4 + i) * 33 + 16 + r] = acc1[i];
    }
    __syncthreads();
    if (tid < 128) {
      const float* bs = (const float*)(smem + OFF_B3);
      float* Cs = (float*)(smem + OFF_C1);
      int row = tid >> 1, j0 = (tid & 1) * 4;
      union { u16 h[4]; u64 qv; } pk;
#pragma unroll
      for (int i = 0; i < 4; i++) {
        int j = j0 + i;
        float vi = Ds[row * 33 + 0 + j]  + bs[0 + j];
        float vf = Ds[row * 33 + 8 + j]  + bs[8 + j];
        float vo = Ds[row * 33 + 16 + j] + bs[16 + j];
        float vc = Ds[row * 33 + 24 + j] + bs[24 + j];
        float I = sigm(vi), F = sigm(vf), O = sigm(vo), Ct = tanh_(vc);
        float Cn = F * Cs[row * 8 + j] + I * Ct;
        Cs[row * 8 + j] = Cn;
        pk.h[i] = f2bf(O * tanh_(Cn));
      }
      st8_llc(H1b + (size_t)(g * 64 + row) * HID_ + c * 8 + j0, pk.qv);
    }
  }

  // ---- all-groups done, then final GEMM with cached loads ----
  donebar(dn, bi);
  if (bi < 250) {
    const int n0 = bi * 128;
    u16* Wf = (u16*)smem;   // reuse weight LDS: [16 kb][8 nt][64 lane][8]
    for (int idx = tid; idx < 512 * 128; idx += NTHR) {
      int k = idx >> 7, nn2 = idx & 127;
      int nt = nn2 >> 4, rr = nn2 & 15;
      int kb = k >> 5, q2 = (k >> 3) & 3, e = k & 7;
      Wf[((size_t)(kb * 8 + nt) * 64 + q2 * 16 + rr) * 8 + e] =
          f2bf(p.Whq[(size_t)k * NCLS + n0 + nn2]);
    }
    float* bqs = (float*)(smem + OFF_C);
    if (tid < 128) bqs[tid] = p.bq[n0 + tid];
    __syncthreads();
    const int r2 = lane & 15, q2 = lane >> 4;
    for (int mt = 0; mt < 4; mt++) {
      int rowb = mt * 64 + w * 16;
      const u16* arow = H1b + (size_t)(rowb + r2) * HID_;
      f32x4 acc[8];
#pragma unroll
      for (int nt = 0; nt < 8; nt++) acc[nt] = (f32x4){0.f, 0.f, 0.f, 0.f};
      for (int kb = 0; kb < 16; kb++) {
        s16x8 a = *(const s16x8*)(arow + kb * 32 + q2 * 8);
#pragma unroll
        for (int nt = 0; nt < 8; nt++) {
          s16x8 b = *(const s16x8*)((const u16*)Wf + ((size_t)(kb * 8 + nt) * 64 + lane) * 8);
          acc[nt] = mfma16(a, b, acc[nt]);
        }
      }
#pragma unroll
      for (int nt = 0; nt < 8; nt++)
#pragma unroll
        for (int i = 0; i < 4; i++)
          p.out[(size_t)(rowb + q2 * 4 + i) * NCLS + n0 + nt * 16 + r2] =
              acc[nt][i] + bqs[nt * 16 + r2];
    }
  }
}

extern "C" void kernel_launch(void* const* d_in, const int* in_sizes, int n_in,
                              void* d_out, int out_size, void* d_ws, size_t ws_size,
                              hipStream_t stream) {
  (void)in_sizes; (void)n_in; (void)out_size; (void)ws_size;
  Params p;
  p.X   = (const int*)d_in[0];
  p.Hin = (const float*)d_in[1];
  p.Cin = (const float*)d_in[2];
  p.E   = (const float*)d_in[3];
  for (int gidx = 0; gidx < 4; gidx++) {   // gate order i,f,o,c
    int base = 4 + gidx * 6;
    p.Wx[gidx]  = (const float*)d_in[base + 0];
    p.Wh[gidx]  = (const float*)d_in[base + 1];
    p.bg[gidx]  = (const float*)d_in[base + 2];
    p.Wx1[gidx] = (const float*)d_in[base + 3];
    p.Wh1[gidx] = (const float*)d_in[base + 4];
    p.bg1[gidx] = (const float*)d_in[base + 5];
  }
  p.Wxh = (const float*)d_in[28];
  p.Whh = (const float*)d_in[29];
  p.bh  = (const float*)d_in[30];
  p.Whq = (const float*)d_in[31];
  p.bq  = (const float*)d_in[32];
  p.out = (float*)d_out;
  p.ws  = (char*)d_ws;

  hipFuncSetAttribute(reinterpret_cast<const void*>(lstm_pers),
                      hipFuncAttributeMaxDynamicSharedMemorySize, SMEM_BYTES);
  lstm_pers<<<dim3(NWG), dim3(NTHR), SMEM_BYTES, stream>>>(p);
}

// Round 10
// 3167.130 us; speedup vs baseline: 1.2517x; 1.0733x over previous
//
#include <hip/hip_runtime.h>
#include <cstdint>
#include <cstddef>

typedef unsigned short u16;
typedef unsigned char u8;
typedef unsigned long long u64;
typedef __attribute__((ext_vector_type(8))) short s16x8;
typedef __attribute__((ext_vector_type(8))) _Float16 f16x8;
typedef __attribute__((ext_vector_type(4))) float f32x4;
typedef __attribute__((ext_vector_type(4))) unsigned int u32x4;
typedef __attribute__((ext_vector_type(4))) unsigned short u16x4;

#define AGENT __HIP_MEMORY_SCOPE_AGENT

namespace {
constexpr int NWG  = 256;
constexpr int NTHR = 256;
constexpr int Bb   = 256;
constexpr int Tt   = 256;
constexpr int EMB_ = 256;
constexpr int HID_ = 512;
constexpr int NCLS = 32000;

constexpr float S_HM = 1.0f / 255.0f;    // H1m u8 scale (sigmoid, unsigned)
constexpr float S_H1 = 1.0f / 127.5f;    // H1 u8 scale (biased: v = u*S - 1)

// ---- LDS layout (bytes) ----
constexpr int OFF_W1  = 0;        // cell1 (all bf16) = 49152 B
constexpr int OFF_W3  = 49152;    // cell2: x-part bf16, H-part f16 (natural scale)
constexpr int OFF_W2  = 98304;    // mix: Wxh bf16, Whh f16
constexpr int OFF_DS  = 131072;   // cell2 gate scratch [64][33] f32
constexpr int OFF_DS1 = 139520;   // cell1 gate scratch
constexpr int OFF_DSM = 147968;   // mix per-wave transpose / init colsum scratch
constexpr int OFF_C   = 150144;   // cell1 C state (bq reuse in final)
constexpr int OFF_C1  = 152192;   // cell2 C state
constexpr int OFF_B1  = 154240;
constexpr int OFF_B3  = 154368;
constexpr int OFF_B2  = 154496;   // bh - colsum(Whh)  (u8-bias folded)
constexpr int SMEM_BYTES = 154560;

// ---- workspace layout ----
constexpr size_t WS_FL   = 0;                          // 256 x 128B
constexpr size_t WS_DONE = 32768;
constexpr size_t WS_HB0  = 33792;                      // H bf16 ping-pong
constexpr size_t WS_HB1  = WS_HB0 + (size_t)Bb * HID_ * 2;
constexpr size_t WS_H18  = WS_HB1 + (size_t)Bb * HID_ * 2;   // H1 u8 [B][512]
constexpr size_t WS_HM8  = WS_H18 + (size_t)Bb * HID_;       // H1m u8
constexpr size_t WS_XE   = WS_HM8 + (size_t)Bb * HID_;       // Xe bf16
}  // namespace

struct Params {
  const int* X; const float* Hin; const float* Cin; const float* E;
  const float* Wx[4];  const float* Wh[4];  const float* bg[4];
  const float* Wx1[4]; const float* Wh1[4]; const float* bg1[4];
  const float* Wxh; const float* Whh; const float* bh;
  const float* Whq; const float* bq;
  float* out; char* ws;
};

__device__ __forceinline__ u16 f2bf(float f) {
  union { float f; unsigned u; } v; v.f = f;
  unsigned r = v.u + 0x7FFFu + ((v.u >> 16) & 1u);
  return (u16)(r >> 16);
}
__device__ __forceinline__ u16 f2h(float f) {   // f16 bits
  _Float16 h = (_Float16)f;
  union { _Float16 h; u16 u; } v; v.h = h; return v.u;
}
__device__ __forceinline__ float sigm(float x) { return 1.f / (1.f + __expf(-x)); }
__device__ __forceinline__ float tanh_(float x) {
  x = fminf(fmaxf(x, -10.f), 10.f);
  float e = __expf(-2.f * x);
  return (1.f - e) / (1.f + e);
}
__device__ __forceinline__ f32x4 mfma16(s16x8 a, s16x8 b, f32x4 c) {
  return __builtin_amdgcn_mfma_f32_16x16x32_bf16(a, b, c, 0, 0, 0);
}
__device__ __forceinline__ f32x4 mfma16h(f16x8 a, f16x8 b, f32x4 c) {
  return __builtin_amdgcn_mfma_f32_16x16x32_f16(a, b, c, 0, 0, 0);
}

// permuted u8 k-layout: consumer lane(q) load j covers frags 2j,2j+1 contiguously.
// k = kb*32 + q*8 + e  ->  pos = (kb>>1)*64 + q*16 + (kb&1)*8 + e   (bijective)
__device__ __forceinline__ int permk(int k) {
  return ((k >> 6) << 6) | (((k >> 3) & 3) << 4) | (((k >> 5) & 1) << 3) | (k & 7);
}

// decode 8 u8 (2 dwords) -> 8 f16 (exact: ints <=255)
__device__ __forceinline__ f16x8 dec8(unsigned lo, unsigned hi) {
  union { unsigned w[4]; f16x8 v; } o;
  float a, b;
  asm("v_cvt_f32_ubyte0 %0, %1" : "=v"(a) : "v"(lo));
  asm("v_cvt_f32_ubyte1 %0, %1" : "=v"(b) : "v"(lo));
  asm("v_cvt_pkrtz_f16_f32 %0, %1, %2" : "=v"(o.w[0]) : "v"(a), "v"(b));
  asm("v_cvt_f32_ubyte2 %0, %1" : "=v"(a) : "v"(lo));
  asm("v_cvt_f32_ubyte3 %0, %1" : "=v"(b) : "v"(lo));
  asm("v_cvt_pkrtz_f16_f32 %0, %1, %2" : "=v"(o.w[1]) : "v"(a), "v"(b));
  asm("v_cvt_f32_ubyte0 %0, %1" : "=v"(a) : "v"(hi));
  asm("v_cvt_f32_ubyte1 %0, %1" : "=v"(b) : "v"(hi));
  asm("v_cvt_pkrtz_f16_f32 %0, %1, %2" : "=v"(o.w[2]) : "v"(a), "v"(b));
  asm("v_cvt_f32_ubyte2 %0, %1" : "=v"(a) : "v"(hi));
  asm("v_cvt_f32_ubyte3 %0, %1" : "=v"(b) : "v"(hi));
  asm("v_cvt_pkrtz_f16_f32 %0, %1, %2" : "=v"(o.w[3]) : "v"(a), "v"(b));
  return o.v;
}
__device__ __forceinline__ unsigned enc4(float a, float b, float c2, float d) {
  unsigned ua = (unsigned)a, ub = (unsigned)b, uc = (unsigned)c2, ud = (unsigned)d;
  return ua | (ub << 8) | (uc << 16) | (ud << 24);
}

// ---- LLC bypass primitives ----
__device__ __forceinline__ void st8_llc(u16* p2, u64 v) {
  __hip_atomic_store((u64*)p2, v, __ATOMIC_RELAXED, AGENT);
}
__device__ __forceinline__ void st4_llc(u8* pb, unsigned v) {
  __hip_atomic_store((unsigned*)pb, v, __ATOMIC_RELAXED, AGENT);
}
#define LD16A(d, b, off)                                                      \
  asm volatile("global_load_dwordx4 %0, %1, off offset:" #off " sc0 sc1"      \
               : "=&v"(d) : "v"(b) : "memory")

__device__ __forceinline__ void ld_h16(s16x8* d, const u16* b) {
  LD16A(d[0],  b, 0);   LD16A(d[1],  b, 64);  LD16A(d[2],  b, 128);
  LD16A(d[3],  b, 192); LD16A(d[4],  b, 256); LD16A(d[5],  b, 320);
  LD16A(d[6],  b, 384); LD16A(d[7],  b, 448); LD16A(d[8],  b, 512);
  LD16A(d[9],  b, 576); LD16A(d[10], b, 640); LD16A(d[11], b, 704);
  LD16A(d[12], b, 768); LD16A(d[13], b, 832); LD16A(d[14], b, 896);
  LD16A(d[15], b, 960);
}
__device__ __forceinline__ void ld_h8a(s16x8* d, const u16* b) {
  LD16A(d[0], b, 0);   LD16A(d[1], b, 64);  LD16A(d[2], b, 128);
  LD16A(d[3], b, 192); LD16A(d[4], b, 256); LD16A(d[5], b, 320);
  LD16A(d[6], b, 384); LD16A(d[7], b, 448);
}
__device__ __forceinline__ void ld_h8b(s16x8* d, const u16* b) {
  LD16A(d[8],  b, 512); LD16A(d[9],  b, 576); LD16A(d[10], b, 640);
  LD16A(d[11], b, 704); LD16A(d[12], b, 768); LD16A(d[13], b, 832);
  LD16A(d[14], b, 896); LD16A(d[15], b, 960);
}
// u8 panel: 8 x 16B loads per lane (half the txns of bf16)
__device__ __forceinline__ void ld_u8x8(u32x4* d, const u8* b) {
  LD16A(d[0], b, 0);   LD16A(d[1], b, 64);  LD16A(d[2], b, 128);
  LD16A(d[3], b, 192); LD16A(d[4], b, 256); LD16A(d[5], b, 320);
  LD16A(d[6], b, 384); LD16A(d[7], b, 448);
}
__device__ __forceinline__ void waitld() {
  asm volatile("s_waitcnt vmcnt(0)" ::: "memory");
  __builtin_amdgcn_sched_barrier(0);
}
#define WAITLDN(n) do {                                                       \
  asm volatile("s_waitcnt vmcnt(" #n ")" ::: "memory");                       \
  __builtin_amdgcn_sched_barrier(0); } while (0)

// ---- counter barrier (poison-zeroed in init; rounds 3/6 lesson) ----
__device__ __forceinline__ void arrive_cnt(int* fl, int c) {
  __syncthreads();
  if (threadIdx.x == 0)
    (void)__hip_atomic_fetch_add(&fl[(c & 7) * 32 + 16], 1, __ATOMIC_RELAXED, AGENT);
}
__device__ __forceinline__ void wait_cnt(int* fl, int ph) {
  const int tgt = ph * 8;
  if (threadIdx.x < 8) {
    for (;;) {
      int v = __hip_atomic_load(&fl[threadIdx.x * 32 + 16], __ATOMIC_RELAXED, AGENT);
      if (!__any(v < tgt)) break;
      __builtin_amdgcn_s_sleep(1);
    }
  }
  __syncthreads();
  __builtin_amdgcn_fence(__ATOMIC_ACQUIRE, "workgroup");
}
__device__ __forceinline__ void groupbar_heavy(int* fl, int slot, int ph) {
  __syncthreads();
  if (threadIdx.x == 0)
    __hip_atomic_store(&fl[slot * 32], ph, __ATOMIC_RELEASE, AGENT);
  if (threadIdx.x < 64) {
    for (;;) {
      int v = __hip_atomic_load(&fl[threadIdx.x * 32], __ATOMIC_RELAXED, AGENT);
      if (!__any(v < ph)) break;
      __builtin_amdgcn_s_sleep(1);
    }
  }
  __syncthreads();
  __builtin_amdgcn_fence(__ATOMIC_ACQUIRE, "agent");
}
__device__ __forceinline__ void donebar(int* dn, int bi) {
  __syncthreads();
  if (threadIdx.x == 0)
    __hip_atomic_store(&dn[bi], 1, __ATOMIC_RELEASE, AGENT);
  for (;;) {
    int v = __hip_atomic_load(&dn[threadIdx.x], __ATOMIC_RELAXED, AGENT);
    if (!__any(v < 1)) break;
    __builtin_amdgcn_s_sleep(1);
  }
  __syncthreads();
  __builtin_amdgcn_fence(__ATOMIC_ACQUIRE, "agent");
}

// Prologue cell1(0): bf16 H in/out, unchanged.
__device__ __forceinline__ void cell_phase(char* smem, int offW, int offB, int offC,
                                           const u16* Xt, const u16* Hrec, u16* Hdst,
                                           int g, int c, int w, int lane, int tid) {
  const int r = lane & 15, q = lane >> 4;
  const int row0 = w * 16;
  const u16* xrow = Xt + (size_t)(g * 64 + row0 + r) * EMB_;
  const u16* hrow = Hrec + (size_t)(g * 64 + row0 + r) * HID_;
  const u16* wb = (const u16*)(smem + offW) + lane * 8;
  f32x4 acc0 = {0.f, 0.f, 0.f, 0.f}, acc1 = {0.f, 0.f, 0.f, 0.f};
#pragma unroll
  for (int kb = 0; kb < 8; kb++) {
    s16x8 a  = *(const s16x8*)(xrow + kb * 32 + q * 8);
    acc0 = mfma16(a, *(const s16x8*)(wb + (size_t)(kb * 2 + 0) * 512), acc0);
    acc1 = mfma16(a, *(const s16x8*)(wb + (size_t)(kb * 2 + 1) * 512), acc1);
  }
  s16x8 ha[16];
  ld_h16(ha, hrow + q * 8);
  waitld();
#pragma unroll
  for (int kb = 0; kb < 16; kb++) {
    acc0 = mfma16(ha[kb], *(const s16x8*)(wb + (size_t)((kb + 8) * 2 + 0) * 512), acc0);
    acc1 = mfma16(ha[kb], *(const s16x8*)(wb + (size_t)((kb + 8) * 2 + 1) * 512), acc1);
  }
  float* Ds = (float*)(smem + OFF_DS);
#pragma unroll
  for (int i = 0; i < 4; i++) {
    Ds[(row0 + q * 4 + i) * 33 + r]      = acc0[i];
    Ds[(row0 + q * 4 + i) * 33 + 16 + r] = acc1[i];
  }
  __syncthreads();
  const float* bs = (const float*)(smem + offB);
  float* Cs = (float*)(smem + offC);
  if (tid < 128) {
    int row = tid >> 1, j0 = (tid & 1) * 4;
    union { u16 h[4]; u64 qv; } pk;
#pragma unroll
    for (int i = 0; i < 4; i++) {
      int j = j0 + i;
      float vi = Ds[row * 33 + 0 + j]  + bs[0 + j];
      float vf = Ds[row * 33 + 8 + j]  + bs[8 + j];
      float vo = Ds[row * 33 + 16 + j] + bs[16 + j];
      float vc = Ds[row * 33 + 24 + j] + bs[24 + j];
      float I = sigm(vi), F = sigm(vf), O = sigm(vo), Ct = tanh_(vc);
      float Cn = F * Cs[row * 8 + j] + I * Ct;
      Cs[row * 8 + j] = Cn;
      pk.h[i] = f2bf(O * tanh_(Cn));
    }
    st8_llc(Hdst + (size_t)(g * 64 + row) * HID_ + c * 8 + j0, pk.qv);
  }
}

// cell1 (slack, bf16 H, unchanged)
__device__ __forceinline__ void cell1_w23(char* smem, const u16* Xt, const u16* Hrec,
                                          u16* Hdst, int g, int c, int lane, int tid) {
  const int wv = (tid >> 6) - 2;
  const int r = lane & 15, q = lane >> 4;
  const u16* wb1 = (const u16*)(smem + OFF_W1) + lane * 8;
  float* D1 = (float*)(smem + OFF_DS1);
#pragma unroll
  for (int blk = 0; blk < 2; blk++) {
    const int rb = wv * 32 + blk * 16;
    const u16* xrow = Xt + (size_t)(g * 64 + rb + r) * EMB_;
    const u16* hrow = Hrec + (size_t)(g * 64 + rb + r) * HID_;
    s16x8 xa[8];
#pragma unroll
    for (int kb = 0; kb < 8; kb++) xa[kb] = *(const s16x8*)(xrow + kb * 32 + q * 8);
    s16x8 hh[16];
    ld_h8a(hh, hrow + q * 8);
    f32x4 a0 = {0.f, 0.f, 0.f, 0.f}, a1 = {0.f, 0.f, 0.f, 0.f};
#pragma unroll
    for (int kb = 0; kb < 8; kb++) {
      a0 = mfma16(xa[kb], *(const s16x8*)(wb1 + (size_t)(kb * 2 + 0) * 512), a0);
      a1 = mfma16(xa[kb], *(const s16x8*)(wb1 + (size_t)(kb * 2 + 1) * 512), a1);
    }
    waitld();
#pragma unroll
    for (int kb = 0; kb < 8; kb++) {
      a0 = mfma16(hh[kb], *(const s16x8*)(wb1 + (size_t)((kb + 8) * 2 + 0) * 512), a0);
      a1 = mfma16(hh[kb], *(const s16x8*)(wb1 + (size_t)((kb + 8) * 2 + 1) * 512), a1);
    }
    ld_h8b(hh, hrow + q * 8);
    waitld();
#pragma unroll
    for (int kb = 8; kb < 16; kb++) {
      a0 = mfma16(hh[kb], *(const s16x8*)(wb1 + (size_t)((kb + 8) * 2 + 0) * 512), a0);
      a1 = mfma16(hh[kb], *(const s16x8*)(wb1 + (size_t)((kb + 8) * 2 + 1) * 512), a1);
    }
#pragma unroll
    for (int i = 0; i < 4; i++) {
      D1[(rb + q * 4 + i) * 33 + r]      = a0[i];
      D1[(rb + q * 4 + i) * 33 + 16 + r] = a1[i];
    }
  }
  const float* bs = (const float*)(smem + OFF_B1);
  float* Cs = (float*)(smem + OFF_C);
  int t2 = tid - 128;
  int row = t2 >> 1, j0 = (t2 & 1) * 4;
  union { u16 h[4]; u64 qv; } pk;
#pragma unroll
  for (int i = 0; i < 4; i++) {
    int j = j0 + i;
    float vi = D1[row * 33 + 0 + j]  + bs[0 + j];
    float vf = D1[row * 33 + 8 + j]  + bs[8 + j];
    float vo = D1[row * 33 + 16 + j] + bs[16 + j];
    float vc = D1[row * 33 + 24 + j] + bs[24 + j];
    float I = sigm(vi), F = sigm(vf), O = sigm(vo), Ct = tanh_(vc);
    float Cn = F * Cs[row * 8 + j] + I * Ct;
    Cs[row * 8 + j] = Cn;
    pk.h[i] = f2bf(O * tanh_(Cn));
  }
  st8_llc(Hdst + (size_t)(g * 64 + row) * HID_ + c * 8 + j0, pk.qv);
}

// mix part 1 (slack, bf16 H, unchanged)
__device__ __forceinline__ f32x4 mix_part1(char* smem, const u16* Hnew, int g, int c,
                                           int w, int lane) {
  const int r = lane & 15, q = lane >> 4;
  int rbase = g * 64 + (c & 1) * 32 + w * 16 + r;
  const u16* h0 = Hnew + (size_t)rbase * HID_;
  const u16* wb = (const u16*)(smem + OFF_W2) + lane * 8;
  s16x8 ha[16];
  f32x4 acc = {0.f, 0.f, 0.f, 0.f};
  ld_h8a(ha, h0 + q * 8);
  waitld();
#pragma unroll
  for (int kb = 0; kb < 8; kb++)
    acc = mfma16(ha[kb], *(const s16x8*)(wb + (size_t)kb * 512), acc);
  ld_h8b(ha, h0 + q * 8);
  waitld();
#pragma unroll
  for (int kb = 8; kb < 16; kb++)
    acc = mfma16(ha[kb], *(const s16x8*)(wb + (size_t)kb * 512), acc);
  return acc;
}

// mix part 2 (CRITICAL): u8 H1 panel (permuted), f16 MFMA, chunked vmcnt.
// B2 already = bh - colsum(Whh) (u8 bias correction folded).
__device__ __forceinline__ void mix_part2(char* smem, f32x4 macc, const u8* H18,
                                          u8* HM8, int g, int c, int w, int lane) {
  const int r = lane & 15, q = lane >> 4;
  int rbase = g * 64 + (c & 1) * 32 + w * 16 + r;
  const u8* h1 = H18 + (size_t)rbase * 512 + q * 16;
  const u16* wb = (const u16*)(smem + OFF_W2) + lane * 8;
  u32x4 rw[8];
  ld_u8x8(rw, h1);
  __builtin_amdgcn_sched_barrier(0);
  f32x4 acch = {0.f, 0.f, 0.f, 0.f};
  WAITLDN(6);
#pragma unroll
  for (int j = 0; j < 2; j++) {
    acch = mfma16h(dec8(rw[j].x, rw[j].y), *(const f16x8*)(wb + (size_t)(16 + 2 * j) * 512), acch);
    acch = mfma16h(dec8(rw[j].z, rw[j].w), *(const f16x8*)(wb + (size_t)(17 + 2 * j) * 512), acch);
  }
  WAITLDN(4);
#pragma unroll
  for (int j = 2; j < 4; j++) {
    acch = mfma16h(dec8(rw[j].x, rw[j].y), *(const f16x8*)(wb + (size_t)(16 + 2 * j) * 512), acch);
    acch = mfma16h(dec8(rw[j].z, rw[j].w), *(const f16x8*)(wb + (size_t)(17 + 2 * j) * 512), acch);
  }
  WAITLDN(2);
#pragma unroll
  for (int j = 4; j < 6; j++) {
    acch = mfma16h(dec8(rw[j].x, rw[j].y), *(const f16x8*)(wb + (size_t)(16 + 2 * j) * 512), acch);
    acch = mfma16h(dec8(rw[j].z, rw[j].w), *(const f16x8*)(wb + (size_t)(17 + 2 * j) * 512), acch);
  }
  WAITLDN(0);
#pragma unroll
  for (int j = 6; j < 8; j++) {
    acch = mfma16h(dec8(rw[j].x, rw[j].y), *(const f16x8*)(wb + (size_t)(16 + 2 * j) * 512), acch);
    acch = mfma16h(dec8(rw[j].z, rw[j].w), *(const f16x8*)(wb + (size_t)(17 + 2 * j) * 512), acch);
  }
  f32x4 acc;
#pragma unroll
  for (int i = 0; i < 4; i++) acc[i] = macc[i] + acch[i] * S_H1;
  float* Dm = (float*)(smem + OFF_DSM) + (size_t)w * 16 * 17;
#pragma unroll
  for (int i = 0; i < 4; i++) Dm[(q * 4 + i) * 17 + r] = acc[i];
  const float* b2 = (const float*)(smem + OFF_B2);
  int row2 = lane >> 2, j0 = (lane & 3) * 4;
  float s0 = sigm(Dm[row2 * 17 + j0 + 0] + b2[j0 + 0]);
  float s1 = sigm(Dm[row2 * 17 + j0 + 1] + b2[j0 + 1]);
  float s2 = sigm(Dm[row2 * 17 + j0 + 2] + b2[j0 + 2]);
  float s3 = sigm(Dm[row2 * 17 + j0 + 3] + b2[j0 + 3]);
  unsigned pv = enc4(s0 * 255.f + 0.5f, s1 * 255.f + 0.5f,
                     s2 * 255.f + 0.5f, s3 * 255.f + 0.5f);
  int colg = (c >> 1) * 16 + j0;
  st4_llc(HM8 + (size_t)(g * 64 + (c & 1) * 32 + w * 16 + row2) * 512 + permk(colg), pv);
}

__global__ __launch_bounds__(NTHR, 1) void lstm_pers(Params p) {
  extern __shared__ char smem[];
  const int tid = threadIdx.x;
  const int bi = blockIdx.x;
  const int w = tid >> 6, lane = tid & 63;
  const int g = bi >> 6, c = bi & 63;
  const int r = lane & 15, q = lane >> 4;

  int* fl = (int*)(p.ws + WS_FL) + g * 64 * 32;
  int* dn = (int*)(p.ws + WS_DONE);
  u16* Hb0 = (u16*)(p.ws + WS_HB0);
  u16* Hb1 = (u16*)(p.ws + WS_HB1);
  u8* H18  = (u8*)(p.ws + WS_H18);
  u8* HM8  = (u8*)(p.ws + WS_HM8);
  u16* Xe  = (u16*)(p.ws + WS_XE);

  // zero phase counters (ws is POISONED; RMW needs explicit zero — rounds 3/6)
  if (tid == 0 && c < 8)
    __hip_atomic_store(&fl[c * 32 + 16], 0, __ATOMIC_RELAXED, AGENT);

  // ---- one-time init ----
  {
    u16* w1 = (u16*)(smem + OFF_W1);
    u16* w3 = (u16*)(smem + OFF_W3);
    int gate = tid >> 6, kk8 = (tid >> 3) & 7, j = tid & 7;
    int cc = gate * 8 + j;
    int n = cc >> 4, rr = cc & 15;
    int hid = c * 8 + j;
    for (int kk = kk8; kk < 768; kk += 8) {
      int kb = kk >> 5, q2 = (kk >> 3) & 3, e = kk & 7;
      size_t dst = ((size_t)(kb * 2 + n) * 64 + q2 * 16 + rr) * 8 + e;
      float s1 = (kk < 256) ? p.Wx[gate][(size_t)kk * HID_ + hid]
                            : p.Wh[gate][(size_t)(kk - 256) * HID_ + hid];
      float s3 = (kk < 256) ? p.Wx1[gate][(size_t)kk * HID_ + hid]
                            : p.Wh1[gate][(size_t)(kk - 256) * HID_ + hid];
      w1[dst] = f2bf(s1);
      w3[dst] = (kk < 256) ? f2bf(s3) : f2h(s3);   // H-part f16 (u8-decoded operand)
    }
    {  // mix weights: Wxh bf16 (kk<512), Whh f16 (kk>=512)
      u16* w2 = (u16*)(smem + OFF_W2);
      int kk16 = tid >> 4, j2 = tid & 15;
      int hid2 = (c >> 1) * 16 + j2;
      for (int kk = kk16; kk < 1024; kk += 16) {
        int kb = kk >> 5, q2 = (kk >> 3) & 3, e = kk & 7;
        size_t dst = ((size_t)kb * 64 + q2 * 16 + j2) * 8 + e;
        float s = (kk < 512) ? p.Wxh[(size_t)kk * HID_ + hid2]
                             : p.Whh[(size_t)(kk - 512) * HID_ + hid2];
        w2[dst] = (kk < 512) ? f2bf(s) : f2h(s);
      }
    }
    // B2 = bh - colsum(Whh)  (u8 bias-fold); scratch in OFF_DSM
    {
      float* scr = (float*)(smem + OFF_DSM);
      int col = tid & 15, part = tid >> 4;
      int hid2 = (c >> 1) * 16 + col;
      float s = 0.f;
      for (int k = part * 32; k < part * 32 + 32; k++)
        s += p.Whh[(size_t)k * HID_ + hid2];
      scr[col * 16 + part] = s;
      __syncthreads();
      if (tid < 16) {
        float t = 0.f;
        for (int i2 = 0; i2 < 16; i2++) t += scr[tid * 16 + i2];
        ((float*)(smem + OFF_B2))[tid] = p.bh[(c >> 1) * 16 + tid] - t;
      }
      __syncthreads();
    }
    if (tid < 32) {
      int gt = tid >> 3, jj = tid & 7;
      ((float*)(smem + OFF_B1))[tid] = p.bg[gt][c * 8 + jj];
      ((float*)(smem + OFF_B3))[tid] = p.bg1[gt][c * 8 + jj];
    }
    float* Cs = (float*)(smem + OFF_C);
    float* C1s = (float*)(smem + OFF_C1);
    for (int it = 0; it < 2; it++) {
      int idx = tid + it * 256;
      int row = idx >> 3, j8 = idx & 7;
      float v = p.Cin[(size_t)(g * 64 + row) * HID_ + c * 8 + j8];
      Cs[row * 8 + j8] = v;
      C1s[row * 8 + j8] = v;
    }
  }
  // H bf16 init + H1 u8 init (biased encode, permuted layout; normal stores)
  for (int it = 0; it < 2; it++) {
    int idx = bi * 512 + tid + it * 256;
    float v = p.Hin[idx];
    Hb1[idx] = f2bf(v);
    float vc2 = fminf(fmaxf(v, -0.999f), 0.999f);
    int row = idx >> 9, k = idx & 511;
    H18[(size_t)row * 512 + permk(k)] = (u8)((vc2 + 1.f) * 127.5f + 0.5f);
  }
  // Embedding gather
  for (int tt = 0; tt < 4; tt++) {
    int t0 = c * 4 + tt;
    for (int pp = 0; pp < 16; pp++) {
      int b = g * 64 + w * 16 + pp;
      int tok = p.X[(size_t)b * Tt + t0];
      const float4* er = (const float4*)(p.E + (size_t)tok * EMB_);
      float4 v = er[lane];
      u16x4 u; u.x = f2bf(v.x); u.y = f2bf(v.y); u.z = f2bf(v.z); u.w = f2bf(v.w);
      *(u16x4*)(Xe + ((size_t)t0 * Bb + b) * EMB_ + lane * 4) = u;
    }
  }
  groupbar_heavy(fl, c, 1);

  int cph = 0;

  // ---- P0: cell1(0): Hb1 -> Hb0 ----
  cell_phase(smem, OFF_W1, OFF_B1, OFF_C, Xe, Hb1, Hb0, g, c, w, lane, tid);
  arrive_cnt(fl, c); ++cph;

  // ---- P1: mix(0) [w 0-1] + cell1(1) [w 2-3] ----
  wait_cnt(fl, cph);
  if (w < 2) {
    f32x4 macc = mix_part1(smem, Hb0, g, c, w, lane);
    mix_part2(smem, macc, H18, HM8, g, c, w, lane);
  } else {
    cell1_w23(smem, Xe + (size_t)1 * Bb * EMB_, Hb0, Hb1, g, c, lane, tid);
  }
  arrive_cnt(fl, c); ++cph;

  // ---- steady state ----
  for (int t = 0; t < Tt - 1; t++) {
    const u16* Xt = Xe + (size_t)t * Bb * EMB_;
    // ---------- Phase A_t: cell2(t) — u8 H1m panel, f16 MFMA, chunked ----------
    {
      const u16* wb3 = (const u16*)(smem + OFF_W3) + lane * 8;
      const u16* xrow = Xt + (size_t)(g * 64 + w * 16 + r) * EMB_;
      f32x4 acc0 = {0.f, 0.f, 0.f, 0.f}, acc1 = {0.f, 0.f, 0.f, 0.f};
      s16x8 xa[8];
#pragma unroll
      for (int kb = 0; kb < 8; kb++) xa[kb] = *(const s16x8*)(xrow + kb * 32 + q * 8);
#pragma unroll
      for (int kb = 0; kb < 8; kb++) {
        acc0 = mfma16(xa[kb], *(const s16x8*)(wb3 + (size_t)(kb * 2 + 0) * 512), acc0);
        acc1 = mfma16(xa[kb], *(const s16x8*)(wb3 + (size_t)(kb * 2 + 1) * 512), acc1);
      }
      wait_cnt(fl, cph);
      const u8* hrow8 = HM8 + (size_t)(g * 64 + w * 16 + r) * 512 + q * 16;
      u32x4 rw[8];
      ld_u8x8(rw, hrow8);
      __builtin_amdgcn_sched_barrier(0);
      f32x4 ah0 = {0.f, 0.f, 0.f, 0.f}, ah1 = {0.f, 0.f, 0.f, 0.f};
      WAITLDN(6);
#pragma unroll
      for (int jj = 0; jj < 2; jj++) {
        f16x8 f0 = dec8(rw[jj].x, rw[jj].y);
        f16x8 f1 = dec8(rw[jj].z, rw[jj].w);
        ah0 = mfma16h(f0, *(const f16x8*)(wb3 + (size_t)((2 * jj + 8) * 2 + 0) * 512), ah0);
        ah1 = mfma16h(f0, *(const f16x8*)(wb3 + (size_t)((2 * jj + 8) * 2 + 1) * 512), ah1);
        ah0 = mfma16h(f1, *(const f16x8*)(wb3 + (size_t)((2 * jj + 9) * 2 + 0) * 512), ah0);
        ah1 = mfma16h(f1, *(const f16x8*)(wb3 + (size_t)((2 * jj + 9) * 2 + 1) * 512), ah1);
      }
      WAITLDN(4);
#pragma unroll
      for (int jj = 2; jj < 4; jj++) {
        f16x8 f0 = dec8(rw[jj].x, rw[jj].y);
        f16x8 f1 = dec8(rw[jj].z, rw[jj].w);
        ah0 = mfma16h(f0, *(const f16x8*)(wb3 + (size_t)((2 * jj + 8) * 2 + 0) * 512), ah0);
        ah1 = mfma16h(f0, *(const f16x8*)(wb3 + (size_t)((2 * jj + 8) * 2 + 1) * 512), ah1);
        ah0 = mfma16h(f1, *(const f16x8*)(wb3 + (size_t)((2 * jj + 9) * 2 + 0) * 512), ah0);
        ah1 = mfma16h(f1, *(const f16x8*)(wb3 + (size_t)((2 * jj + 9) * 2 + 1) * 512), ah1);
      }
      WAITLDN(2);
#pragma unroll
      for (int jj = 4; jj < 6; jj++) {
        f16x8 f0 = dec8(rw[jj].x, rw[jj].y);
        f16x8 f1 = dec8(rw[jj].z, rw[jj].w);
        ah0 = mfma16h(f0, *(const f16x8*)(wb3 + (size_t)((2 * jj + 8) * 2 + 0) * 512), ah0);
        ah1 = mfma16h(f0, *(const f16x8*)(wb3 + (size_t)((2 * jj + 8) * 2 + 1) * 512), ah1);
        ah0 = mfma16h(f1, *(const f16x8*)(wb3 + (size_t)((2 * jj + 9) * 2 + 0) * 512), ah0);
        ah1 = mfma16h(f1, *(const f16x8*)(wb3 + (size_t)((2 * jj + 9) * 2 + 1) * 512), ah1);
      }
      WAITLDN(0);
#pragma unroll
      for (int jj = 6; jj < 8; jj++) {
        f16x8 f0 = dec8(rw[jj].x, rw[jj].y);
        f16x8 f1 = dec8(rw[jj].z, rw[jj].w);
        ah0 = mfma16h(f0, *(const f16x8*)(wb3 + (size_t)((2 * jj + 8) * 2 + 0) * 512), ah0);
        ah1 = mfma16h(f0, *(const f16x8*)(wb3 + (size_t)((2 * jj + 8) * 2 + 1) * 512), ah1);
        ah0 = mfma16h(f1, *(const f16x8*)(wb3 + (size_t)((2 * jj + 9) * 2 + 0) * 512), ah0);
        ah1 = mfma16h(f1, *(const f16x8*)(wb3 + (size_t)((2 * jj + 9) * 2 + 1) * 512), ah1);
      }
#pragma unroll
      for (int i = 0; i < 4; i++) {
        acc0[i] += ah0[i] * S_HM;
        acc1[i] += ah1[i] * S_HM;
      }
      float* Ds = (float*)(smem + OFF_DS);
#pragma unroll
      for (int i = 0; i < 4; i++) {
        Ds[(w * 16 + q * 4 + i) * 33 + r]      = acc0[i];
        Ds[(w * 16 + q * 4 + i) * 33 + 16 + r] = acc1[i];
      }
      __syncthreads();
      if (tid < 128) {
        const float* bs = (const float*)(smem + OFF_B3);
        float* Cs = (float*)(smem + OFF_C1);
        int row = tid >> 1, j0 = (tid & 1) * 4;
        float hv[4];
#pragma unroll
        for (int i = 0; i < 4; i++) {
          int j = j0 + i;
          float vi = Ds[row * 33 + 0 + j]  + bs[0 + j];
          float vf = Ds[row * 33 + 8 + j]  + bs[8 + j];
          float vo = Ds[row * 33 + 16 + j] + bs[16 + j];
          float vc = Ds[row * 33 + 24 + j] + bs[24 + j];
          float I = sigm(vi), F = sigm(vf), O = sigm(vo), Ct = tanh_(vc);
          float Cn = F * Cs[row * 8 + j] + I * Ct;
          Cs[row * 8 + j] = Cn;
          hv[i] = O * tanh_(Cn);
        }
        unsigned pv = enc4((hv[0] + 1.f) * 127.5f + 0.5f, (hv[1] + 1.f) * 127.5f + 0.5f,
                           (hv[2] + 1.f) * 127.5f + 0.5f, (hv[3] + 1.f) * 127.5f + 0.5f);
        st4_llc(H18 + (size_t)(g * 64 + row) * 512 + permk(c * 8 + j0), pv);
      }
      arrive_cnt(fl, c); ++cph;
    }
    // ---------- Phase B_t ----------
    {
      const u16* Hnew = (t & 1) ? Hb0 : Hb1;
      u16* Hdst1      = (t & 1) ? Hb1 : Hb0;
      f32x4 macc = {0.f, 0.f, 0.f, 0.f};
      if (w < 2) {
        macc = mix_part1(smem, Hnew, g, c, w, lane);
      } else if (t + 2 < Tt) {
        cell1_w23(smem, Xe + (size_t)(t + 2) * Bb * EMB_, Hnew, Hdst1, g, c, lane, tid);
      }
      wait_cnt(fl, cph);
      if (w < 2) mix_part2(smem, macc, H18, HM8, g, c, w, lane);
      arrive_cnt(fl, c); ++cph;
    }
  }

  // ---- epilogue: cell2(255) ----
  {
    const u16* Xt = Xe + (size_t)(Tt - 1) * Bb * EMB_;
    const u16* wb3 = (const u16*)(smem + OFF_W3) + lane * 8;
    const u16* xrow = Xt + (size_t)(g * 64 + w * 16 + r) * EMB_;
    f32x4 acc0 = {0.f, 0.f, 0.f, 0.f}, acc1 = {0.f, 0.f, 0.f, 0.f};
    s16x8 xa[8];
#pragma unroll
    for (int kb = 0; kb < 8; kb++) xa[kb] = *(const s16x8*)(xrow + kb * 32 + q * 8);
#pragma unroll
    for (int kb = 0; kb < 8; kb++) {
      acc0 = mfma16(xa[kb], *(const s16x8*)(wb3 + (size_t)(kb * 2 + 0) * 512), acc0);
      acc1 = mfma16(xa[kb], *(const s16x8*)(wb3 + (size_t)(kb * 2 + 1) * 512), acc1);
    }
    wait_cnt(fl, cph);
    const u8* hrow8 = HM8 + (size_t)(g * 64 + w * 16 + r) * 512 + q * 16;
    u32x4 rw[8];
    ld_u8x8(rw, hrow8);
    waitld();
    f32x4 ah0 = {0.f, 0.f, 0.f, 0.f}, ah1 = {0.f, 0.f, 0.f, 0.f};
#pragma unroll
    for (int jj = 0; jj < 8; jj++) {
      f16x8 f0 = dec8(rw[jj].x, rw[jj].y);
      f16x8 f1 = dec8(rw[jj].z, rw[jj].w);
      ah0 = mfma16h(f0, *(const f16x8*)(wb3 + (size_t)((2 * jj + 8) * 2 + 0) * 512), ah0);
      ah1 = mfma16h(f0, *(const f16x8*)(wb3 + (size_t)((2 * jj + 8) * 2 + 1) * 512), ah1);
      ah0 = mfma16h(f1, *(const f16x8*)(wb3 + (size_t)((2 * jj + 9) * 2 + 0) * 512), ah0);
      ah1 = mfma16h(f1, *(const f16x8*)(wb3 + (size_t)((2 * jj + 9) * 2 + 1) * 512), ah1);
    }
#pragma unroll
    for (int i = 0; i < 4; i++) {
      acc0[i] += ah0[i] * S_HM;
      acc1[i] += ah1[i] * S_HM;
    }
    float* Ds = (float*)(smem + OFF_DS);
#pragma unroll
    for (int i = 0; i < 4; i++) {
      Ds[(w * 16 + q * 4 + i) * 33 + r]      = acc0[i];
      Ds[(w * 16 + q * 4 + i) * 33 + 16 + r] = acc1[i];
    }
    __syncthreads();
    if (tid < 128) {
      const float* bs = (const float*)(smem + OFF_B3);
      float* Cs = (float*)(smem + OFF_C1);
      int row = tid >> 1, j0 = (tid & 1) * 4;
      float hv[4];
#pragma unroll
      for (int i = 0; i < 4; i++) {
        int j = j0 + i;
        float vi = Ds[row * 33 + 0 + j]  + bs[0 + j];
        float vf = Ds[row * 33 + 8 + j]  + bs[8 + j];
        float vo = Ds[row * 33 + 16 + j] + bs[16 + j];
        float vc = Ds[row * 33 + 24 + j] + bs[24 + j];
        float I = sigm(vi), F = sigm(vf), O = sigm(vo), Ct = tanh_(vc);
        float Cn = F * Cs[row * 8 + j] + I * Ct;
        Cs[row * 8 + j] = Cn;
        hv[i] = O * tanh_(Cn);
      }
      unsigned pv = enc4((hv[0] + 1.f) * 127.5f + 0.5f, (hv[1] + 1.f) * 127.5f + 0.5f,
                         (hv[2] + 1.f) * 127.5f + 0.5f, (hv[3] + 1.f) * 127.5f + 0.5f);
      st4_llc(H18 + (size_t)(g * 64 + row) * 512 + permk(c * 8 + j0), pv);
    }
  }

  // ---- final GEMM: u8 H1 (cached loads post-donebar), f16 Wf, bias-corrected ----
  donebar(dn, bi);
  if (bi < 250) {
    const int n0 = bi * 128;
    _Float16* Wf = (_Float16*)smem;   // [16 kb][8 nt][64 lane][8] f16 (natural scale)
    for (int idx = tid; idx < 512 * 128; idx += NTHR) {
      int k = idx >> 7, nn2 = idx & 127;
      int nt = nn2 >> 4, rr = nn2 & 15;
      int kb = k >> 5, q2 = (k >> 3) & 3, e = k & 7;
      Wf[((size_t)(kb * 8 + nt) * 64 + q2 * 16 + rr) * 8 + e] =
          (_Float16)p.Whq[(size_t)k * NCLS + n0 + nn2];
    }
    float* bqs = (float*)(smem + OFF_C);
    __syncthreads();
    if (tid < 128) {       // bqs = bq - colsum(Whq)  (u8 bias-fold), from LDS
      int nt = tid >> 4, rr = tid & 15;
      float s = 0.f;
      for (int kb = 0; kb < 16; kb++)
        for (int q2 = 0; q2 < 4; q2++)
#pragma unroll
          for (int e = 0; e < 8; e++)
            s += (float)Wf[((size_t)(kb * 8 + nt) * 64 + q2 * 16 + rr) * 8 + e];
      bqs[tid] = p.bq[n0 + tid] - s;
    }
    __syncthreads();
    const int r2 = lane & 15, q2 = lane >> 4;
    for (int mt = 0; mt < 4; mt++) {
      int rowb = mt * 64 + w * 16;
      const u8* h1base = H18 + (size_t)(rowb + r2) * 512 + q2 * 16;
      f16x8 haf[16];
#pragma unroll
      for (int jj = 0; jj < 8; jj++) {
        u32x4 rwv = *(const u32x4*)(h1base + jj * 64);
        haf[2 * jj]     = dec8(rwv.x, rwv.y);
        haf[2 * jj + 1] = dec8(rwv.z, rwv.w);
      }
      f32x4 acc[8];
#pragma unroll
      for (int nt = 0; nt < 8; nt++) acc[nt] = (f32x4){0.f, 0.f, 0.f, 0.f};
      for (int kb = 0; kb < 16; kb++) {
#pragma unroll
        for (int nt = 0; nt < 8; nt++) {
          f16x8 b = *(const f16x8*)(Wf + ((size_t)(kb * 8 + nt) * 64 + lane) * 8);
          acc[nt] = mfma16h(haf[kb], b, acc[nt]);
        }
      }
#pragma unroll
      for (int nt = 0; nt < 8; nt++)
#pragma unroll
        for (int i = 0; i < 4; i++)
          p.out[(size_t)(rowb + q2 * 4 + i) * NCLS + n0 + nt * 16 + r2] =
              acc[nt][i] * S_H1 + bqs[nt * 16 + r2];
    }
  }
}

extern "C" void kernel_launch(void* const* d_in, const int* in_sizes, int n_in,
                              void* d_out, int out_size, void* d_ws, size_t ws_size,
                              hipStream_t stream) {
  (void)in_sizes; (void)n_in; (void)out_size; (void)ws_size;
  Params p;
  p.X   = (const int*)d_in[0];
  p.Hin = (const float*)d_in[1];
  p.Cin = (const float*)d_in[2];
  p.E   = (const float*)d_in[3];
  for (int gidx = 0; gidx < 4; gidx++) {
    int base = 4 + gidx * 6;
    p.Wx[gidx]  = (const float*)d_in[base + 0];
    p.Wh[gidx]  = (const float*)d_in[base + 1];
    p.bg[gidx]  = (const float*)d_in[base + 2];
    p.Wx1[gidx] = (const float*)d_in[base + 3];
    p.Wh1[gidx] = (const float*)d_in[base + 4];
    p.bg1[gidx] = (const float*)d_in[base + 5];
  }
  p.Wxh = (const float*)d_in[28];
  p.Whh = (const float*)d_in[29];
  p.bh  = (const float*)d_in[30];
  p.Whq = (const float*)d_in[31];
  p.bq  = (const float*)d_in[32];
  p.out = (float*)d_out;
  p.ws  = (char*)d_ws;

  hipFuncSetAttribute(reinterpret_cast<const void*>(lstm_pers),
                      hipFuncAttributeMaxDynamicSharedMemorySize, SMEM_BYTES);
  lstm_pers<<<dim3(NWG), dim3(NTHR), SMEM_BYTES, stream>>>(p);
}

// Round 11
// 3058.659 us; speedup vs baseline: 1.2961x; 1.0355x over previous
//
#include <hip/hip_runtime.h>
#include <cstdint>
#include <cstddef>

typedef unsigned short u16;
typedef unsigned char u8;
typedef unsigned long long u64;
typedef __attribute__((ext_vector_type(8))) short s16x8;
typedef __attribute__((ext_vector_type(8))) _Float16 f16x8;
typedef __attribute__((ext_vector_type(4))) float f32x4;
typedef __attribute__((ext_vector_type(4))) unsigned int u32x4;
typedef __attribute__((ext_vector_type(4))) unsigned short u16x4;

#define AGENT __HIP_MEMORY_SCOPE_AGENT

namespace {
constexpr int NWG  = 256;
constexpr int NTHR = 256;
constexpr int Bb   = 256;
constexpr int Tt   = 256;
constexpr int EMB_ = 256;
constexpr int HID_ = 512;
constexpr int NCLS = 32000;

constexpr float S_HM = 1.0f / 255.0f;    // H1m u8 scale (sigmoid, unsigned)
constexpr float S_H1 = 1.0f / 127.5f;    // H / H1 u8 scale (biased: v = u*S - 1)

// ---- LDS layout (bytes) ----
constexpr int OFF_W1  = 0;        // cell1: x bf16, H f16
constexpr int OFF_W3  = 49152;    // cell2: x bf16, H f16
constexpr int OFF_W2  = 98304;    // mix: all f16 (both operand halves u8-decoded)
constexpr int OFF_DS  = 131072;   // cell2 gate scratch [64][33] f32
constexpr int OFF_DS1 = 139520;   // cell1 gate scratch
constexpr int OFF_DSM = 147968;   // mix per-wave transpose / init colsum scratch
constexpr int OFF_C   = 150144;   // cell1 C state (bq reuse in final)
constexpr int OFF_C1  = 152192;   // cell2 C state
constexpr int OFF_B1  = 154240;   // bg - colsum(Wh)   (u8-bias folded)
constexpr int OFF_B3  = 154368;   // bg1 (H1m unsigned -> no fold)
constexpr int OFF_B2  = 154496;   // bh - colsum(Wxh) - colsum(Whh)
constexpr int SMEM_BYTES = 154560;

// ---- workspace layout ----
constexpr size_t WS_FL   = 0;                          // 256 x 128B
constexpr size_t WS_DONE = 32768;
constexpr size_t WS_HQ0  = 33792;                      // H u8 ping [B][512]
constexpr size_t WS_HQ1  = WS_HQ0 + (size_t)Bb * HID_;
constexpr size_t WS_H18  = WS_HQ1 + (size_t)Bb * HID_; // H1 u8
constexpr size_t WS_HM8  = WS_H18 + (size_t)Bb * HID_; // H1m u8
constexpr size_t WS_XE   = WS_HM8 + (size_t)Bb * HID_; // Xe bf16
}  // namespace

struct Params {
  const int* X; const float* Hin; const float* Cin; const float* E;
  const float* Wx[4];  const float* Wh[4];  const float* bg[4];
  const float* Wx1[4]; const float* Wh1[4]; const float* bg1[4];
  const float* Wxh; const float* Whh; const float* bh;
  const float* Whq; const float* bq;
  float* out; char* ws;
};

__device__ __forceinline__ u16 f2bf(float f) {
  union { float f; unsigned u; } v; v.f = f;
  unsigned r = v.u + 0x7FFFu + ((v.u >> 16) & 1u);
  return (u16)(r >> 16);
}
__device__ __forceinline__ u16 f2h(float f) {
  _Float16 h = (_Float16)f;
  union { _Float16 h; u16 u; } v; v.h = h; return v.u;
}
__device__ __forceinline__ float sigm(float x) { return 1.f / (1.f + __expf(-x)); }
__device__ __forceinline__ float tanh_(float x) {
  x = fminf(fmaxf(x, -10.f), 10.f);
  float e = __expf(-2.f * x);
  return (1.f - e) / (1.f + e);
}
__device__ __forceinline__ f32x4 mfma16(s16x8 a, s16x8 b, f32x4 c) {
  return __builtin_amdgcn_mfma_f32_16x16x32_bf16(a, b, c, 0, 0, 0);
}
__device__ __forceinline__ f32x4 mfma16h(f16x8 a, f16x8 b, f32x4 c) {
  return __builtin_amdgcn_mfma_f32_16x16x32_f16(a, b, c, 0, 0, 0);
}

// permuted u8 k-layout: consumer lane(q) load j covers frags 2j,2j+1 contiguously.
// k = kb*32 + q*8 + e  ->  pos = (kb>>1)*64 + q*16 + (kb&1)*8 + e   (bijective)
__device__ __forceinline__ int permk(int k) {
  return ((k >> 6) << 6) | (((k >> 3) & 3) << 4) | (((k >> 5) & 1) << 3) | (k & 7);
}

// decode 8 u8 (2 dwords) -> 8 f16 (exact: ints <=255)
__device__ __forceinline__ f16x8 dec8(unsigned lo, unsigned hi) {
  union { unsigned w[4]; f16x8 v; } o;
  float a, b;
  asm("v_cvt_f32_ubyte0 %0, %1" : "=v"(a) : "v"(lo));
  asm("v_cvt_f32_ubyte1 %0, %1" : "=v"(b) : "v"(lo));
  asm("v_cvt_pkrtz_f16_f32 %0, %1, %2" : "=v"(o.w[0]) : "v"(a), "v"(b));
  asm("v_cvt_f32_ubyte2 %0, %1" : "=v"(a) : "v"(lo));
  asm("v_cvt_f32_ubyte3 %0, %1" : "=v"(b) : "v"(lo));
  asm("v_cvt_pkrtz_f16_f32 %0, %1, %2" : "=v"(o.w[1]) : "v"(a), "v"(b));
  asm("v_cvt_f32_ubyte0 %0, %1" : "=v"(a) : "v"(hi));
  asm("v_cvt_f32_ubyte1 %0, %1" : "=v"(b) : "v"(hi));
  asm("v_cvt_pkrtz_f16_f32 %0, %1, %2" : "=v"(o.w[2]) : "v"(a), "v"(b));
  asm("v_cvt_f32_ubyte2 %0, %1" : "=v"(a) : "v"(hi));
  asm("v_cvt_f32_ubyte3 %0, %1" : "=v"(b) : "v"(hi));
  asm("v_cvt_pkrtz_f16_f32 %0, %1, %2" : "=v"(o.w[3]) : "v"(a), "v"(b));
  return o.v;
}
__device__ __forceinline__ unsigned enc4(float a, float b, float c2, float d) {
  unsigned ua = (unsigned)a, ub = (unsigned)b, uc = (unsigned)c2, ud = (unsigned)d;
  return ua | (ub << 8) | (uc << 16) | (ud << 24);
}
__device__ __forceinline__ unsigned enc4s(const float* hv) {   // biased signed encode
  return enc4((hv[0] + 1.f) * 127.5f + 0.5f, (hv[1] + 1.f) * 127.5f + 0.5f,
              (hv[2] + 1.f) * 127.5f + 0.5f, (hv[3] + 1.f) * 127.5f + 0.5f);
}

// ---- LLC bypass primitives ----
__device__ __forceinline__ void st4_llc(u8* pb, unsigned v) {
  __hip_atomic_store((unsigned*)pb, v, __ATOMIC_RELAXED, AGENT);
}
#define LD16A(d, b, off)                                                      \
  asm volatile("global_load_dwordx4 %0, %1, off offset:" #off " sc0 sc1"      \
               : "=&v"(d) : "v"(b) : "memory")

// u8 panel: 8 x 16B loads per lane = full 512B row across 4 lanes
__device__ __forceinline__ void ld_u8x8(u32x4* d, const u8* b) {
  LD16A(d[0], b, 0);   LD16A(d[1], b, 64);  LD16A(d[2], b, 128);
  LD16A(d[3], b, 192); LD16A(d[4], b, 256); LD16A(d[5], b, 320);
  LD16A(d[6], b, 384); LD16A(d[7], b, 448);
}
__device__ __forceinline__ void waitld() {
  asm volatile("s_waitcnt vmcnt(0)" ::: "memory");
  __builtin_amdgcn_sched_barrier(0);
}
#define WAITLDN(n) do {                                                       \
  asm volatile("s_waitcnt vmcnt(" #n ")" ::: "memory");                       \
  __builtin_amdgcn_sched_barrier(0); } while (0)

// ---- counter barrier (poison-zeroed in init; rounds 3/6 lesson) ----
__device__ __forceinline__ void arrive_cnt(int* fl, int c) {
  __syncthreads();
  if (threadIdx.x == 0)
    (void)__hip_atomic_fetch_add(&fl[(c & 7) * 32 + 16], 1, __ATOMIC_RELAXED, AGENT);
}
__device__ __forceinline__ void wait_cnt(int* fl, int ph) {
  const int tgt = ph * 8;
  if (threadIdx.x < 8) {
    for (;;) {
      int v = __hip_atomic_load(&fl[threadIdx.x * 32 + 16], __ATOMIC_RELAXED, AGENT);
      if (!__any(v < tgt)) break;
      __builtin_amdgcn_s_sleep(1);
    }
  }
  __syncthreads();
  __builtin_amdgcn_fence(__ATOMIC_ACQUIRE, "workgroup");
}
__device__ __forceinline__ void groupbar_heavy(int* fl, int slot, int ph) {
  __syncthreads();
  if (threadIdx.x == 0)
    __hip_atomic_store(&fl[slot * 32], ph, __ATOMIC_RELEASE, AGENT);
  if (threadIdx.x < 64) {
    for (;;) {
      int v = __hip_atomic_load(&fl[threadIdx.x * 32], __ATOMIC_RELAXED, AGENT);
      if (!__any(v < ph)) break;
      __builtin_amdgcn_s_sleep(1);
    }
  }
  __syncthreads();
  __builtin_amdgcn_fence(__ATOMIC_ACQUIRE, "agent");
}
__device__ __forceinline__ void donebar(int* dn, int bi) {
  __syncthreads();
  if (threadIdx.x == 0)
    __hip_atomic_store(&dn[bi], 1, __ATOMIC_RELEASE, AGENT);
  for (;;) {
    int v = __hip_atomic_load(&dn[threadIdx.x], __ATOMIC_RELAXED, AGENT);
    if (!__any(v < 1)) break;
    __builtin_amdgcn_s_sleep(1);
  }
  __syncthreads();
  __builtin_amdgcn_fence(__ATOMIC_ACQUIRE, "agent");
}

// Prologue cell1(0): 4 waves, u8 H in/out, f16 H-part MFMA, full syncthreads.
__device__ __forceinline__ void cell_phase_q(char* smem, int offW, int offB, int offC,
                                             const u16* Xt, const u8* Hrec, u8* Hdst,
                                             int g, int c, int w, int lane, int tid) {
  const int r = lane & 15, q = lane >> 4;
  const int row0 = w * 16;
  const u16* xrow = Xt + (size_t)(g * 64 + row0 + r) * EMB_;
  const u8* hrow = Hrec + (size_t)(g * 64 + row0 + r) * 512 + q * 16;
  const u16* wb = (const u16*)(smem + offW) + lane * 8;
  f32x4 acc0 = {0.f, 0.f, 0.f, 0.f}, acc1 = {0.f, 0.f, 0.f, 0.f};
#pragma unroll
  for (int kb = 0; kb < 8; kb++) {
    s16x8 a  = *(const s16x8*)(xrow + kb * 32 + q * 8);
    acc0 = mfma16(a, *(const s16x8*)(wb + (size_t)(kb * 2 + 0) * 512), acc0);
    acc1 = mfma16(a, *(const s16x8*)(wb + (size_t)(kb * 2 + 1) * 512), acc1);
  }
  u32x4 rw[8];
  ld_u8x8(rw, hrow);
  waitld();
  f32x4 ah0 = {0.f, 0.f, 0.f, 0.f}, ah1 = {0.f, 0.f, 0.f, 0.f};
#pragma unroll
  for (int jj = 0; jj < 8; jj++) {
    f16x8 f0 = dec8(rw[jj].x, rw[jj].y);
    f16x8 f1 = dec8(rw[jj].z, rw[jj].w);
    ah0 = mfma16h(f0, *(const f16x8*)(wb + (size_t)((2 * jj + 8) * 2 + 0) * 512), ah0);
    ah1 = mfma16h(f0, *(const f16x8*)(wb + (size_t)((2 * jj + 8) * 2 + 1) * 512), ah1);
    ah0 = mfma16h(f1, *(const f16x8*)(wb + (size_t)((2 * jj + 9) * 2 + 0) * 512), ah0);
    ah1 = mfma16h(f1, *(const f16x8*)(wb + (size_t)((2 * jj + 9) * 2 + 1) * 512), ah1);
  }
#pragma unroll
  for (int i = 0; i < 4; i++) { acc0[i] += ah0[i] * S_H1; acc1[i] += ah1[i] * S_H1; }
  float* Ds = (float*)(smem + OFF_DS);
#pragma unroll
  for (int i = 0; i < 4; i++) {
    Ds[(row0 + q * 4 + i) * 33 + r]      = acc0[i];
    Ds[(row0 + q * 4 + i) * 33 + 16 + r] = acc1[i];
  }
  __syncthreads();
  const float* bs = (const float*)(smem + offB);
  float* Cs = (float*)(smem + offC);
  if (tid < 128) {
    int row = tid >> 1, j0 = (tid & 1) * 4;
    float hv[4];
#pragma unroll
    for (int i = 0; i < 4; i++) {
      int j = j0 + i;
      float vi = Ds[row * 33 + 0 + j]  + bs[0 + j];
      float vf = Ds[row * 33 + 8 + j]  + bs[8 + j];
      float vo = Ds[row * 33 + 16 + j] + bs[16 + j];
      float vc = Ds[row * 33 + 24 + j] + bs[24 + j];
      float I = sigm(vi), F = sigm(vf), O = sigm(vo), Ct = tanh_(vc);
      float Cn = F * Cs[row * 8 + j] + I * Ct;
      Cs[row * 8 + j] = Cn;
      hv[i] = O * tanh_(Cn);
    }
    st4_llc(Hdst + (size_t)(g * 64 + row) * 512 + permk(c * 8 + j0), enc4s(hv));
  }
}

// cell1 on waves 2-3: u8 H in/out, wave-local (no barrier). Runs PRE-wait in B.
__device__ __forceinline__ void cell1_w23_q(char* smem, const u16* Xt, const u8* Hrec,
                                            u8* Hdst, int g, int c, int lane, int tid) {
  const int wv = (tid >> 6) - 2;
  const int r = lane & 15, q = lane >> 4;
  const u16* wb1 = (const u16*)(smem + OFF_W1) + lane * 8;
  float* D1 = (float*)(smem + OFF_DS1);
#pragma unroll
  for (int blk = 0; blk < 2; blk++) {
    const int rb = wv * 32 + blk * 16;
    const u16* xrow = Xt + (size_t)(g * 64 + rb + r) * EMB_;
    const u8* hrow = Hrec + (size_t)(g * 64 + rb + r) * 512 + q * 16;
    s16x8 xa[8];
#pragma unroll
    for (int kb = 0; kb < 8; kb++) xa[kb] = *(const s16x8*)(xrow + kb * 32 + q * 8);
    u32x4 rw[8];
    ld_u8x8(rw, hrow);
    f32x4 a0 = {0.f, 0.f, 0.f, 0.f}, a1 = {0.f, 0.f, 0.f, 0.f};
#pragma unroll
    for (int kb = 0; kb < 8; kb++) {
      a0 = mfma16(xa[kb], *(const s16x8*)(wb1 + (size_t)(kb * 2 + 0) * 512), a0);
      a1 = mfma16(xa[kb], *(const s16x8*)(wb1 + (size_t)(kb * 2 + 1) * 512), a1);
    }
    waitld();
    f32x4 ah0 = {0.f, 0.f, 0.f, 0.f}, ah1 = {0.f, 0.f, 0.f, 0.f};
#pragma unroll
    for (int jj = 0; jj < 8; jj++) {
      f16x8 f0 = dec8(rw[jj].x, rw[jj].y);
      f16x8 f1 = dec8(rw[jj].z, rw[jj].w);
      ah0 = mfma16h(f0, *(const f16x8*)(wb1 + (size_t)((2 * jj + 8) * 2 + 0) * 512), ah0);
      ah1 = mfma16h(f0, *(const f16x8*)(wb1 + (size_t)((2 * jj + 8) * 2 + 1) * 512), ah1);
      ah0 = mfma16h(f1, *(const f16x8*)(wb1 + (size_t)((2 * jj + 9) * 2 + 0) * 512), ah0);
      ah1 = mfma16h(f1, *(const f16x8*)(wb1 + (size_t)((2 * jj + 9) * 2 + 1) * 512), ah1);
    }
#pragma unroll
    for (int i = 0; i < 4; i++) {
      D1[(rb + q * 4 + i) * 33 + r]      = a0[i] + ah0[i] * S_H1;
      D1[(rb + q * 4 + i) * 33 + 16 + r] = a1[i] + ah1[i] * S_H1;
    }
  }
  const float* bs = (const float*)(smem + OFF_B1);
  float* Cs = (float*)(smem + OFF_C);
  int t2 = tid - 128;
  int row = t2 >> 1, j0 = (t2 & 1) * 4;
  float hv[4];
#pragma unroll
  for (int i = 0; i < 4; i++) {
    int j = j0 + i;
    float vi = D1[row * 33 + 0 + j]  + bs[0 + j];
    float vf = D1[row * 33 + 8 + j]  + bs[8 + j];
    float vo = D1[row * 33 + 16 + j] + bs[16 + j];
    float vc = D1[row * 33 + 24 + j] + bs[24 + j];
    float I = sigm(vi), F = sigm(vf), O = sigm(vo), Ct = tanh_(vc);
    float Cn = F * Cs[row * 8 + j] + I * Ct;
    Cs[row * 8 + j] = Cn;
    hv[i] = O * tanh_(Cn);
  }
  st4_llc(Hdst + (size_t)(g * 64 + row) * 512 + permk(c * 8 + j0), enc4s(hv));
}

// mix part 1 (slack, waves 0-1): u8 H panel, f16 MFMA. Returns u8-scaled acc.
__device__ __forceinline__ f32x4 mix_part1_q(char* smem, const u8* Hq, int g, int c,
                                             int w, int lane) {
  const int r = lane & 15, q = lane >> 4;
  int rbase = g * 64 + (c & 1) * 32 + w * 16 + r;
  const u8* h0 = Hq + (size_t)rbase * 512 + q * 16;
  const u16* wb = (const u16*)(smem + OFF_W2) + lane * 8;
  u32x4 rw[8];
  ld_u8x8(rw, h0);
  waitld();
  f32x4 acc = {0.f, 0.f, 0.f, 0.f};
#pragma unroll
  for (int jj = 0; jj < 8; jj++) {
    acc = mfma16h(dec8(rw[jj].x, rw[jj].y), *(const f16x8*)(wb + (size_t)(2 * jj) * 512), acc);
    acc = mfma16h(dec8(rw[jj].z, rw[jj].w), *(const f16x8*)(wb + (size_t)(2 * jj + 1) * 512), acc);
  }
  return acc;
}

// mix part 2 (CRITICAL): u8 H1 panel, f16 MFMA, chunked vmcnt.
// B2 = bh - colsum(Wxh) - colsum(Whh) (both u8-bias folds).
__device__ __forceinline__ void mix_part2(char* smem, f32x4 macc, const u8* H18,
                                          u8* HM8, int g, int c, int w, int lane) {
  const int r = lane & 15, q = lane >> 4;
  int rbase = g * 64 + (c & 1) * 32 + w * 16 + r;
  const u8* h1 = H18 + (size_t)rbase * 512 + q * 16;
  const u16* wb = (const u16*)(smem + OFF_W2) + lane * 8;
  u32x4 rw[8];
  ld_u8x8(rw, h1);
  __builtin_amdgcn_sched_barrier(0);
  f32x4 acch = {0.f, 0.f, 0.f, 0.f};
  WAITLDN(6);
#pragma unroll
  for (int j = 0; j < 2; j++) {
    acch = mfma16h(dec8(rw[j].x, rw[j].y), *(const f16x8*)(wb + (size_t)(16 + 2 * j) * 512), acch);
    acch = mfma16h(dec8(rw[j].z, rw[j].w), *(const f16x8*)(wb + (size_t)(17 + 2 * j) * 512), acch);
  }
  WAITLDN(4);
#pragma unroll
  for (int j = 2; j < 4; j++) {
    acch = mfma16h(dec8(rw[j].x, rw[j].y), *(const f16x8*)(wb + (size_t)(16 + 2 * j) * 512), acch);
    acch = mfma16h(dec8(rw[j].z, rw[j].w), *(const f16x8*)(wb + (size_t)(17 + 2 * j) * 512), acch);
  }
  WAITLDN(2);
#pragma unroll
  for (int j = 4; j < 6; j++) {
    acch = mfma16h(dec8(rw[j].x, rw[j].y), *(const f16x8*)(wb + (size_t)(16 + 2 * j) * 512), acch);
    acch = mfma16h(dec8(rw[j].z, rw[j].w), *(const f16x8*)(wb + (size_t)(17 + 2 * j) * 512), acch);
  }
  WAITLDN(0);
#pragma unroll
  for (int j = 6; j < 8; j++) {
    acch = mfma16h(dec8(rw[j].x, rw[j].y), *(const f16x8*)(wb + (size_t)(16 + 2 * j) * 512), acch);
    acch = mfma16h(dec8(rw[j].z, rw[j].w), *(const f16x8*)(wb + (size_t)(17 + 2 * j) * 512), acch);
  }
  f32x4 acc;
#pragma unroll
  for (int i = 0; i < 4; i++) acc[i] = (macc[i] + acch[i]) * S_H1;
  float* Dm = (float*)(smem + OFF_DSM) + (size_t)w * 16 * 17;
#pragma unroll
  for (int i = 0; i < 4; i++) Dm[(q * 4 + i) * 17 + r] = acc[i];
  const float* b2 = (const float*)(smem + OFF_B2);
  int row2 = lane >> 2, j0 = (lane & 3) * 4;
  float s0 = sigm(Dm[row2 * 17 + j0 + 0] + b2[j0 + 0]);
  float s1 = sigm(Dm[row2 * 17 + j0 + 1] + b2[j0 + 1]);
  float s2 = sigm(Dm[row2 * 17 + j0 + 2] + b2[j0 + 2]);
  float s3 = sigm(Dm[row2 * 17 + j0 + 3] + b2[j0 + 3]);
  unsigned pv = enc4(s0 * 255.f + 0.5f, s1 * 255.f + 0.5f,
                     s2 * 255.f + 0.5f, s3 * 255.f + 0.5f);
  int colg = (c >> 1) * 16 + j0;
  st4_llc(HM8 + (size_t)(g * 64 + (c & 1) * 32 + w * 16 + row2) * 512 + permk(colg), pv);
}

__global__ __launch_bounds__(NTHR, 1) void lstm_pers(Params p) {
  extern __shared__ char smem[];
  const int tid = threadIdx.x;
  const int bi = blockIdx.x;
  const int w = tid >> 6, lane = tid & 63;
  const int g = bi >> 6, c = bi & 63;
  const int r = lane & 15, q = lane >> 4;

  int* fl = (int*)(p.ws + WS_FL) + g * 64 * 32;
  int* dn = (int*)(p.ws + WS_DONE);
  u8* Hq0 = (u8*)(p.ws + WS_HQ0);
  u8* Hq1 = (u8*)(p.ws + WS_HQ1);
  u8* H18 = (u8*)(p.ws + WS_H18);
  u8* HM8 = (u8*)(p.ws + WS_HM8);
  u16* Xe = (u16*)(p.ws + WS_XE);

  // zero phase counters (ws is POISONED; RMW needs explicit zero — rounds 3/6)
  if (tid == 0 && c < 8)
    __hip_atomic_store(&fl[c * 32 + 16], 0, __ATOMIC_RELAXED, AGENT);

  // ---- one-time init ----
  {
    u16* w1 = (u16*)(smem + OFF_W1);
    u16* w3 = (u16*)(smem + OFF_W3);
    int gate = tid >> 6, kk8 = (tid >> 3) & 7, j = tid & 7;
    int cc = gate * 8 + j;
    int n = cc >> 4, rr = cc & 15;
    int hid = c * 8 + j;
    for (int kk = kk8; kk < 768; kk += 8) {
      int kb = kk >> 5, q2 = (kk >> 3) & 3, e = kk & 7;
      size_t dst = ((size_t)(kb * 2 + n) * 64 + q2 * 16 + rr) * 8 + e;
      float s1 = (kk < 256) ? p.Wx[gate][(size_t)kk * HID_ + hid]
                            : p.Wh[gate][(size_t)(kk - 256) * HID_ + hid];
      float s3 = (kk < 256) ? p.Wx1[gate][(size_t)kk * HID_ + hid]
                            : p.Wh1[gate][(size_t)(kk - 256) * HID_ + hid];
      w1[dst] = (kk < 256) ? f2bf(s1) : f2h(s1);   // H-part f16 (u8-decoded operand)
      w3[dst] = (kk < 256) ? f2bf(s3) : f2h(s3);
    }
    {  // mix weights: all f16 (both operand halves are u8-decoded)
      u16* w2 = (u16*)(smem + OFF_W2);
      int kk16 = tid >> 4, j2 = tid & 15;
      int hid2 = (c >> 1) * 16 + j2;
      for (int kk = kk16; kk < 1024; kk += 16) {
        int kb = kk >> 5, q2 = (kk >> 3) & 3, e = kk & 7;
        size_t dst = ((size_t)kb * 64 + q2 * 16 + j2) * 8 + e;
        float s = (kk < 512) ? p.Wxh[(size_t)kk * HID_ + hid2]
                             : p.Whh[(size_t)(kk - 512) * HID_ + hid2];
        w2[dst] = f2h(s);
      }
    }
    // B1 = bg - colsum(Wh)  (u8-bias fold for cell1's H input)
    {
      float* scr = (float*)(smem + OFF_DSM);
      int col32 = tid & 31, part = tid >> 5;
      int gt = col32 >> 3, jj = col32 & 7;
      int hid1 = c * 8 + jj;
      float s = 0.f;
      for (int k = part * 64; k < part * 64 + 64; k++)
        s += p.Wh[gt][(size_t)k * HID_ + hid1];
      scr[col32 * 8 + part] = s;
      __syncthreads();
      if (tid < 32) {
        float t2 = 0.f;
        for (int i2 = 0; i2 < 8; i2++) t2 += scr[tid * 8 + i2];
        ((float*)(smem + OFF_B1))[tid] = p.bg[tid >> 3][c * 8 + (tid & 7)] - t2;
      }
      __syncthreads();
    }
    // B2 = bh - colsum(Wxh) - colsum(Whh)
    {
      float* scr = (float*)(smem + OFF_DSM);
      int col = tid & 15, part = tid >> 4;
      int hid2 = (c >> 1) * 16 + col;
      float s = 0.f;
      for (int k = part * 32; k < part * 32 + 32; k++)
        s += p.Whh[(size_t)k * HID_ + hid2] + p.Wxh[(size_t)k * HID_ + hid2];
      scr[col * 16 + part] = s;
      __syncthreads();
      if (tid < 16) {
        float t2 = 0.f;
        for (int i2 = 0; i2 < 16; i2++) t2 += scr[tid * 16 + i2];
        ((float*)(smem + OFF_B2))[tid] = p.bh[(c >> 1) * 16 + tid] - t2;
      }
      __syncthreads();
    }
    if (tid < 32) {   // B3 plain (H1m unsigned u8 -> no fold)
      ((float*)(smem + OFF_B3))[tid] = p.bg1[tid >> 3][c * 8 + (tid & 7)];
    }
    float* Cs = (float*)(smem + OFF_C);
    float* C1s = (float*)(smem + OFF_C1);
    for (int it = 0; it < 2; it++) {
      int idx = tid + it * 256;
      int row = idx >> 3, j8 = idx & 7;
      float v = p.Cin[(size_t)(g * 64 + row) * HID_ + c * 8 + j8];
      Cs[row * 8 + j8] = v;
      C1s[row * 8 + j8] = v;
    }
  }
  // H(-1) and H1(-1) u8 init from Hin (biased encode, permuted; normal stores)
  for (int it = 0; it < 2; it++) {
    int idx = bi * 512 + tid + it * 256;
    float v = p.Hin[idx];
    float vc2 = fminf(fmaxf(v, -0.999f), 0.999f);
    u8 ev = (u8)((vc2 + 1.f) * 127.5f + 0.5f);
    int row = idx >> 9, k = idx & 511;
    Hq1[(size_t)row * 512 + permk(k)] = ev;
    H18[(size_t)row * 512 + permk(k)] = ev;
  }
  // Embedding gather
  for (int tt = 0; tt < 4; tt++) {
    int t0 = c * 4 + tt;
    for (int pp = 0; pp < 16; pp++) {
      int b = g * 64 + w * 16 + pp;
      int tok = p.X[(size_t)b * Tt + t0];
      const float4* er = (const float4*)(p.E + (size_t)tok * EMB_);
      float4 v = er[lane];
      u16x4 u; u.x = f2bf(v.x); u.y = f2bf(v.y); u.z = f2bf(v.z); u.w = f2bf(v.w);
      *(u16x4*)(Xe + ((size_t)t0 * Bb + b) * EMB_ + lane * 4) = u;
    }
  }
  groupbar_heavy(fl, c, 1);

  int cph = 0;

  // ---- P0: cell1(0): Hq1 -> Hq0 ----
  cell_phase_q(smem, OFF_W1, OFF_B1, OFF_C, Xe, Hq1, Hq0, g, c, w, lane, tid);
  arrive_cnt(fl, c); ++cph;

  // ---- P1: mix(0) [w 0-1] + cell1(1) [w 2-3] ----
  wait_cnt(fl, cph);
  if (w < 2) {
    f32x4 macc = mix_part1_q(smem, Hq0, g, c, w, lane);
    mix_part2(smem, macc, H18, HM8, g, c, w, lane);
  } else {
    cell1_w23_q(smem, Xe + (size_t)1 * Bb * EMB_, Hq0, Hq1, g, c, lane, tid);
  }
  arrive_cnt(fl, c); ++cph;

  // ---- steady state ----
  for (int t = 0; t < Tt - 1; t++) {
    const u16* Xt = Xe + (size_t)t * Bb * EMB_;
    // ---------- Phase A_t: cell2(t) — u8 H1m panel, f16 MFMA, chunked ----------
    {
      const u16* wb3 = (const u16*)(smem + OFF_W3) + lane * 8;
      const u16* xrow = Xt + (size_t)(g * 64 + w * 16 + r) * EMB_;
      f32x4 acc0 = {0.f, 0.f, 0.f, 0.f}, acc1 = {0.f, 0.f, 0.f, 0.f};
      s16x8 xa[8];
#pragma unroll
      for (int kb = 0; kb < 8; kb++) xa[kb] = *(const s16x8*)(xrow + kb * 32 + q * 8);
#pragma unroll
      for (int kb = 0; kb < 8; kb++) {
        acc0 = mfma16(xa[kb], *(const s16x8*)(wb3 + (size_t)(kb * 2 + 0) * 512), acc0);
        acc1 = mfma16(xa[kb], *(const s16x8*)(wb3 + (size_t)(kb * 2 + 1) * 512), acc1);
      }
      wait_cnt(fl, cph);
      const u8* hrow8 = HM8 + (size_t)(g * 64 + w * 16 + r) * 512 + q * 16;
      u32x4 rw[8];
      ld_u8x8(rw, hrow8);
      __builtin_amdgcn_sched_barrier(0);
      f32x4 ah0 = {0.f, 0.f, 0.f, 0.f}, ah1 = {0.f, 0.f, 0.f, 0.f};
      WAITLDN(6);
#pragma unroll
      for (int jj = 0; jj < 2; jj++) {
        f16x8 f0 = dec8(rw[jj].x, rw[jj].y);
        f16x8 f1 = dec8(rw[jj].z, rw[jj].w);
        ah0 = mfma16h(f0, *(const f16x8*)(wb3 + (size_t)((2 * jj + 8) * 2 + 0) * 512), ah0);
        ah1 = mfma16h(f0, *(const f16x8*)(wb3 + (size_t)((2 * jj + 8) * 2 + 1) * 512), ah1);
        ah0 = mfma16h(f1, *(const f16x8*)(wb3 + (size_t)((2 * jj + 9) * 2 + 0) * 512), ah0);
        ah1 = mfma16h(f1, *(const f16x8*)(wb3 + (size_t)((2 * jj + 9) * 2 + 1) * 512), ah1);
      }
      WAITLDN(4);
#pragma unroll
      for (int jj = 2; jj < 4; jj++) {
        f16x8 f0 = dec8(rw[jj].x, rw[jj].y);
        f16x8 f1 = dec8(rw[jj].z, rw[jj].w);
        ah0 = mfma16h(f0, *(const f16x8*)(wb3 + (size_t)((2 * jj + 8) * 2 + 0) * 512), ah0);
        ah1 = mfma16h(f0, *(const f16x8*)(wb3 + (size_t)((2 * jj + 8) * 2 + 1) * 512), ah1);
        ah0 = mfma16h(f1, *(const f16x8*)(wb3 + (size_t)((2 * jj + 9) * 2 + 0) * 512), ah0);
        ah1 = mfma16h(f1, *(const f16x8*)(wb3 + (size_t)((2 * jj + 9) * 2 + 1) * 512), ah1);
      }
      WAITLDN(2);
#pragma unroll
      for (int jj = 4; jj < 6; jj++) {
        f16x8 f0 = dec8(rw[jj].x, rw[jj].y);
        f16x8 f1 = dec8(rw[jj].z, rw[jj].w);
        ah0 = mfma16h(f0, *(const f16x8*)(wb3 + (size_t)((2 * jj + 8) * 2 + 0) * 512), ah0);
        ah1 = mfma16h(f0, *(const f16x8*)(wb3 + (size_t)((2 * jj + 8) * 2 + 1) * 512), ah1);
        ah0 = mfma16h(f1, *(const f16x8*)(wb3 + (size_t)((2 * jj + 9) * 2 + 0) * 512), ah0);
        ah1 = mfma16h(f1, *(const f16x8*)(wb3 + (size_t)((2 * jj + 9) * 2 + 1) * 512), ah1);
      }
      WAITLDN(0);
#pragma unroll
      for (int jj = 6; jj < 8; jj++) {
        f16x8 f0 = dec8(rw[jj].x, rw[jj].y);
        f16x8 f1 = dec8(rw[jj].z, rw[jj].w);
        ah0 = mfma16h(f0, *(const f16x8*)(wb3 + (size_t)((2 * jj + 8) * 2 + 0) * 512), ah0);
        ah1 = mfma16h(f0, *(const f16x8*)(wb3 + (size_t)((2 * jj + 8) * 2 + 1) * 512), ah1);
        ah0 = mfma16h(f1, *(const f16x8*)(wb3 + (size_t)((2 * jj + 9) * 2 + 0) * 512), ah0);
        ah1 = mfma16h(f1, *(const f16x8*)(wb3 + (size_t)((2 * jj + 9) * 2 + 1) * 512), ah1);
      }
#pragma unroll
      for (int i = 0; i < 4; i++) {
        acc0[i] += ah0[i] * S_HM;
        acc1[i] += ah1[i] * S_HM;
      }
      float* Ds = (float*)(smem + OFF_DS);
#pragma unroll
      for (int i = 0; i < 4; i++) {
        Ds[(w * 16 + q * 4 + i) * 33 + r]      = acc0[i];
        Ds[(w * 16 + q * 4 + i) * 33 + 16 + r] = acc1[i];
      }
      __syncthreads();
      if (tid < 128) {
        const float* bs = (const float*)(smem + OFF_B3);
        float* Cs = (float*)(smem + OFF_C1);
        int row = tid >> 1, j0 = (tid & 1) * 4;
        float hv[4];
#pragma unroll
        for (int i = 0; i < 4; i++) {
          int j = j0 + i;
          float vi = Ds[row * 33 + 0 + j]  + bs[0 + j];
          float vf = Ds[row * 33 + 8 + j]  + bs[8 + j];
          float vo = Ds[row * 33 + 16 + j] + bs[16 + j];
          float vc = Ds[row * 33 + 24 + j] + bs[24 + j];
          float I = sigm(vi), F = sigm(vf), O = sigm(vo), Ct = tanh_(vc);
          float Cn = F * Cs[row * 8 + j] + I * Ct;
          Cs[row * 8 + j] = Cn;
          hv[i] = O * tanh_(Cn);
        }
        st4_llc(H18 + (size_t)(g * 64 + row) * 512 + permk(c * 8 + j0), enc4s(hv));
      }
      arrive_cnt(fl, c); ++cph;
    }
    // ---------- Phase B_t: mix(t+1) [w 0-1] + cell1(t+2) [w 2-3, pre-wait] ----------
    {
      const u8* Hnew = (t & 1) ? Hq0 : Hq1;   // H(t+1)
      u8* Hdst1      = (t & 1) ? Hq1 : Hq0;   // H(t+2)
      f32x4 macc = {0.f, 0.f, 0.f, 0.f};
      if (w < 2) {
        macc = mix_part1_q(smem, Hnew, g, c, w, lane);
      } else if (t + 2 < Tt) {
        cell1_w23_q(smem, Xe + (size_t)(t + 2) * Bb * EMB_, Hnew, Hdst1, g, c, lane, tid);
      }
      wait_cnt(fl, cph);
      if (w < 2) mix_part2(smem, macc, H18, HM8, g, c, w, lane);
      arrive_cnt(fl, c); ++cph;
    }
  }

  // ---- epilogue: cell2(255) ----
  {
    const u16* Xt = Xe + (size_t)(Tt - 1) * Bb * EMB_;
    const u16* wb3 = (const u16*)(smem + OFF_W3) + lane * 8;
    const u16* xrow = Xt + (size_t)(g * 64 + w * 16 + r) * EMB_;
    f32x4 acc0 = {0.f, 0.f, 0.f, 0.f}, acc1 = {0.f, 0.f, 0.f, 0.f};
    s16x8 xa[8];
#pragma unroll
    for (int kb = 0; kb < 8; kb++) xa[kb] = *(const s16x8*)(xrow + kb * 32 + q * 8);
#pragma unroll
    for (int kb = 0; kb < 8; kb++) {
      acc0 = mfma16(xa[kb], *(const s16x8*)(wb3 + (size_t)(kb * 2 + 0) * 512), acc0);
      acc1 = mfma16(xa[kb], *(const s16x8*)(wb3 + (size_t)(kb * 2 + 1) * 512), acc1);
    }
    wait_cnt(fl, cph);
    const u8* hrow8 = HM8 + (size_t)(g * 64 + w * 16 + r) * 512 + q * 16;
    u32x4 rw[8];
    ld_u8x8(rw, hrow8);
    waitld();
    f32x4 ah0 = {0.f, 0.f, 0.f, 0.f}, ah1 = {0.f, 0.f, 0.f, 0.f};
#pragma unroll
    for (int jj = 0; jj < 8; jj++) {
      f16x8 f0 = dec8(rw[jj].x, rw[jj].y);
      f16x8 f1 = dec8(rw[jj].z, rw[jj].w);
      ah0 = mfma16h(f0, *(const f16x8*)(wb3 + (size_t)((2 * jj + 8) * 2 + 0) * 512), ah0);
      ah1 = mfma16h(f0, *(const f16x8*)(wb3 + (size_t)((2 * jj + 8) * 2 + 1) * 512), ah1);
      ah0 = mfma16h(f1, *(const f16x8*)(wb3 + (size_t)((2 * jj + 9) * 2 + 0) * 512), ah0);
      ah1 = mfma16h(f1, *(const f16x8*)(wb3 + (size_t)((2 * jj + 9) * 2 + 1) * 512), ah1);
    }
#pragma unroll
    for (int i = 0; i < 4; i++) {
      acc0[i] += ah0[i] * S_HM;
      acc1[i] += ah1[i] * S_HM;
    }
    float* Ds = (float*)(smem + OFF_DS);
#pragma unroll
    for (int i = 0; i < 4; i++) {
      Ds[(w * 16 + q * 4 + i) * 33 + r]      = acc0[i];
      Ds[(w * 16 + q * 4 + i) * 33 + 16 + r] = acc1[i];
    }
    __syncthreads();
    if (tid < 128) {
      const float* bs = (const float*)(smem + OFF_B3);
      float* Cs = (float*)(smem + OFF_C1);
      int row = tid >> 1, j0 = (tid & 1) * 4;
      float hv[4];
#pragma unroll
      for (int i = 0; i < 4; i++) {
        int j = j0 + i;
        float vi = Ds[row * 33 + 0 + j]  + bs[0 + j];
        float vf = Ds[row * 33 + 8 + j]  + bs[8 + j];
        float vo = Ds[row * 33 + 16 + j] + bs[16 + j];
        float vc = Ds[row * 33 + 24 + j] + bs[24 + j];
        float I = sigm(vi), F = sigm(vf), O = sigm(vo), Ct = tanh_(vc);
        float Cn = F * Cs[row * 8 + j] + I * Ct;
        Cs[row * 8 + j] = Cn;
        hv[i] = O * tanh_(Cn);
      }
      st4_llc(H18 + (size_t)(g * 64 + row) * 512 + permk(c * 8 + j0), enc4s(hv));
    }
  }

  // ---- final GEMM: u8 H1 (cached loads post-donebar), f16 Wf, bias-corrected ----
  donebar(dn, bi);
  if (bi < 250) {
    const int n0 = bi * 128;
    _Float16* Wf = (_Float16*)smem;   // [16 kb][8 nt][64 lane][8] f16
    for (int idx = tid; idx < 512 * 128; idx += NTHR) {
      int k = idx >> 7, nn2 = idx & 127;
      int nt = nn2 >> 4, rr = nn2 & 15;
      int kb = k >> 5, q2 = (k >> 3) & 3, e = k & 7;
      Wf[((size_t)(kb * 8 + nt) * 64 + q2 * 16 + rr) * 8 + e] =
          (_Float16)p.Whq[(size_t)k * NCLS + n0 + nn2];
    }
    float* bqs = (float*)(smem + OFF_C);
    __syncthreads();
    if (tid < 128) {       // bqs = bq - colsum(Whq)  (u8 bias-fold), from LDS
      int nt = tid >> 4, rr = tid & 15;
      float s = 0.f;
      for (int kb = 0; kb < 16; kb++)
        for (int q2 = 0; q2 < 4; q2++)
#pragma unroll
          for (int e = 0; e < 8; e++)
            s += (float)Wf[((size_t)(kb * 8 + nt) * 64 + q2 * 16 + rr) * 8 + e];
      bqs[tid] = p.bq[n0 + tid] - s;
    }
    __syncthreads();
    const int r2 = lane & 15, q2 = lane >> 4;
    for (int mt = 0; mt < 4; mt++) {
      int rowb = mt * 64 + w * 16;
      const u8* h1base = H18 + (size_t)(rowb + r2) * 512 + q2 * 16;
      f16x8 haf[16];
#pragma unroll
      for (int jj = 0; jj < 8; jj++) {
        u32x4 rwv = *(const u32x4*)(h1base + jj * 64);
        haf[2 * jj]     = dec8(rwv.x, rwv.y);
        haf[2 * jj + 1] = dec8(rwv.z, rwv.w);
      }
      f32x4 acc[8];
#pragma unroll
      for (int nt = 0; nt < 8; nt++) acc[nt] = (f32x4){0.f, 0.f, 0.f, 0.f};
      for (int kb = 0; kb < 16; kb++) {
#pragma unroll
        for (int nt = 0; nt < 8; nt++) {
          f16x8 b = *(const f16x8*)(Wf + ((size_t)(kb * 8 + nt) * 64 + lane) * 8);
          acc[nt] = mfma16h(haf[kb], b, acc[nt]);
        }
      }
#pragma unroll
      for (int nt = 0; nt < 8; nt++)
#pragma unroll
        for (int i = 0; i < 4; i++)
          p.out[(size_t)(rowb + q2 * 4 + i) * NCLS + n0 + nt * 16 + r2] =
              acc[nt][i] * S_H1 + bqs[nt * 16 + r2];
    }
  }
}

extern "C" void kernel_launch(void* const* d_in, const int* in_sizes, int n_in,
                              void* d_out, int out_size, void* d_ws, size_t ws_size,
                              hipStream_t stream) {
  (void)in_sizes; (void)n_in; (void)out_size; (void)ws_size;
  Params p;
  p.X   = (const int*)d_in[0];
  p.Hin = (const float*)d_in[1];
  p.Cin = (const float*)d_in[2];
  p.E   = (const float*)d_in[3];
  for (int gidx = 0; gidx < 4; gidx++) {
    int base = 4 + gidx * 6;
    p.Wx[gidx]  = (const float*)d_in[base + 0];
    p.Wh[gidx]  = (const float*)d_in[base + 1];
    p.bg[gidx]  = (const float*)d_in[base + 2];
    p.Wx1[gidx] = (const float*)d_in[base + 3];
    p.Wh1[gidx] = (const float*)d_in[base + 4];
    p.bg1[gidx] = (const float*)d_in[base + 5];
  }
  p.Wxh = (const float*)d_in[28];
  p.Whh = (const float*)d_in[29];
  p.bh  = (const float*)d_in[30];
  p.Whq = (const float*)d_in[31];
  p.bq  = (const float*)d_in[32];
  p.out = (float*)d_out;
  p.ws  = (char*)d_ws;

  hipFuncSetAttribute(reinterpret_cast<const void*>(lstm_pers),
                      hipFuncAttributeMaxDynamicSharedMemorySize, SMEM_BYTES);
  lstm_pers<<<dim3(NWG), dim3(NTHR), SMEM_BYTES, stream>>>(p);
}

// Round 12
// 3034.809 us; speedup vs baseline: 1.3062x; 1.0079x over previous
//
#include <hip/hip_runtime.h>
#include <cstdint>
#include <cstddef>

typedef unsigned short u16;
typedef unsigned char u8;
typedef unsigned long long u64;
typedef __attribute__((ext_vector_type(8))) short s16x8;
typedef __attribute__((ext_vector_type(8))) _Float16 f16x8;
typedef __attribute__((ext_vector_type(4))) float f32x4;
typedef __attribute__((ext_vector_type(4))) unsigned int u32x4;
typedef __attribute__((ext_vector_type(4))) unsigned short u16x4;

#define AGENT __HIP_MEMORY_SCOPE_AGENT

namespace {
constexpr int NWG  = 256;
constexpr int NTHR = 256;
constexpr int Bb   = 256;
constexpr int Tt   = 256;
constexpr int EMB_ = 256;
constexpr int HID_ = 512;
constexpr int NCLS = 32000;

constexpr float S_HM = 1.0f / 255.0f;    // H1m u8 scale (sigmoid, unsigned)
constexpr float S_H1 = 1.0f / 127.5f;    // H / H1 u8 scale (biased: v = u*S - 1)

// ---- LDS layout (bytes) ----
constexpr int OFF_W1  = 0;        // cell1: x bf16, H f16
constexpr int OFF_W3  = 49152;    // cell2: x bf16, H f16
constexpr int OFF_W2  = 98304;    // mix: all f16 (both operand halves u8-decoded)
constexpr int OFF_DS  = 131072;   // cell2 gate scratch [64][33] f32 (wave-disjoint rows)
constexpr int OFF_DS1 = 139520;   // cell1 gate scratch
constexpr int OFF_DSM = 147968;   // mix per-wave transpose / init colsum scratch
constexpr int OFF_C   = 150144;   // cell1 C state (bq reuse in final)
constexpr int OFF_C1  = 152192;   // cell2 C state
constexpr int OFF_B1  = 154240;   // bg - colsum(Wh)   (u8-bias folded)
constexpr int OFF_B3  = 154368;   // bg1 (H1m unsigned -> no fold)
constexpr int OFF_B2  = 154496;   // bh - colsum(Wxh) - colsum(Whh)
constexpr int SMEM_BYTES = 154560;

// ---- workspace layout ----
constexpr size_t WS_FL   = 0;                          // 256 x 128B
constexpr size_t WS_DONE = 32768;
constexpr size_t WS_HQ0  = 33792;                      // H u8 ping [B][512]
constexpr size_t WS_HQ1  = WS_HQ0 + (size_t)Bb * HID_;
constexpr size_t WS_H18  = WS_HQ1 + (size_t)Bb * HID_; // H1 u8
constexpr size_t WS_HM8  = WS_H18 + (size_t)Bb * HID_; // H1m u8
constexpr size_t WS_XE   = WS_HM8 + (size_t)Bb * HID_; // Xe bf16
}  // namespace

struct Params {
  const int* X; const float* Hin; const float* Cin; const float* E;
  const float* Wx[4];  const float* Wh[4];  const float* bg[4];
  const float* Wx1[4]; const float* Wh1[4]; const float* bg1[4];
  const float* Wxh; const float* Whh; const float* bh;
  const float* Whq; const float* bq;
  float* out; char* ws;
};

__device__ __forceinline__ u16 f2bf(float f) {
  union { float f; unsigned u; } v; v.f = f;
  unsigned r = v.u + 0x7FFFu + ((v.u >> 16) & 1u);
  return (u16)(r >> 16);
}
__device__ __forceinline__ u16 f2h(float f) {
  _Float16 h = (_Float16)f;
  union { _Float16 h; u16 u; } v; v.h = h; return v.u;
}
__device__ __forceinline__ float sigm(float x) { return 1.f / (1.f + __expf(-x)); }
__device__ __forceinline__ float tanh_(float x) {
  x = fminf(fmaxf(x, -10.f), 10.f);
  float e = __expf(-2.f * x);
  return (1.f - e) / (1.f + e);
}
__device__ __forceinline__ f32x4 mfma16(s16x8 a, s16x8 b, f32x4 c) {
  return __builtin_amdgcn_mfma_f32_16x16x32_bf16(a, b, c, 0, 0, 0);
}
__device__ __forceinline__ f32x4 mfma16h(f16x8 a, f16x8 b, f32x4 c) {
  return __builtin_amdgcn_mfma_f32_16x16x32_f16(a, b, c, 0, 0, 0);
}

// permuted u8 k-layout: consumer lane(q) load j covers frags 2j,2j+1 contiguously.
// k = kb*32 + q*8 + e  ->  pos = (kb>>1)*64 + q*16 + (kb&1)*8 + e   (bijective)
__device__ __forceinline__ int permk(int k) {
  return ((k >> 6) << 6) | (((k >> 3) & 3) << 4) | (((k >> 5) & 1) << 3) | (k & 7);
}

// decode 8 u8 (2 dwords) -> 8 f16 (exact: ints <=255)
__device__ __forceinline__ f16x8 dec8(unsigned lo, unsigned hi) {
  union { unsigned w[4]; f16x8 v; } o;
  float a, b;
  asm("v_cvt_f32_ubyte0 %0, %1" : "=v"(a) : "v"(lo));
  asm("v_cvt_f32_ubyte1 %0, %1" : "=v"(b) : "v"(lo));
  asm("v_cvt_pkrtz_f16_f32 %0, %1, %2" : "=v"(o.w[0]) : "v"(a), "v"(b));
  asm("v_cvt_f32_ubyte2 %0, %1" : "=v"(a) : "v"(lo));
  asm("v_cvt_f32_ubyte3 %0, %1" : "=v"(b) : "v"(lo));
  asm("v_cvt_pkrtz_f16_f32 %0, %1, %2" : "=v"(o.w[1]) : "v"(a), "v"(b));
  asm("v_cvt_f32_ubyte0 %0, %1" : "=v"(a) : "v"(hi));
  asm("v_cvt_f32_ubyte1 %0, %1" : "=v"(b) : "v"(hi));
  asm("v_cvt_pkrtz_f16_f32 %0, %1, %2" : "=v"(o.w[2]) : "v"(a), "v"(b));
  asm("v_cvt_f32_ubyte2 %0, %1" : "=v"(a) : "v"(hi));
  asm("v_cvt_f32_ubyte3 %0, %1" : "=v"(b) : "v"(hi));
  asm("v_cvt_pkrtz_f16_f32 %0, %1, %2" : "=v"(o.w[3]) : "v"(a), "v"(b));
  return o.v;
}
__device__ __forceinline__ unsigned enc4(float a, float b, float c2, float d) {
  unsigned ua = (unsigned)a, ub = (unsigned)b, uc = (unsigned)c2, ud = (unsigned)d;
  return ua | (ub << 8) | (uc << 16) | (ud << 24);
}
__device__ __forceinline__ unsigned enc4s(const float* hv) {   // biased signed encode
  return enc4((hv[0] + 1.f) * 127.5f + 0.5f, (hv[1] + 1.f) * 127.5f + 0.5f,
              (hv[2] + 1.f) * 127.5f + 0.5f, (hv[3] + 1.f) * 127.5f + 0.5f);
}

// ---- LLC bypass primitives ----
__device__ __forceinline__ void st4_llc(u8* pb, unsigned v) {
  __hip_atomic_store((unsigned*)pb, v, __ATOMIC_RELAXED, AGENT);
}
#define LD16A(d, b, off)                                                      \
  asm volatile("global_load_dwordx4 %0, %1, off offset:" #off " sc0 sc1"      \
               : "=&v"(d) : "v"(b) : "memory")

// u8 panel: 8 x 16B loads per lane = full 512B row across 4 lanes
__device__ __forceinline__ void ld_u8x8(u32x4* d, const u8* b) {
  LD16A(d[0], b, 0);   LD16A(d[1], b, 64);  LD16A(d[2], b, 128);
  LD16A(d[3], b, 192); LD16A(d[4], b, 256); LD16A(d[5], b, 320);
  LD16A(d[6], b, 384); LD16A(d[7], b, 448);
}
__device__ __forceinline__ void waitld() {
  asm volatile("s_waitcnt vmcnt(0)" ::: "memory");
  __builtin_amdgcn_sched_barrier(0);
}
#define WAITLDN(n) do {                                                       \
  asm volatile("s_waitcnt vmcnt(" #n ")" ::: "memory");                       \
  __builtin_amdgcn_sched_barrier(0); } while (0)
// intra-wave LDS write->read fence (wave-local transpose; no barrier needed)
__device__ __forceinline__ void waitlds() {
  asm volatile("s_waitcnt lgkmcnt(0)" ::: "memory");
  __builtin_amdgcn_sched_barrier(0);
}

// ---- counter barrier (poison-zeroed in init; rounds 3/6 lesson) ----
__device__ __forceinline__ void arrive_cnt(int* fl, int c) {
  __syncthreads();
  if (threadIdx.x == 0)
    (void)__hip_atomic_fetch_add(&fl[(c & 7) * 32 + 16], 1, __ATOMIC_RELAXED, AGENT);
}
__device__ __forceinline__ void wait_cnt(int* fl, int ph) {
  const int tgt = ph * 8;
  if (threadIdx.x < 8) {
    for (;;) {
      int v = __hip_atomic_load(&fl[threadIdx.x * 32 + 16], __ATOMIC_RELAXED, AGENT);
      if (!__any(v < tgt)) break;
      __builtin_amdgcn_s_sleep(1);
    }
  }
  __syncthreads();
  __builtin_amdgcn_fence(__ATOMIC_ACQUIRE, "workgroup");
}
__device__ __forceinline__ void groupbar_heavy(int* fl, int slot, int ph) {
  __syncthreads();
  if (threadIdx.x == 0)
    __hip_atomic_store(&fl[slot * 32], ph, __ATOMIC_RELEASE, AGENT);
  if (threadIdx.x < 64) {
    for (;;) {
      int v = __hip_atomic_load(&fl[threadIdx.x * 32], __ATOMIC_RELAXED, AGENT);
      if (!__any(v < ph)) break;
      __builtin_amdgcn_s_sleep(1);
    }
  }
  __syncthreads();
  __builtin_amdgcn_fence(__ATOMIC_ACQUIRE, "agent");
}
__device__ __forceinline__ void donebar(int* dn, int bi) {
  __syncthreads();
  if (threadIdx.x == 0)
    __hip_atomic_store(&dn[bi], 1, __ATOMIC_RELEASE, AGENT);
  for (;;) {
    int v = __hip_atomic_load(&dn[threadIdx.x], __ATOMIC_RELAXED, AGENT);
    if (!__any(v < 1)) break;
    __builtin_amdgcn_s_sleep(1);
  }
  __syncthreads();
  __builtin_amdgcn_fence(__ATOMIC_ACQUIRE, "agent");
}

// Wave-local gate epilogue for cell2-style phases: wave w owns rows row0..+15.
// Ds slice is wave-disjoint; intra-wave lgkmcnt fence only; lanes 0-31 do the
// elementwise + packed u32 store. No __syncthreads on this path (the following
// arrive_cnt's barrier covers the WAR on Ds for the next phase).
__device__ __forceinline__ void cell2_epi(char* smem, int offB, int offC,
                                          f32x4 acc0, f32x4 acc1, u8* Hdst,
                                          int g, int c, int w, int lane) {
  const int r = lane & 15, q = lane >> 4;
  const int row0 = w * 16;
  float* Ds = (float*)(smem + OFF_DS);
#pragma unroll
  for (int i = 0; i < 4; i++) {
    Ds[(row0 + q * 4 + i) * 33 + r]      = acc0[i];
    Ds[(row0 + q * 4 + i) * 33 + 16 + r] = acc1[i];
  }
  waitlds();
  const float* bs = (const float*)(smem + offB);
  float* Cs = (float*)(smem + offC);
  if (lane < 32) {
    int row = row0 + (lane >> 1), j0 = (lane & 1) * 4;
    float hv[4];
#pragma unroll
    for (int i = 0; i < 4; i++) {
      int j = j0 + i;
      float vi = Ds[row * 33 + 0 + j]  + bs[0 + j];
      float vf = Ds[row * 33 + 8 + j]  + bs[8 + j];
      float vo = Ds[row * 33 + 16 + j] + bs[16 + j];
      float vc = Ds[row * 33 + 24 + j] + bs[24 + j];
      float I = sigm(vi), F = sigm(vf), O = sigm(vo), Ct = tanh_(vc);
      float Cn = F * Cs[row * 8 + j] + I * Ct;
      Cs[row * 8 + j] = Cn;
      hv[i] = O * tanh_(Cn);
    }
    st4_llc(Hdst + (size_t)(g * 64 + row) * 512 + permk(c * 8 + j0), enc4s(hv));
  }
}

// Prologue cell1(0): 4 waves, u8 H in/out, f16 H-part MFMA, wave-local epilogue.
__device__ __forceinline__ void cell_phase_q(char* smem, int offW, int offB, int offC,
                                             const u16* Xt, const u8* Hrec, u8* Hdst,
                                             int g, int c, int w, int lane) {
  const int r = lane & 15, q = lane >> 4;
  const int row0 = w * 16;
  const u16* xrow = Xt + (size_t)(g * 64 + row0 + r) * EMB_;
  const u8* hrow = Hrec + (size_t)(g * 64 + row0 + r) * 512 + q * 16;
  const u16* wb = (const u16*)(smem + offW) + lane * 8;
  f32x4 acc0 = {0.f, 0.f, 0.f, 0.f}, acc1 = {0.f, 0.f, 0.f, 0.f};
#pragma unroll
  for (int kb = 0; kb < 8; kb++) {
    s16x8 a  = *(const s16x8*)(xrow + kb * 32 + q * 8);
    acc0 = mfma16(a, *(const s16x8*)(wb + (size_t)(kb * 2 + 0) * 512), acc0);
    acc1 = mfma16(a, *(const s16x8*)(wb + (size_t)(kb * 2 + 1) * 512), acc1);
  }
  u32x4 rw[8];
  ld_u8x8(rw, hrow);
  waitld();
  f32x4 ah0 = {0.f, 0.f, 0.f, 0.f}, ah1 = {0.f, 0.f, 0.f, 0.f};
#pragma unroll
  for (int jj = 0; jj < 8; jj++) {
    f16x8 f0 = dec8(rw[jj].x, rw[jj].y);
    f16x8 f1 = dec8(rw[jj].z, rw[jj].w);
    ah0 = mfma16h(f0, *(const f16x8*)(wb + (size_t)((2 * jj + 8) * 2 + 0) * 512), ah0);
    ah1 = mfma16h(f0, *(const f16x8*)(wb + (size_t)((2 * jj + 8) * 2 + 1) * 512), ah1);
    ah0 = mfma16h(f1, *(const f16x8*)(wb + (size_t)((2 * jj + 9) * 2 + 0) * 512), ah0);
    ah1 = mfma16h(f1, *(const f16x8*)(wb + (size_t)((2 * jj + 9) * 2 + 1) * 512), ah1);
  }
#pragma unroll
  for (int i = 0; i < 4; i++) { acc0[i] += ah0[i] * S_H1; acc1[i] += ah1[i] * S_H1; }
  cell2_epi(smem, offB, offC, acc0, acc1, Hdst, g, c, w, lane);
}

// cell1 on waves 2-3: u8 H in/out, wave-local (no barrier). Runs PRE-wait in B.
__device__ __forceinline__ void cell1_w23_q(char* smem, const u16* Xt, const u8* Hrec,
                                            u8* Hdst, int g, int c, int lane, int tid) {
  const int wv = (tid >> 6) - 2;
  const int r = lane & 15, q = lane >> 4;
  const u16* wb1 = (const u16*)(smem + OFF_W1) + lane * 8;
  float* D1 = (float*)(smem + OFF_DS1);
#pragma unroll
  for (int blk = 0; blk < 2; blk++) {
    const int rb = wv * 32 + blk * 16;
    const u16* xrow = Xt + (size_t)(g * 64 + rb + r) * EMB_;
    const u8* hrow = Hrec + (size_t)(g * 64 + rb + r) * 512 + q * 16;
    s16x8 xa[8];
#pragma unroll
    for (int kb = 0; kb < 8; kb++) xa[kb] = *(const s16x8*)(xrow + kb * 32 + q * 8);
    u32x4 rw[8];
    ld_u8x8(rw, hrow);
    f32x4 a0 = {0.f, 0.f, 0.f, 0.f}, a1 = {0.f, 0.f, 0.f, 0.f};
#pragma unroll
    for (int kb = 0; kb < 8; kb++) {
      a0 = mfma16(xa[kb], *(const s16x8*)(wb1 + (size_t)(kb * 2 + 0) * 512), a0);
      a1 = mfma16(xa[kb], *(const s16x8*)(wb1 + (size_t)(kb * 2 + 1) * 512), a1);
    }
    waitld();
    f32x4 ah0 = {0.f, 0.f, 0.f, 0.f}, ah1 = {0.f, 0.f, 0.f, 0.f};
#pragma unroll
    for (int jj = 0; jj < 8; jj++) {
      f16x8 f0 = dec8(rw[jj].x, rw[jj].y);
      f16x8 f1 = dec8(rw[jj].z, rw[jj].w);
      ah0 = mfma16h(f0, *(const f16x8*)(wb1 + (size_t)((2 * jj + 8) * 2 + 0) * 512), ah0);
      ah1 = mfma16h(f0, *(const f16x8*)(wb1 + (size_t)((2 * jj + 8) * 2 + 1) * 512), ah1);
      ah0 = mfma16h(f1, *(const f16x8*)(wb1 + (size_t)((2 * jj + 9) * 2 + 0) * 512), ah0);
      ah1 = mfma16h(f1, *(const f16x8*)(wb1 + (size_t)((2 * jj + 9) * 2 + 1) * 512), ah1);
    }
#pragma unroll
    for (int i = 0; i < 4; i++) {
      D1[(rb + q * 4 + i) * 33 + r]      = a0[i] + ah0[i] * S_H1;
      D1[(rb + q * 4 + i) * 33 + 16 + r] = a1[i] + ah1[i] * S_H1;
    }
  }
  waitlds();
  const float* bs = (const float*)(smem + OFF_B1);
  float* Cs = (float*)(smem + OFF_C);
  int t2 = tid - 128;
  int row = t2 >> 1, j0 = (t2 & 1) * 4;
  float hv[4];
#pragma unroll
  for (int i = 0; i < 4; i++) {
    int j = j0 + i;
    float vi = D1[row * 33 + 0 + j]  + bs[0 + j];
    float vf = D1[row * 33 + 8 + j]  + bs[8 + j];
    float vo = D1[row * 33 + 16 + j] + bs[16 + j];
    float vc = D1[row * 33 + 24 + j] + bs[24 + j];
    float I = sigm(vi), F = sigm(vf), O = sigm(vo), Ct = tanh_(vc);
    float Cn = F * Cs[row * 8 + j] + I * Ct;
    Cs[row * 8 + j] = Cn;
    hv[i] = O * tanh_(Cn);
  }
  st4_llc(Hdst + (size_t)(g * 64 + row) * 512 + permk(c * 8 + j0), enc4s(hv));
}

// mix part 1 (slack, waves 0-1): u8 H panel, f16 MFMA. Returns u8-scaled acc.
__device__ __forceinline__ f32x4 mix_part1_q(char* smem, const u8* Hq, int g, int c,
                                             int w, int lane) {
  const int r = lane & 15, q = lane >> 4;
  int rbase = g * 64 + (c & 1) * 32 + w * 16 + r;
  const u8* h0 = Hq + (size_t)rbase * 512 + q * 16;
  const u16* wb = (const u16*)(smem + OFF_W2) + lane * 8;
  u32x4 rw[8];
  ld_u8x8(rw, h0);
  waitld();
  f32x4 acc = {0.f, 0.f, 0.f, 0.f};
#pragma unroll
  for (int jj = 0; jj < 8; jj++) {
    acc = mfma16h(dec8(rw[jj].x, rw[jj].y), *(const f16x8*)(wb + (size_t)(2 * jj) * 512), acc);
    acc = mfma16h(dec8(rw[jj].z, rw[jj].w), *(const f16x8*)(wb + (size_t)(2 * jj + 1) * 512), acc);
  }
  return acc;
}

// mix part 2 (CRITICAL): u8 H1 panel, f16 MFMA, chunked vmcnt.
// B2 = bh - colsum(Wxh) - colsum(Whh) (both u8-bias folds).
__device__ __forceinline__ void mix_part2(char* smem, f32x4 macc, const u8* H18,
                                          u8* HM8, int g, int c, int w, int lane) {
  const int r = lane & 15, q = lane >> 4;
  int rbase = g * 64 + (c & 1) * 32 + w * 16 + r;
  const u8* h1 = H18 + (size_t)rbase * 512 + q * 16;
  const u16* wb = (const u16*)(smem + OFF_W2) + lane * 8;
  u32x4 rw[8];
  ld_u8x8(rw, h1);
  __builtin_amdgcn_sched_barrier(0);
  f32x4 acch = {0.f, 0.f, 0.f, 0.f};
  WAITLDN(6);
#pragma unroll
  for (int j = 0; j < 2; j++) {
    acch = mfma16h(dec8(rw[j].x, rw[j].y), *(const f16x8*)(wb + (size_t)(16 + 2 * j) * 512), acch);
    acch = mfma16h(dec8(rw[j].z, rw[j].w), *(const f16x8*)(wb + (size_t)(17 + 2 * j) * 512), acch);
  }
  WAITLDN(4);
#pragma unroll
  for (int j = 2; j < 4; j++) {
    acch = mfma16h(dec8(rw[j].x, rw[j].y), *(const f16x8*)(wb + (size_t)(16 + 2 * j) * 512), acch);
    acch = mfma16h(dec8(rw[j].z, rw[j].w), *(const f16x8*)(wb + (size_t)(17 + 2 * j) * 512), acch);
  }
  WAITLDN(2);
#pragma unroll
  for (int j = 4; j < 6; j++) {
    acch = mfma16h(dec8(rw[j].x, rw[j].y), *(const f16x8*)(wb + (size_t)(16 + 2 * j) * 512), acch);
    acch = mfma16h(dec8(rw[j].z, rw[j].w), *(const f16x8*)(wb + (size_t)(17 + 2 * j) * 512), acch);
  }
  WAITLDN(0);
#pragma unroll
  for (int j = 6; j < 8; j++) {
    acch = mfma16h(dec8(rw[j].x, rw[j].y), *(const f16x8*)(wb + (size_t)(16 + 2 * j) * 512), acch);
    acch = mfma16h(dec8(rw[j].z, rw[j].w), *(const f16x8*)(wb + (size_t)(17 + 2 * j) * 512), acch);
  }
  f32x4 acc;
#pragma unroll
  for (int i = 0; i < 4; i++) acc[i] = (macc[i] + acch[i]) * S_H1;
  float* Dm = (float*)(smem + OFF_DSM) + (size_t)w * 16 * 17;
#pragma unroll
  for (int i = 0; i < 4; i++) Dm[(q * 4 + i) * 17 + r] = acc[i];
  waitlds();
  const float* b2 = (const float*)(smem + OFF_B2);
  int row2 = lane >> 2, j0 = (lane & 3) * 4;
  float s0 = sigm(Dm[row2 * 17 + j0 + 0] + b2[j0 + 0]);
  float s1 = sigm(Dm[row2 * 17 + j0 + 1] + b2[j0 + 1]);
  float s2 = sigm(Dm[row2 * 17 + j0 + 2] + b2[j0 + 2]);
  float s3 = sigm(Dm[row2 * 17 + j0 + 3] + b2[j0 + 3]);
  unsigned pv = enc4(s0 * 255.f + 0.5f, s1 * 255.f + 0.5f,
                     s2 * 255.f + 0.5f, s3 * 255.f + 0.5f);
  int colg = (c >> 1) * 16 + j0;
  st4_llc(HM8 + (size_t)(g * 64 + (c & 1) * 32 + w * 16 + row2) * 512 + permk(colg), pv);
}

__global__ __launch_bounds__(NTHR, 1) void lstm_pers(Params p) {
  extern __shared__ char smem[];
  const int tid = threadIdx.x;
  const int bi = blockIdx.x;
  const int w = tid >> 6, lane = tid & 63;
  const int g = bi >> 6, c = bi & 63;
  const int r = lane & 15, q = lane >> 4;

  int* fl = (int*)(p.ws + WS_FL) + g * 64 * 32;
  int* dn = (int*)(p.ws + WS_DONE);
  u8* Hq0 = (u8*)(p.ws + WS_HQ0);
  u8* Hq1 = (u8*)(p.ws + WS_HQ1);
  u8* H18 = (u8*)(p.ws + WS_H18);
  u8* HM8 = (u8*)(p.ws + WS_HM8);
  u16* Xe = (u16*)(p.ws + WS_XE);

  // zero phase counters (ws is POISONED; RMW needs explicit zero — rounds 3/6)
  if (tid == 0 && c < 8)
    __hip_atomic_store(&fl[c * 32 + 16], 0, __ATOMIC_RELAXED, AGENT);

  // ---- one-time init ----
  {
    u16* w1 = (u16*)(smem + OFF_W1);
    u16* w3 = (u16*)(smem + OFF_W3);
    int gate = tid >> 6, kk8 = (tid >> 3) & 7, j = tid & 7;
    int cc = gate * 8 + j;
    int n = cc >> 4, rr = cc & 15;
    int hid = c * 8 + j;
    for (int kk = kk8; kk < 768; kk += 8) {
      int kb = kk >> 5, q2 = (kk >> 3) & 3, e = kk & 7;
      size_t dst = ((size_t)(kb * 2 + n) * 64 + q2 * 16 + rr) * 8 + e;
      float s1 = (kk < 256) ? p.Wx[gate][(size_t)kk * HID_ + hid]
                            : p.Wh[gate][(size_t)(kk - 256) * HID_ + hid];
      float s3 = (kk < 256) ? p.Wx1[gate][(size_t)kk * HID_ + hid]
                            : p.Wh1[gate][(size_t)(kk - 256) * HID_ + hid];
      w1[dst] = (kk < 256) ? f2bf(s1) : f2h(s1);   // H-part f16 (u8-decoded operand)
      w3[dst] = (kk < 256) ? f2bf(s3) : f2h(s3);
    }
    {  // mix weights: all f16 (both operand halves are u8-decoded)
      u16* w2 = (u16*)(smem + OFF_W2);
      int kk16 = tid >> 4, j2 = tid & 15;
      int hid2 = (c >> 1) * 16 + j2;
      for (int kk = kk16; kk < 1024; kk += 16) {
        int kb = kk >> 5, q2 = (kk >> 3) & 3, e = kk & 7;
        size_t dst = ((size_t)kb * 64 + q2 * 16 + j2) * 8 + e;
        float s = (kk < 512) ? p.Wxh[(size_t)kk * HID_ + hid2]
                             : p.Whh[(size_t)(kk - 512) * HID_ + hid2];
        w2[dst] = f2h(s);
      }
    }
    // B1 = bg - colsum(Wh)  (u8-bias fold for cell1's H input)
    {
      float* scr = (float*)(smem + OFF_DSM);
      int col32 = tid & 31, part = tid >> 5;
      int gt = col32 >> 3, jj = col32 & 7;
      int hid1 = c * 8 + jj;
      float s = 0.f;
      for (int k = part * 64; k < part * 64 + 64; k++)
        s += p.Wh[gt][(size_t)k * HID_ + hid1];
      scr[col32 * 8 + part] = s;
      __syncthreads();
      if (tid < 32) {
        float t2 = 0.f;
        for (int i2 = 0; i2 < 8; i2++) t2 += scr[tid * 8 + i2];
        ((float*)(smem + OFF_B1))[tid] = p.bg[tid >> 3][c * 8 + (tid & 7)] - t2;
      }
      __syncthreads();
    }
    // B2 = bh - colsum(Wxh) - colsum(Whh)
    {
      float* scr = (float*)(smem + OFF_DSM);
      int col = tid & 15, part = tid >> 4;
      int hid2 = (c >> 1) * 16 + col;
      float s = 0.f;
      for (int k = part * 32; k < part * 32 + 32; k++)
        s += p.Whh[(size_t)k * HID_ + hid2] + p.Wxh[(size_t)k * HID_ + hid2];
      scr[col * 16 + part] = s;
      __syncthreads();
      if (tid < 16) {
        float t2 = 0.f;
        for (int i2 = 0; i2 < 16; i2++) t2 += scr[tid * 16 + i2];
        ((float*)(smem + OFF_B2))[tid] = p.bh[(c >> 1) * 16 + tid] - t2;
      }
      __syncthreads();
    }
    if (tid < 32) {   // B3 plain (H1m unsigned u8 -> no fold)
      ((float*)(smem + OFF_B3))[tid] = p.bg1[tid >> 3][c * 8 + (tid & 7)];
    }
    float* Cs = (float*)(smem + OFF_C);
    float* C1s = (float*)(smem + OFF_C1);
    for (int it = 0; it < 2; it++) {
      int idx = tid + it * 256;
      int row = idx >> 3, j8 = idx & 7;
      float v = p.Cin[(size_t)(g * 64 + row) * HID_ + c * 8 + j8];
      Cs[row * 8 + j8] = v;
      C1s[row * 8 + j8] = v;
    }
  }
  // H(-1) and H1(-1) u8 init from Hin (biased encode, permuted; normal stores)
  for (int it = 0; it < 2; it++) {
    int idx = bi * 512 + tid + it * 256;
    float v = p.Hin[idx];
    float vc2 = fminf(fmaxf(v, -0.999f), 0.999f);
    u8 ev = (u8)((vc2 + 1.f) * 127.5f + 0.5f);
    int row = idx >> 9, k = idx & 511;
    Hq1[(size_t)row * 512 + permk(k)] = ev;
    H18[(size_t)row * 512 + permk(k)] = ev;
  }
  // Embedding gather
  for (int tt = 0; tt < 4; tt++) {
    int t0 = c * 4 + tt;
    for (int pp = 0; pp < 16; pp++) {
      int b = g * 64 + w * 16 + pp;
      int tok = p.X[(size_t)b * Tt + t0];
      const float4* er = (const float4*)(p.E + (size_t)tok * EMB_);
      float4 v = er[lane];
      u16x4 u; u.x = f2bf(v.x); u.y = f2bf(v.y); u.z = f2bf(v.z); u.w = f2bf(v.w);
      *(u16x4*)(Xe + ((size_t)t0 * Bb + b) * EMB_ + lane * 4) = u;
    }
  }
  groupbar_heavy(fl, c, 1);

  int cph = 0;

  // ---- P0: cell1(0): Hq1 -> Hq0 ----
  cell_phase_q(smem, OFF_W1, OFF_B1, OFF_C, Xe, Hq1, Hq0, g, c, w, lane);
  arrive_cnt(fl, c); ++cph;

  // ---- P1: mix(0) [w 0-1] + cell1(1) [w 2-3] ----
  wait_cnt(fl, cph);
  if (w < 2) {
    f32x4 macc = mix_part1_q(smem, Hq0, g, c, w, lane);
    mix_part2(smem, macc, H18, HM8, g, c, w, lane);
  } else {
    cell1_w23_q(smem, Xe + (size_t)1 * Bb * EMB_, Hq0, Hq1, g, c, lane, tid);
  }
  arrive_cnt(fl, c); ++cph;

  // ---- steady state ----
  for (int t = 0; t < Tt - 1; t++) {
    const u16* Xt = Xe + (size_t)t * Bb * EMB_;
    // ---------- Phase A_t: cell2(t) — u8 H1m panel, f16 MFMA, chunked ----------
    {
      const u16* wb3 = (const u16*)(smem + OFF_W3) + lane * 8;
      const u16* xrow = Xt + (size_t)(g * 64 + w * 16 + r) * EMB_;
      f32x4 acc0 = {0.f, 0.f, 0.f, 0.f}, acc1 = {0.f, 0.f, 0.f, 0.f};
      s16x8 xa[8];
#pragma unroll
      for (int kb = 0; kb < 8; kb++) xa[kb] = *(const s16x8*)(xrow + kb * 32 + q * 8);
#pragma unroll
      for (int kb = 0; kb < 8; kb++) {
        acc0 = mfma16(xa[kb], *(const s16x8*)(wb3 + (size_t)(kb * 2 + 0) * 512), acc0);
        acc1 = mfma16(xa[kb], *(const s16x8*)(wb3 + (size_t)(kb * 2 + 1) * 512), acc1);
      }
      wait_cnt(fl, cph);
      const u8* hrow8 = HM8 + (size_t)(g * 64 + w * 16 + r) * 512 + q * 16;
      u32x4 rw[8];
      ld_u8x8(rw, hrow8);
      __builtin_amdgcn_sched_barrier(0);
      f32x4 ah0 = {0.f, 0.f, 0.f, 0.f}, ah1 = {0.f, 0.f, 0.f, 0.f};
      WAITLDN(6);
#pragma unroll
      for (int jj = 0; jj < 2; jj++) {
        f16x8 f0 = dec8(rw[jj].x, rw[jj].y);
        f16x8 f1 = dec8(rw[jj].z, rw[jj].w);
        ah0 = mfma16h(f0, *(const f16x8*)(wb3 + (size_t)((2 * jj + 8) * 2 + 0) * 512), ah0);
        ah1 = mfma16h(f0, *(const f16x8*)(wb3 + (size_t)((2 * jj + 8) * 2 + 1) * 512), ah1);
        ah0 = mfma16h(f1, *(const f16x8*)(wb3 + (size_t)((2 * jj + 9) * 2 + 0) * 512), ah0);
        ah1 = mfma16h(f1, *(const f16x8*)(wb3 + (size_t)((2 * jj + 9) * 2 + 1) * 512), ah1);
      }
      WAITLDN(4);
#pragma unroll
      for (int jj = 2; jj < 4; jj++) {
        f16x8 f0 = dec8(rw[jj].x, rw[jj].y);
        f16x8 f1 = dec8(rw[jj].z, rw[jj].w);
        ah0 = mfma16h(f0, *(const f16x8*)(wb3 + (size_t)((2 * jj + 8) * 2 + 0) * 512), ah0);
        ah1 = mfma16h(f0, *(const f16x8*)(wb3 + (size_t)((2 * jj + 8) * 2 + 1) * 512), ah1);
        ah0 = mfma16h(f1, *(const f16x8*)(wb3 + (size_t)((2 * jj + 9) * 2 + 0) * 512), ah0);
        ah1 = mfma16h(f1, *(const f16x8*)(wb3 + (size_t)((2 * jj + 9) * 2 + 1) * 512), ah1);
      }
      WAITLDN(2);
#pragma unroll
      for (int jj = 4; jj < 6; jj++) {
        f16x8 f0 = dec8(rw[jj].x, rw[jj].y);
        f16x8 f1 = dec8(rw[jj].z, rw[jj].w);
        ah0 = mfma16h(f0, *(const f16x8*)(wb3 + (size_t)((2 * jj + 8) * 2 + 0) * 512), ah0);
        ah1 = mfma16h(f0, *(const f16x8*)(wb3 + (size_t)((2 * jj + 8) * 2 + 1) * 512), ah1);
        ah0 = mfma16h(f1, *(const f16x8*)(wb3 + (size_t)((2 * jj + 9) * 2 + 0) * 512), ah0);
        ah1 = mfma16h(f1, *(const f16x8*)(wb3 + (size_t)((2 * jj + 9) * 2 + 1) * 512), ah1);
      }
      WAITLDN(0);
#pragma unroll
      for (int jj = 6; jj < 8; jj++) {
        f16x8 f0 = dec8(rw[jj].x, rw[jj].y);
        f16x8 f1 = dec8(rw[jj].z, rw[jj].w);
        ah0 = mfma16h(f0, *(const f16x8*)(wb3 + (size_t)((2 * jj + 8) * 2 + 0) * 512), ah0);
        ah1 = mfma16h(f0, *(const f16x8*)(wb3 + (size_t)((2 * jj + 8) * 2 + 1) * 512), ah1);
        ah0 = mfma16h(f1, *(const f16x8*)(wb3 + (size_t)((2 * jj + 9) * 2 + 0) * 512), ah0);
        ah1 = mfma16h(f1, *(const f16x8*)(wb3 + (size_t)((2 * jj + 9) * 2 + 1) * 512), ah1);
      }
#pragma unroll
      for (int i = 0; i < 4; i++) {
        acc0[i] += ah0[i] * S_HM;
        acc1[i] += ah1[i] * S_HM;
      }
      cell2_epi(smem, OFF_B3, OFF_C1, acc0, acc1, H18, g, c, w, lane);
      arrive_cnt(fl, c); ++cph;
    }
    // ---------- Phase B_t: mix(t+1) [w 0-1] + cell1(t+2) [w 2-3, pre-wait] ----------
    {
      const u8* Hnew = (t & 1) ? Hq0 : Hq1;   // H(t+1)
      u8* Hdst1      = (t & 1) ? Hq1 : Hq0;   // H(t+2)
      f32x4 macc = {0.f, 0.f, 0.f, 0.f};
      if (w < 2) {
        macc = mix_part1_q(smem, Hnew, g, c, w, lane);
      } else if (t + 2 < Tt) {
        cell1_w23_q(smem, Xe + (size_t)(t + 2) * Bb * EMB_, Hnew, Hdst1, g, c, lane, tid);
      }
      wait_cnt(fl, cph);
      if (w < 2) mix_part2(smem, macc, H18, HM8, g, c, w, lane);
      arrive_cnt(fl, c); ++cph;
    }
  }

  // ---- epilogue: cell2(255) ----
  {
    const u16* Xt = Xe + (size_t)(Tt - 1) * Bb * EMB_;
    const u16* wb3 = (const u16*)(smem + OFF_W3) + lane * 8;
    const u16* xrow = Xt + (size_t)(g * 64 + w * 16 + r) * EMB_;
    f32x4 acc0 = {0.f, 0.f, 0.f, 0.f}, acc1 = {0.f, 0.f, 0.f, 0.f};
    s16x8 xa[8];
#pragma unroll
    for (int kb = 0; kb < 8; kb++) xa[kb] = *(const s16x8*)(xrow + kb * 32 + q * 8);
#pragma unroll
    for (int kb = 0; kb < 8; kb++) {
      acc0 = mfma16(xa[kb], *(const s16x8*)(wb3 + (size_t)(kb * 2 + 0) * 512), acc0);
      acc1 = mfma16(xa[kb], *(const s16x8*)(wb3 + (size_t)(kb * 2 + 1) * 512), acc1);
    }
    wait_cnt(fl, cph);
    const u8* hrow8 = HM8 + (size_t)(g * 64 + w * 16 + r) * 512 + q * 16;
    u32x4 rw[8];
    ld_u8x8(rw, hrow8);
    waitld();
    f32x4 ah0 = {0.f, 0.f, 0.f, 0.f}, ah1 = {0.f, 0.f, 0.f, 0.f};
#pragma unroll
    for (int jj = 0; jj < 8; jj++) {
      f16x8 f0 = dec8(rw[jj].x, rw[jj].y);
      f16x8 f1 = dec8(rw[jj].z, rw[jj].w);
      ah0 = mfma16h(f0, *(const f16x8*)(wb3 + (size_t)((2 * jj + 8) * 2 + 0) * 512), ah0);
      ah1 = mfma16h(f0, *(const f16x8*)(wb3 + (size_t)((2 * jj + 8) * 2 + 1) * 512), ah1);
      ah0 = mfma16h(f1, *(const f16x8*)(wb3 + (size_t)((2 * jj + 9) * 2 + 0) * 512), ah0);
      ah1 = mfma16h(f1, *(const f16x8*)(wb3 + (size_t)((2 * jj + 9) * 2 + 1) * 512), ah1);
    }
#pragma unroll
    for (int i = 0; i < 4; i++) {
      acc0[i] += ah0[i] * S_HM;
      acc1[i] += ah1[i] * S_HM;
    }
    cell2_epi(smem, OFF_B3, OFF_C1, acc0, acc1, H18, g, c, w, lane);
  }

  // ---- final GEMM: u8 H1 (cached loads post-donebar), f16 Wf, bias-corrected ----
  donebar(dn, bi);
  if (bi < 250) {
    const int n0 = bi * 128;
    _Float16* Wf = (_Float16*)smem;   // [16 kb][8 nt][64 lane][8] f16
    for (int idx = tid; idx < 512 * 128; idx += NTHR) {
      int k = idx >> 7, nn2 = idx & 127;
      int nt = nn2 >> 4, rr = nn2 & 15;
      int kb = k >> 5, q2 = (k >> 3) & 3, e = k & 7;
      Wf[((size_t)(kb * 8 + nt) * 64 + q2 * 16 + rr) * 8 + e] =
          (_Float16)p.Whq[(size_t)k * NCLS + n0 + nn2];
    }
    float* bqs = (float*)(smem + OFF_C);
    __syncthreads();
    if (tid < 128) {       // bqs = bq - colsum(Whq)  (u8 bias-fold), from LDS
      int nt = tid >> 4, rr = tid & 15;
      float s = 0.f;
      for (int kb = 0; kb < 16; kb++)
        for (int q2 = 0; q2 < 4; q2++)
#pragma unroll
          for (int e = 0; e < 8; e++)
            s += (float)Wf[((size_t)(kb * 8 + nt) * 64 + q2 * 16 + rr) * 8 + e];
      bqs[tid] = p.bq[n0 + tid] - s;
    }
    __syncthreads();
    const int r2 = lane & 15, q2 = lane >> 4;
    for (int mt = 0; mt < 4; mt++) {
      int rowb = mt * 64 + w * 16;
      const u8* h1base = H18 + (size_t)(rowb + r2) * 512 + q2 * 16;
      f16x8 haf[16];
#pragma unroll
      for (int jj = 0; jj < 8; jj++) {
        u32x4 rwv = *(const u32x4*)(h1base + jj * 64);
        haf[2 * jj]     = dec8(rwv.x, rwv.y);
        haf[2 * jj + 1] = dec8(rwv.z, rwv.w);
      }
      f32x4 acc[8];
#pragma unroll
      for (int nt = 0; nt < 8; nt++) acc[nt] = (f32x4){0.f, 0.f, 0.f, 0.f};
      for (int kb = 0; kb < 16; kb++) {
#pragma unroll
        for (int nt = 0; nt < 8; nt++) {
          f16x8 b = *(const f16x8*)(Wf + ((size_t)(kb * 8 + nt) * 64 + lane) * 8);
          acc[nt] = mfma16h(haf[kb], b, acc[nt]);
        }
      }
#pragma unroll
      for (int nt = 0; nt < 8; nt++)
#pragma unroll
        for (int i = 0; i < 4; i++)
          p.out[(size_t)(rowb + q2 * 4 + i) * NCLS + n0 + nt * 16 + r2] =
              acc[nt][i] * S_H1 + bqs[nt * 16 + r2];
    }
  }
}

extern "C" void kernel_launch(void* const* d_in, const int* in_sizes, int n_in,
                              void* d_out, int out_size, void* d_ws, size_t ws_size,
                              hipStream_t stream) {
  (void)in_sizes; (void)n_in; (void)out_size; (void)ws_size;
  Params p;
  p.X   = (const int*)d_in[0];
  p.Hin = (const float*)d_in[1];
  p.Cin = (const float*)d_in[2];
  p.E   = (const float*)d_in[3];
  for (int gidx = 0; gidx < 4; gidx++) {
    int base = 4 + gidx * 6;
    p.Wx[gidx]  = (const float*)d_in[base + 0];
    p.Wh[gidx]  = (const float*)d_in[base + 1];
    p.bg[gidx]  = (const float*)d_in[base + 2];
    p.Wx1[gidx] = (const float*)d_in[base + 3];
    p.Wh1[gidx] = (const float*)d_in[base + 4];
    p.bg1[gidx] = (const float*)d_in[base + 5];
  }
  p.Wxh = (const float*)d_in[28];
  p.Whh = (const float*)d_in[29];
  p.bh  = (const float*)d_in[30];
  p.Whq = (const float*)d_in[31];
  p.bq  = (const float*)d_in[32];
  p.out = (float*)d_out;
  p.ws  = (char*)d_ws;

  hipFuncSetAttribute(reinterpret_cast<const void*>(lstm_pers),
                      hipFuncAttributeMaxDynamicSharedMemorySize, SMEM_BYTES);
  lstm_pers<<<dim3(NWG), dim3(NTHR), SMEM_BYTES, stream>>>(p);
}